// Round 6
// baseline (267.201 us; speedup 1.0000x reference)
//
#include <hip/hip_runtime.h>
#include <hip/hip_bf16.h>
#include <stdint.h>

typedef __attribute__((ext_vector_type(4))) float f32x4;
typedef _Float16 f16;
typedef __attribute__((ext_vector_type(8))) _Float16 f16x8;
typedef decltype(__builtin_amdgcn_cvt_pkrtz(0.f, 0.f)) pk16;

#define DIM   768
#define NH    12
#define HD    64
#define NB    8
#define SEQ   512
#define SCALE 0.125f

#define MFMA16H __builtin_amdgcn_mfma_f32_16x16x32_f16

// gelu tanh-approx: x * sigmoid(2*0.7978845608*(x + 0.044715 x^3))
__device__ __forceinline__ float gelu_f(float x) {
    float pp = x * x;
    float poly = __builtin_fmaf(pp, -0.1029433f, -2.3022077f);
    float ev = __builtin_amdgcn_exp2f(x * poly);
    return x * __builtin_amdgcn_rcpf(1.0f + ev);
}

// ---------------- prep: f32 -> f16 convert, 2 tensors ----------------
__global__ void k_cvt16(const float* __restrict__ in0, f16* __restrict__ out0,
                        const float* __restrict__ in1, f16* __restrict__ out1) {
    int i = blockIdx.x * blockDim.x + threadIdx.x;
    const float* in = blockIdx.y ? in1 : in0;
    f16* out = blockIdx.y ? out1 : out0;
    const float4* s = reinterpret_cast<const float4*>(in + i * 8);
    float4 f0 = s[0], f1 = s[1];
    union { pk16 h[4]; uint4 v; } o;
    o.h[0] = __builtin_amdgcn_cvt_pkrtz(f0.x, f0.y);
    o.h[1] = __builtin_amdgcn_cvt_pkrtz(f0.z, f0.w);
    o.h[2] = __builtin_amdgcn_cvt_pkrtz(f1.x, f1.y);
    o.h[3] = __builtin_amdgcn_cvt_pkrtz(f1.z, f1.w);
    reinterpret_cast<uint4*>(out)[i] = o.v;
}

// ---------------- prep: 4x W[768][768] f32 -> WT f16 transposed ----------------
struct W4 { const float* W[4]; f16* WT[4]; };
__global__ void k_wt4(W4 a) {
    __shared__ float t[32][33];
    const float* W = a.W[blockIdx.z];
    f16* WT = a.WT[blockIdx.z];
    int n0 = blockIdx.x * 32, k0 = blockIdx.y * 32;
    int tx = threadIdx.x, ty = threadIdx.y; // 32 x 8
#pragma unroll
    for (int j = 0; j < 4; ++j)
        t[ty + 8 * j][tx] = W[(k0 + ty + 8 * j) * DIM + n0 + tx];
    __syncthreads();
#pragma unroll
    for (int j = 0; j < 4; ++j)
        WT[(n0 + ty + 8 * j) * DIM + k0 + tx] = (f16)t[tx][ty + 8 * j];
}

// ---------------- prep: pack MLP param tables (f16 MFMA fragments) ----------------
__global__ void k_pack3(const float* __restrict__ W1, const float* __restrict__ b1,
                        const float* __restrict__ W2, f16* __restrict__ W1tab,
                        f16* __restrict__ W2tab) {
    int i = blockIdx.x * 256 + threadIdx.x;
    if (i < 3072) {
        int lane = i & 63;
        int hi = lane >> 4, m = lane & 15;
        int u = (i >> 6) * 16 + m;
#pragma unroll
        for (int e = 0; e < 8; ++e) {
            float v = 0.f;
            if (hi == 0) {
                if (e < 6) v = W1[e * DIM + u];
                else if (e == 6) v = b1[u];
            }
            W1tab[i * 8 + e] = (f16)v;
        }
    } else if (i < 4608) {
        int i2 = i - 3072;
        int j = i2 >> 6, lane = i2 & 63;
        int g = lane >> 4, h = lane & 15;
#pragma unroll
        for (int e = 0; e < 8; ++e) {
            int u = 32 * j + ((e >> 2) << 4) + (g << 2) + (e & 3);
            float v = (h < 12) ? W2[u * 12 + h] : 0.f;
            W2tab[i2 * 8 + e] = (f16)v;
        }
    }
}

// ---------------- fused: bias MLP (4096 blocks) + QKV GEMM (576 blocks) ----------------
struct FArgs {
    const float* qc; const float* kc;
    const f16x8* W1tab; const f16x8* W2tab; const float* b2; f16* bias16;
    const f16* Xq; const f16* Xkv;
    const f16* WqT; const f16* WkT; const f16* WvT;
    const float* bq; const float* bk; const float* bv;
    f16* q_ws; f16* k_ws; f16* v_t;
};

__global__ void __launch_bounds__(256) k_fused(FArgs fa) {
    __shared__ uint4 lds[2048];
    int g = blockIdx.x;
    bool isGemm = ((g & 7) == 1) && (g < 4608);
    int t = threadIdx.x, lane = t & 63, w = t >> 6;
    int hi = lane >> 4, lm = lane & 15;

    if (isGemm) {
        int gi = g >> 3;           // 0..575
        int z = gi / 192;
        int xy = gi - z * 192;
        int m0 = (xy & 31) * 128, n0 = (xy >> 5) * 128;
        const f16* X = (z == 0) ? fa.Xq : fa.Xkv;
        const f16* W = (z == 0) ? fa.WqT : (z == 1) ? fa.WkT : fa.WvT;
        const float* bias = (z == 0) ? fa.bq : (z == 1) ? fa.bk : fa.bv;
        f16* out = (z == 0) ? fa.q_ws : (z == 1) ? fa.k_ws : fa.v_t;

        int wr = w >> 1, wc = w & 1;
        int srow = t >> 1, sch = t & 1;
        const f16* Ag = X + (m0 + srow) * DIM + sch * 16;
        const f16* Bg = W + (n0 + srow) * DIM + sch * 16;
        int sw = (srow >> 1) & 3;
        int wiA0 = srow * 4 + ((2 * sch) ^ sw);
        int wiA1 = srow * 4 + ((2 * sch + 1) ^ sw);

        int aidx[4], bidx[4];
#pragma unroll
        for (int i = 0; i < 4; ++i) {
            int ar = wr * 64 + i * 16 + lm;
            aidx[i] = ar * 4 + (hi ^ ((ar >> 1) & 3));
            int br = wc * 64 + i * 16 + lm;
            bidx[i] = 512 + br * 4 + (hi ^ ((br >> 1) & 3));
        }

        f32x4 acc[4][4] = {};
        {
            uint4 a0 = *(const uint4*)(Ag);
            uint4 a1 = *(const uint4*)(Ag + 8);
            uint4 b0 = *(const uint4*)(Bg);
            uint4 b1 = *(const uint4*)(Bg + 8);
            lds[wiA0] = a0; lds[wiA1] = a1;
            lds[512 + wiA0] = b0; lds[512 + wiA1] = b1;
        }
        __syncthreads();

        for (int kt = 0; kt < 24; ++kt) {
            uint4 na0, na1, nb0, nb1;
            bool pf = kt < 23;
            if (pf) {
                const f16* An = Ag + (kt + 1) * 32;
                const f16* Bn = Bg + (kt + 1) * 32;
                na0 = *(const uint4*)(An);
                na1 = *(const uint4*)(An + 8);
                nb0 = *(const uint4*)(Bn);
                nb1 = *(const uint4*)(Bn + 8);
            }
            int bo = (kt & 1) << 10;
            f16x8 af[4], bf[4];
#pragma unroll
            for (int i = 0; i < 4; ++i) {
                af[i] = *(const f16x8*)&lds[bo + aidx[i]];
                bf[i] = *(const f16x8*)&lds[bo + bidx[i]];
            }
#pragma unroll
            for (int mi = 0; mi < 4; ++mi)
#pragma unroll
                for (int ni = 0; ni < 4; ++ni)
                    acc[mi][ni] = MFMA16H(af[mi], bf[ni], acc[mi][ni], 0, 0, 0);
            if (pf) {
                __syncthreads();
                int bo2 = bo ^ 1024;
                lds[bo2 + wiA0] = na0; lds[bo2 + wiA1] = na1;
                lds[bo2 + 512 + wiA0] = nb0; lds[bo2 + 512 + wiA1] = nb1;
                __syncthreads();
            }
        }

#pragma unroll
        for (int mi = 0; mi < 4; ++mi)
#pragma unroll
            for (int ni = 0; ni < 4; ++ni) {
                int n = n0 + wc * 64 + ni * 16 + lm;
                float bn = bias[n];
#pragma unroll
                for (int r = 0; r < 4; ++r) {
                    int m = m0 + wr * 64 + mi * 16 + hi * 4 + r;
                    float v = acc[mi][ni][r] + bn;
                    int bb = m >> 9, l = m & 511, h = n >> 6, d = n & 63;
                    if (z == 2)
                        out[(((bb * NH + h) * HD) + d) * SEQ + l] = (f16)v;  // transposed V
                    else
                        out[(((bb * NH + h) * SEQ) + l) * HD + d] = (f16)v;
                }
            }
    } else {
        // -------- MLP role --------
        int mi = g - min((g + 6) >> 3, 576);   // 0..4095
        int p0 = mi * 64 + w * 16;
        int pair = p0 + lm;
        int qi = pair >> 9, ki = pair & 511;
        float dx = fa.qc[2 * qi] - fa.kc[2 * ki];
        float dy = fa.qc[2 * qi + 1] - fa.kc[2 * ki + 1];

        union { f16x8 v; pk16 h2[4]; } rf;
        { f16x8 z = {}; rf.v = z; }
        if (hi == 0) {
            rf.h2[0] = __builtin_amdgcn_cvt_pkrtz(dx, dy);
            rf.h2[1] = __builtin_amdgcn_cvt_pkrtz(fabsf(dx), fabsf(dy));
            rf.h2[2] = __builtin_amdgcn_cvt_pkrtz(dx * dx, dy * dy);
            rf.h2[3] = __builtin_amdgcn_cvt_pkrtz(1.0f, 0.0f);
        }

        float b2h = (lm < 12) ? fa.b2[lm] : 0.f;
        f32x4 acc = {b2h, b2h, b2h, b2h};
        const f32x4 zero = {};
        const f16x8* w1p = fa.W1tab + lane;
        const f16x8* w2p = fa.W2tab + lane;

#pragma unroll 2
        for (int j = 0; j < 24; ++j) {
            f16x8 a0  = w1p[(2 * j) * 64];
            f16x8 a1  = w1p[(2 * j + 1) * 64];
            f16x8 w2v = w2p[j * 64];
            f32x4 pre0 = MFMA16H(a0, rf.v, zero, 0, 0, 0);
            f32x4 pre1 = MFMA16H(a1, rf.v, zero, 0, 0, 0);
            float g0 = gelu_f(pre0[0]), g1 = gelu_f(pre0[1]);
            float g2 = gelu_f(pre0[2]), g3 = gelu_f(pre0[3]);
            float g4 = gelu_f(pre1[0]), g5 = gelu_f(pre1[1]);
            float g6 = gelu_f(pre1[2]), g7 = gelu_f(pre1[3]);
            union { f16x8 v; pk16 h2[4]; } pa;
            pa.h2[0] = __builtin_amdgcn_cvt_pkrtz(g0, g1);
            pa.h2[1] = __builtin_amdgcn_cvt_pkrtz(g2, g3);
            pa.h2[2] = __builtin_amdgcn_cvt_pkrtz(g4, g5);
            pa.h2[3] = __builtin_amdgcn_cvt_pkrtz(g6, g7);
            acc = MFMA16H(pa.v, w2v, acc, 0, 0, 0);
        }
        if (lm < 12) {
            union { pk16 h[2]; uint2 u2; } o;
            o.h[0] = __builtin_amdgcn_cvt_pkrtz(acc[0], acc[1]);
            o.h[1] = __builtin_amdgcn_cvt_pkrtz(acc[2], acc[3]);
            *reinterpret_cast<uint2*>(fa.bias16 + lm * (SEQ * SEQ) + p0 + hi * 4) = o.u2;
        }
    }
}

// ---------------- O-proj GEMM: 128x128 tile, f32 out ----------------
__global__ void __launch_bounds__(256) k_gemmO(const f16* __restrict__ X,
                                               const f16* __restrict__ WT,
                                               const float* __restrict__ bias,
                                               float* __restrict__ out) {
    __shared__ uint4 lds[2048];
    int m0 = blockIdx.x * 128, n0 = blockIdx.y * 128;
    int t = threadIdx.x, lane = t & 63, w = t >> 6;
    int wr = w >> 1, wc = w & 1;
    int lm = lane & 15, hi = lane >> 4;

    int srow = t >> 1, sch = t & 1;
    const f16* Ag = X + (m0 + srow) * DIM + sch * 16;
    const f16* Bg = WT + (n0 + srow) * DIM + sch * 16;
    int sw = (srow >> 1) & 3;
    int wiA0 = srow * 4 + ((2 * sch) ^ sw);
    int wiA1 = srow * 4 + ((2 * sch + 1) ^ sw);

    int aidx[4], bidx[4];
#pragma unroll
    for (int i = 0; i < 4; ++i) {
        int ar = wr * 64 + i * 16 + lm;
        aidx[i] = ar * 4 + (hi ^ ((ar >> 1) & 3));
        int br = wc * 64 + i * 16 + lm;
        bidx[i] = 512 + br * 4 + (hi ^ ((br >> 1) & 3));
    }

    f32x4 acc[4][4] = {};
    {
        uint4 a0 = *(const uint4*)(Ag);
        uint4 a1 = *(const uint4*)(Ag + 8);
        uint4 b0 = *(const uint4*)(Bg);
        uint4 b1 = *(const uint4*)(Bg + 8);
        lds[wiA0] = a0; lds[wiA1] = a1;
        lds[512 + wiA0] = b0; lds[512 + wiA1] = b1;
    }
    __syncthreads();

    for (int kt = 0; kt < 24; ++kt) {
        uint4 na0, na1, nb0, nb1;
        bool pf = kt < 23;
        if (pf) {
            const f16* An = Ag + (kt + 1) * 32;
            const f16* Bn = Bg + (kt + 1) * 32;
            na0 = *(const uint4*)(An);
            na1 = *(const uint4*)(An + 8);
            nb0 = *(const uint4*)(Bn);
            nb1 = *(const uint4*)(Bn + 8);
        }
        int bo = (kt & 1) << 10;
        f16x8 af[4], bf[4];
#pragma unroll
        for (int i = 0; i < 4; ++i) {
            af[i] = *(const f16x8*)&lds[bo + aidx[i]];
            bf[i] = *(const f16x8*)&lds[bo + bidx[i]];
        }
#pragma unroll
        for (int mi = 0; mi < 4; ++mi)
#pragma unroll
            for (int ni = 0; ni < 4; ++ni)
                acc[mi][ni] = MFMA16H(af[mi], bf[ni], acc[mi][ni], 0, 0, 0);
        if (pf) {
            __syncthreads();
            int bo2 = bo ^ 1024;
            lds[bo2 + wiA0] = na0; lds[bo2 + wiA1] = na1;
            lds[bo2 + 512 + wiA0] = nb0; lds[bo2 + 512 + wiA1] = nb1;
            __syncthreads();
        }
    }

#pragma unroll
    for (int mi = 0; mi < 4; ++mi)
#pragma unroll
        for (int ni = 0; ni < 4; ++ni) {
            int n = n0 + wc * 64 + ni * 16 + lm;
            float bn = bias[n];
#pragma unroll
            for (int r = 0; r < 4; ++r) {
                int m = m0 + wr * 64 + mi * 16 + hi * 4 + r;
                out[m * DIM + n] = acc[mi][ni][r] + bn;
            }
        }
}

// ---------------- attention: per (qtile32, h, b), f16 internals ----------------
__global__ void __launch_bounds__(256) k_attn3(const f16* __restrict__ q_ws,
                                               const f16* __restrict__ k_ws,
                                               const f16* __restrict__ v_t,
                                               const f16* __restrict__ bias16,
                                               f16* __restrict__ attn_out) {
    __shared__ float sm[32 * 516 + 32];   // logits [32][516] + inv[32]
    int qt = blockIdx.x, h = blockIdx.y, b = blockIdx.z;
    int q0 = qt * 32;
    int t = threadIdx.x, lane = t & 63, w = t >> 6;
    int lrow = lane & 15, hi = lane >> 4;
    int bh = b * NH + h;
    const f16* Q = q_ws + (bh * SEQ + q0) * HD;
    const f16* K = k_ws + bh * SEQ * HD;
    const f16* Bias = bias16 + (h * SEQ + q0) * SEQ;

    f16x8 aq[2][2];
#pragma unroll
    for (int rt = 0; rt < 2; ++rt)
#pragma unroll
        for (int ds = 0; ds < 2; ++ds)
            aq[rt][ds] = *(const f16x8*)(Q + (rt * 16 + lrow) * HD + ds * 32 + hi * 8);

#pragma unroll
    for (int ct = 0; ct < 8; ++ct) {
        f32x4 acc0 = {}, acc1 = {};
        int kk = w * 128 + ct * 16 + lrow;
#pragma unroll
        for (int ds = 0; ds < 2; ++ds) {
            f16x8 bk = *(const f16x8*)(K + kk * HD + ds * 32 + hi * 8);
            acc0 = MFMA16H(aq[0][ds], bk, acc0, 0, 0, 0);
            acc1 = MFMA16H(aq[1][ds], bk, acc1, 0, 0, 0);
        }
#pragma unroll
        for (int r = 0; r < 4; ++r) {
            int row0 = hi * 4 + r;
            sm[row0 * 516 + kk] = acc0[r] * SCALE + (float)Bias[row0 * SEQ + kk];
            int row1 = 16 + hi * 4 + r;
            sm[row1 * 516 + kk] = acc1[r] * SCALE + (float)Bias[row1 * SEQ + kk];
        }
    }
    __syncthreads();

    {
        int row = t >> 3, seg = t & 7;
        float mx = -1e30f;
#pragma unroll 8
        for (int i = 0; i < 64; ++i)
            mx = fmaxf(mx, sm[row * 516 + seg + 8 * i]);
        mx = fmaxf(mx, __shfl_xor(mx, 1));
        mx = fmaxf(mx, __shfl_xor(mx, 2));
        mx = fmaxf(mx, __shfl_xor(mx, 4));
        float s = 0.f;
#pragma unroll 8
        for (int i = 0; i < 64; ++i) {
            int idx = row * 516 + seg + 8 * i;
            float pe = __builtin_amdgcn_exp2f((sm[idx] - mx) * 1.442695041f);
            sm[idx] = pe;
            s += pe;
        }
        s += __shfl_xor(s, 1);
        s += __shfl_xor(s, 2);
        s += __shfl_xor(s, 4);
        if (seg == 0) sm[32 * 516 + row] = 1.0f / s;
    }
    __syncthreads();

    const f16* Vt = v_t + bh * HD * SEQ + (w * 16 + lrow) * SEQ;
    f32x4 oacc0 = {}, oacc1 = {};
    for (int kt = 0; kt < 16; ++kt) {
        f16x8 bv = *(const f16x8*)(Vt + kt * 32 + hi * 8);
#pragma unroll
        for (int rt = 0; rt < 2; ++rt) {
            const float* ps = &sm[(rt * 16 + lrow) * 516 + kt * 32 + hi * 8];
            float4 p0 = *(const float4*)(ps);
            float4 p1 = *(const float4*)(ps + 4);
            union { f16x8 v; pk16 h2[4]; } pa;
            pa.h2[0] = __builtin_amdgcn_cvt_pkrtz(p0.x, p0.y);
            pa.h2[1] = __builtin_amdgcn_cvt_pkrtz(p0.z, p0.w);
            pa.h2[2] = __builtin_amdgcn_cvt_pkrtz(p1.x, p1.y);
            pa.h2[3] = __builtin_amdgcn_cvt_pkrtz(p1.z, p1.w);
            if (rt == 0) oacc0 = MFMA16H(pa.v, bv, oacc0, 0, 0, 0);
            else         oacc1 = MFMA16H(pa.v, bv, oacc1, 0, 0, 0);
        }
    }
#pragma unroll
    for (int r = 0; r < 4; ++r) {
        int row0 = hi * 4 + r;
        float v0 = oacc0[r] * sm[32 * 516 + row0];
        attn_out[(b * SEQ + q0 + row0) * DIM + h * HD + w * 16 + lrow] = (f16)v0;
        int row1 = 16 + hi * 4 + r;
        float v1 = oacc1[r] * sm[32 * 516 + row1];
        attn_out[(b * SEQ + q0 + row1) * DIM + h * HD + w * 16 + lrow] = (f16)v1;
    }
}

extern "C" void kernel_launch(void* const* d_in, const int* in_sizes, int n_in,
                              void* d_out, int out_size, void* d_ws, size_t ws_size,
                              hipStream_t stream) {
    const float* query     = (const float*)d_in[0];
    const float* key_value = (const float*)d_in[1];
    const float* qc        = (const float*)d_in[2];
    const float* kc        = (const float*)d_in[3];
    const float* Wq        = (const float*)d_in[4];
    const float* bq        = (const float*)d_in[5];
    const float* Wk        = (const float*)d_in[6];
    const float* bk        = (const float*)d_in[7];
    const float* Wv        = (const float*)d_in[8];
    const float* bv        = (const float*)d_in[9];
    const float* Wo        = (const float*)d_in[10];
    const float* bo        = (const float*)d_in[11];
    const float* W1        = (const float*)d_in[12];
    const float* b1        = (const float*)d_in[13];
    const float* W2        = (const float*)d_in[14];
    const float* b2        = (const float*)d_in[15];

    char* ws = (char*)d_ws;
    f16* Xq   = (f16*)(ws + 0);          // reused as attn_out
    f16* Xkv  = (f16*)(ws + 6291456);
    f16* WqT  = (f16*)(ws + 12582912);
    f16* WkT  = (f16*)(ws + 13762560);
    f16* WvT  = (f16*)(ws + 14942208);
    f16* WoT  = (f16*)(ws + 16121856);
    f16* q_ws = (f16*)(ws + 17301504);
    f16* k_ws = (f16*)(ws + 23592960);
    f16* v_t  = (f16*)(ws + 29884416);   // V written directly transposed [b,h,d,l]
    f16* bias16 = (f16*)(ws + 36175872); // 6291456 B
    f16* W1tab  = (f16*)(ws + 42467328);
    f16* W2tab  = (f16*)(ws + 42516480);
    f16* attn_out = Xq;   // Xq dead after Q projection

    k_cvt16<<<dim3(1536, 2), dim3(256), 0, stream>>>(query, Xq, key_value, Xkv);
    W4 w4 = {{Wq, Wk, Wv, Wo}, {WqT, WkT, WvT, WoT}};
    k_wt4<<<dim3(24, 24, 4), dim3(32, 8), 0, stream>>>(w4);
    k_pack3<<<dim3(18), dim3(256), 0, stream>>>(W1, b1, W2, W1tab, W2tab);

    FArgs fa;
    fa.qc = qc; fa.kc = kc;
    fa.W1tab = (const f16x8*)W1tab; fa.W2tab = (const f16x8*)W2tab;
    fa.b2 = b2; fa.bias16 = bias16;
    fa.Xq = Xq; fa.Xkv = Xkv;
    fa.WqT = WqT; fa.WkT = WkT; fa.WvT = WvT;
    fa.bq = bq; fa.bk = bk; fa.bv = bv;
    fa.q_ws = q_ws; fa.k_ws = k_ws; fa.v_t = v_t;
    k_fused<<<dim3(4672), dim3(256), 0, stream>>>(fa);

    k_attn3<<<dim3(16, NH, NB), dim3(256), 0, stream>>>(q_ws, k_ws, v_t, bias16, attn_out);
    k_gemmO<<<dim3(32, 6), dim3(256), 0, stream>>>(attn_out, WoT, bo, (float*)d_out);
}

// Round 7
// 160.487 us; speedup vs baseline: 1.6649x; 1.6649x over previous
//
#include <hip/hip_runtime.h>
#include <hip/hip_bf16.h>
#include <stdint.h>

typedef __attribute__((ext_vector_type(4))) float f32x4;
typedef _Float16 f16;
typedef __attribute__((ext_vector_type(8))) _Float16 f16x8;
typedef decltype(__builtin_amdgcn_cvt_pkrtz(0.f, 0.f)) pk16;

#define DIM   768
#define NH    12
#define HD    64
#define NB    8
#define SEQ   512
#define SCALE 0.125f

#define MFMA16H __builtin_amdgcn_mfma_f32_16x16x32_f16

// gelu tanh-approx: x * sigmoid(2*0.7978845608*(x + 0.044715 x^3))
__device__ __forceinline__ float gelu_f(float x) {
    float pp = x * x;
    float poly = __builtin_fmaf(pp, -0.1029433f, -2.3022077f);
    float ev = __builtin_amdgcn_exp2f(x * poly);
    return x * __builtin_amdgcn_rcpf(1.0f + ev);
}

// ---------------- prep: f32 -> f16 convert, 2 tensors ----------------
__global__ void k_cvt16(const float* __restrict__ in0, f16* __restrict__ out0,
                        const float* __restrict__ in1, f16* __restrict__ out1) {
    int i = blockIdx.x * blockDim.x + threadIdx.x;
    const float* in = blockIdx.y ? in1 : in0;
    f16* out = blockIdx.y ? out1 : out0;
    const float4* s = reinterpret_cast<const float4*>(in + i * 8);
    float4 f0 = s[0], f1 = s[1];
    union { pk16 h[4]; uint4 v; } o;
    o.h[0] = __builtin_amdgcn_cvt_pkrtz(f0.x, f0.y);
    o.h[1] = __builtin_amdgcn_cvt_pkrtz(f0.z, f0.w);
    o.h[2] = __builtin_amdgcn_cvt_pkrtz(f1.x, f1.y);
    o.h[3] = __builtin_amdgcn_cvt_pkrtz(f1.z, f1.w);
    reinterpret_cast<uint4*>(out)[i] = o.v;
}

// ---------------- prep: 4x W[768][768] f32 -> WT f16 transposed ----------------
struct W4 { const float* W[4]; f16* WT[4]; };
__global__ void k_wt4(W4 a) {
    __shared__ float t[32][33];
    const float* W = a.W[blockIdx.z];
    f16* WT = a.WT[blockIdx.z];
    int n0 = blockIdx.x * 32, k0 = blockIdx.y * 32;
    int tx = threadIdx.x, ty = threadIdx.y; // 32 x 8
#pragma unroll
    for (int j = 0; j < 4; ++j)
        t[ty + 8 * j][tx] = W[(k0 + ty + 8 * j) * DIM + n0 + tx];
    __syncthreads();
#pragma unroll
    for (int j = 0; j < 4; ++j)
        WT[(n0 + ty + 8 * j) * DIM + k0 + tx] = (f16)t[tx][ty + 8 * j];
}

// ---------------- prep: pack MLP param tables (f16 MFMA fragments) ----------------
__global__ void k_pack3(const float* __restrict__ W1, const float* __restrict__ b1,
                        const float* __restrict__ W2, f16* __restrict__ W1tab,
                        f16* __restrict__ W2tab) {
    int i = blockIdx.x * 256 + threadIdx.x;
    if (i < 3072) {
        int lane = i & 63;
        int hi = lane >> 4, m = lane & 15;
        int u = (i >> 6) * 16 + m;
#pragma unroll
        for (int e = 0; e < 8; ++e) {
            float v = 0.f;
            if (hi == 0) {
                if (e < 6) v = W1[e * DIM + u];
                else if (e == 6) v = b1[u];
            }
            W1tab[i * 8 + e] = (f16)v;
        }
    } else if (i < 4608) {
        int i2 = i - 3072;
        int j = i2 >> 6, lane = i2 & 63;
        int g = lane >> 4, h = lane & 15;
#pragma unroll
        for (int e = 0; e < 8; ++e) {
            int u = 32 * j + ((e >> 2) << 4) + (g << 2) + (e & 3);
            float v = (h < 12) ? W2[u * 12 + h] : 0.f;
            W2tab[i2 * 8 + e] = (f16)v;
        }
    }
}

// ---------------- pairwise bias MLP (MFMA), f16 output ----------------
__global__ void __launch_bounds__(256) k_mlp5(const float* __restrict__ qc, const float* __restrict__ kc,
                                              const f16x8* __restrict__ W1tab,   // [48][64]
                                              const f16x8* __restrict__ W2tab,   // [24][64]
                                              const float* __restrict__ b2,
                                              f16* __restrict__ bias16) {
    int t = threadIdx.x, lane = t & 63, w = t >> 6;
    int hi = lane >> 4, m = lane & 15;
    int p0 = blockIdx.x * 64 + w * 16;
    int pair = p0 + m;
    int qi = pair >> 9, ki = pair & 511;
    float dx = qc[2 * qi] - kc[2 * ki];
    float dy = qc[2 * qi + 1] - kc[2 * ki + 1];

    union { f16x8 v; pk16 h2[4]; } rf;
    { f16x8 z = {}; rf.v = z; }
    if (hi == 0) {
        rf.h2[0] = __builtin_amdgcn_cvt_pkrtz(dx, dy);
        rf.h2[1] = __builtin_amdgcn_cvt_pkrtz(fabsf(dx), fabsf(dy));
        rf.h2[2] = __builtin_amdgcn_cvt_pkrtz(dx * dx, dy * dy);
        rf.h2[3] = __builtin_amdgcn_cvt_pkrtz(1.0f, 0.0f);
    }

    float b2h = (m < 12) ? b2[m] : 0.f;
    f32x4 acc = {b2h, b2h, b2h, b2h};
    const f32x4 zero = {};
    const f16x8* w1p = W1tab + lane;
    const f16x8* w2p = W2tab + lane;

#pragma unroll 2
    for (int j = 0; j < 24; ++j) {
        f16x8 a0  = w1p[(2 * j) * 64];
        f16x8 a1  = w1p[(2 * j + 1) * 64];
        f16x8 w2v = w2p[j * 64];
        f32x4 pre0 = MFMA16H(a0, rf.v, zero, 0, 0, 0);
        f32x4 pre1 = MFMA16H(a1, rf.v, zero, 0, 0, 0);
        float g0 = gelu_f(pre0[0]), g1 = gelu_f(pre0[1]);
        float g2 = gelu_f(pre0[2]), g3 = gelu_f(pre0[3]);
        float g4 = gelu_f(pre1[0]), g5 = gelu_f(pre1[1]);
        float g6 = gelu_f(pre1[2]), g7 = gelu_f(pre1[3]);
        union { f16x8 v; pk16 h2[4]; } pa;
        pa.h2[0] = __builtin_amdgcn_cvt_pkrtz(g0, g1);
        pa.h2[1] = __builtin_amdgcn_cvt_pkrtz(g2, g3);
        pa.h2[2] = __builtin_amdgcn_cvt_pkrtz(g4, g5);
        pa.h2[3] = __builtin_amdgcn_cvt_pkrtz(g6, g7);
        acc = MFMA16H(pa.v, w2v, acc, 0, 0, 0);
    }
    if (m < 12) {
        union { pk16 h[2]; uint2 u2; } o;
        o.h[0] = __builtin_amdgcn_cvt_pkrtz(acc[0], acc[1]);
        o.h[1] = __builtin_amdgcn_cvt_pkrtz(acc[2], acc[3]);
        *reinterpret_cast<uint2*>(bias16 + m * (SEQ * SEQ) + p0 + hi * 4) = o.u2;
    }
}

// ---------------- LDS-staged QKV GEMM: 128x128, BK=32, dbuf; V stored transposed ----------------
struct GArgs { const f16* X; const f16* W; const float* bias; f16* out; };
struct G3 { GArgs a[3]; };

__global__ void __launch_bounds__(256) k_gemm3(G3 args) {
    __shared__ uint4 lds[2048];
    int z = blockIdx.z;
    GArgs ga = args.a[z];
    int m0 = blockIdx.x * 128, n0 = blockIdx.y * 128;
    int t = threadIdx.x, lane = t & 63, w = t >> 6;
    int wr = w >> 1, wc = w & 1;
    int lm = lane & 15, hi = lane >> 4;

    int srow = t >> 1, sch = t & 1;
    const f16* Ag = ga.X + (m0 + srow) * DIM + sch * 16;
    const f16* Bg = ga.W + (n0 + srow) * DIM + sch * 16;
    int sw = (srow >> 1) & 3;
    int wiA0 = srow * 4 + ((2 * sch) ^ sw);
    int wiA1 = srow * 4 + ((2 * sch + 1) ^ sw);

    int aidx[4], bidx[4];
#pragma unroll
    for (int i = 0; i < 4; ++i) {
        int ar = wr * 64 + i * 16 + lm;
        aidx[i] = ar * 4 + (hi ^ ((ar >> 1) & 3));
        int br = wc * 64 + i * 16 + lm;
        bidx[i] = 512 + br * 4 + (hi ^ ((br >> 1) & 3));
    }

    f32x4 acc[4][4] = {};
    {
        uint4 a0 = *(const uint4*)(Ag);
        uint4 a1 = *(const uint4*)(Ag + 8);
        uint4 b0 = *(const uint4*)(Bg);
        uint4 b1 = *(const uint4*)(Bg + 8);
        lds[wiA0] = a0; lds[wiA1] = a1;
        lds[512 + wiA0] = b0; lds[512 + wiA1] = b1;
    }
    __syncthreads();

    for (int kt = 0; kt < 24; ++kt) {
        uint4 na0, na1, nb0, nb1;
        bool pf = kt < 23;
        if (pf) {
            const f16* An = Ag + (kt + 1) * 32;
            const f16* Bn = Bg + (kt + 1) * 32;
            na0 = *(const uint4*)(An);
            na1 = *(const uint4*)(An + 8);
            nb0 = *(const uint4*)(Bn);
            nb1 = *(const uint4*)(Bn + 8);
        }
        int bo = (kt & 1) << 10;
        f16x8 af[4], bf[4];
#pragma unroll
        for (int i = 0; i < 4; ++i) {
            af[i] = *(const f16x8*)&lds[bo + aidx[i]];
            bf[i] = *(const f16x8*)&lds[bo + bidx[i]];
        }
#pragma unroll
        for (int mi = 0; mi < 4; ++mi)
#pragma unroll
            for (int ni = 0; ni < 4; ++ni)
                acc[mi][ni] = MFMA16H(af[mi], bf[ni], acc[mi][ni], 0, 0, 0);
        if (pf) {
            __syncthreads();
            int bo2 = bo ^ 1024;
            lds[bo2 + wiA0] = na0; lds[bo2 + wiA1] = na1;
            lds[bo2 + 512 + wiA0] = nb0; lds[bo2 + 512 + wiA1] = nb1;
            __syncthreads();
        }
    }

#pragma unroll
    for (int mi = 0; mi < 4; ++mi)
#pragma unroll
        for (int ni = 0; ni < 4; ++ni) {
            int n = n0 + wc * 64 + ni * 16 + lm;
            float bn = ga.bias[n];
            int h = n >> 6, d = n & 63;
            int mbase = m0 + wr * 64 + mi * 16 + hi * 4;
            int bb = mbase >> 9, l0 = mbase & 511;
            if (z == 2) {
                // V: store transposed [b,h,d,l], 4 consecutive l packed (8B)
                union { pk16 h2[2]; uint2 u2; } o;
                o.h2[0] = __builtin_amdgcn_cvt_pkrtz(acc[mi][ni][0] + bn, acc[mi][ni][1] + bn);
                o.h2[1] = __builtin_amdgcn_cvt_pkrtz(acc[mi][ni][2] + bn, acc[mi][ni][3] + bn);
                *reinterpret_cast<uint2*>(ga.out + (((bb * NH + h) * HD) + d) * SEQ + l0) = o.u2;
            } else {
#pragma unroll
                for (int r = 0; r < 4; ++r)
                    ga.out[(((bb * NH + h) * SEQ) + l0 + r) * HD + d] = (f16)(acc[mi][ni][r] + bn);
            }
        }
}

// ---------------- O-proj GEMM: 128x128 tile, f32 out ----------------
__global__ void __launch_bounds__(256) k_gemmO(const f16* __restrict__ X,
                                               const f16* __restrict__ WT,
                                               const float* __restrict__ bias,
                                               float* __restrict__ out) {
    __shared__ uint4 lds[2048];
    int m0 = blockIdx.x * 128, n0 = blockIdx.y * 128;
    int t = threadIdx.x, lane = t & 63, w = t >> 6;
    int wr = w >> 1, wc = w & 1;
    int lm = lane & 15, hi = lane >> 4;

    int srow = t >> 1, sch = t & 1;
    const f16* Ag = X + (m0 + srow) * DIM + sch * 16;
    const f16* Bg = WT + (n0 + srow) * DIM + sch * 16;
    int sw = (srow >> 1) & 3;
    int wiA0 = srow * 4 + ((2 * sch) ^ sw);
    int wiA1 = srow * 4 + ((2 * sch + 1) ^ sw);

    int aidx[4], bidx[4];
#pragma unroll
    for (int i = 0; i < 4; ++i) {
        int ar = wr * 64 + i * 16 + lm;
        aidx[i] = ar * 4 + (hi ^ ((ar >> 1) & 3));
        int br = wc * 64 + i * 16 + lm;
        bidx[i] = 512 + br * 4 + (hi ^ ((br >> 1) & 3));
    }

    f32x4 acc[4][4] = {};
    {
        uint4 a0 = *(const uint4*)(Ag);
        uint4 a1 = *(const uint4*)(Ag + 8);
        uint4 b0 = *(const uint4*)(Bg);
        uint4 b1 = *(const uint4*)(Bg + 8);
        lds[wiA0] = a0; lds[wiA1] = a1;
        lds[512 + wiA0] = b0; lds[512 + wiA1] = b1;
    }
    __syncthreads();

    for (int kt = 0; kt < 24; ++kt) {
        uint4 na0, na1, nb0, nb1;
        bool pf = kt < 23;
        if (pf) {
            const f16* An = Ag + (kt + 1) * 32;
            const f16* Bn = Bg + (kt + 1) * 32;
            na0 = *(const uint4*)(An);
            na1 = *(const uint4*)(An + 8);
            nb0 = *(const uint4*)(Bn);
            nb1 = *(const uint4*)(Bn + 8);
        }
        int bo = (kt & 1) << 10;
        f16x8 af[4], bf[4];
#pragma unroll
        for (int i = 0; i < 4; ++i) {
            af[i] = *(const f16x8*)&lds[bo + aidx[i]];
            bf[i] = *(const f16x8*)&lds[bo + bidx[i]];
        }
#pragma unroll
        for (int mi = 0; mi < 4; ++mi)
#pragma unroll
            for (int ni = 0; ni < 4; ++ni)
                acc[mi][ni] = MFMA16H(af[mi], bf[ni], acc[mi][ni], 0, 0, 0);
        if (pf) {
            __syncthreads();
            int bo2 = bo ^ 1024;
            lds[bo2 + wiA0] = na0; lds[bo2 + wiA1] = na1;
            lds[bo2 + 512 + wiA0] = nb0; lds[bo2 + 512 + wiA1] = nb1;
            __syncthreads();
        }
    }

#pragma unroll
    for (int mi = 0; mi < 4; ++mi)
#pragma unroll
        for (int ni = 0; ni < 4; ++ni) {
            int n = n0 + wc * 64 + ni * 16 + lm;
            float bn = bias[n];
#pragma unroll
            for (int r = 0; r < 4; ++r) {
                int m = m0 + wr * 64 + mi * 16 + hi * 4 + r;
                out[m * DIM + n] = acc[mi][ni][r] + bn;
            }
        }
}

// ---------------- attention: per (qtile32, h, b), f16 logits LDS ----------------
__global__ void __launch_bounds__(256) k_attn4(const f16* __restrict__ q_ws,
                                               const f16* __restrict__ k_ws,
                                               const f16* __restrict__ v_t,
                                               const f16* __restrict__ bias16,
                                               f16* __restrict__ attn_out) {
    __shared__ __align__(16) unsigned short sm16[32 * 520];  // f16 logits [32][520]
    __shared__ float inv32[32];
    int qt = blockIdx.x, h = blockIdx.y, b = blockIdx.z;
    int q0 = qt * 32;
    int t = threadIdx.x, lane = t & 63, w = t >> 6;
    int lrow = lane & 15, hi = lane >> 4;
    int bh = b * NH + h;
    const f16* Q = q_ws + (bh * SEQ + q0) * HD;
    const f16* K = k_ws + bh * SEQ * HD;
    const f16* Bias = bias16 + (h * SEQ + q0) * SEQ;

    // phase A: S = (Q*SCALE) K^T + bias -> f16 LDS (wave w owns cols [w*128,+128))
    f16x8 aq[2][2];
#pragma unroll
    for (int rt = 0; rt < 2; ++rt)
#pragma unroll
        for (int ds = 0; ds < 2; ++ds) {
            f16x8 v = *(const f16x8*)(Q + (rt * 16 + lrow) * HD + ds * 32 + hi * 8);
            aq[rt][ds] = v * (f16)SCALE;   // exact (pow2)
        }

#pragma unroll
    for (int ct = 0; ct < 8; ++ct) {
        f32x4 acc0 = {}, acc1 = {};
        int kk = w * 128 + ct * 16 + lrow;
#pragma unroll
        for (int ds = 0; ds < 2; ++ds) {
            f16x8 bk = *(const f16x8*)(K + kk * HD + ds * 32 + hi * 8);
            acc0 = MFMA16H(aq[0][ds], bk, acc0, 0, 0, 0);
            acc1 = MFMA16H(aq[1][ds], bk, acc1, 0, 0, 0);
        }
#pragma unroll
        for (int r = 0; r < 4; ++r) {
            int row0 = hi * 4 + r;
            sm16[row0 * 520 + kk] = (unsigned short)__builtin_bit_cast(unsigned short,
                (f16)(acc0[r] + (float)Bias[row0 * SEQ + kk]));
            int row1 = 16 + hi * 4 + r;
            sm16[row1 * 520 + kk] = (unsigned short)__builtin_bit_cast(unsigned short,
                (f16)(acc1[r] + (float)Bias[row1 * SEQ + kk]));
        }
    }
    __syncthreads();

    // phase B: row softmax, 8 lanes/row, 2 cols per load (f16 pairs)
    {
        int row = t >> 3, seg = t & 7;
        int base = row * 520 + 2 * seg;
        float mx = -1e30f;
#pragma unroll 8
        for (int j = 0; j < 32; ++j) {
            union { uint u; f16 h[2]; } cv;
            cv.u = *(const uint*)&sm16[base + 16 * j];
            mx = fmaxf(mx, fmaxf((float)cv.h[0], (float)cv.h[1]));
        }
        mx = fmaxf(mx, __shfl_xor(mx, 1));
        mx = fmaxf(mx, __shfl_xor(mx, 2));
        mx = fmaxf(mx, __shfl_xor(mx, 4));
        float s = 0.f;
#pragma unroll 8
        for (int j = 0; j < 32; ++j) {
            union { uint u; f16 h[2]; } cv;
            cv.u = *(const uint*)&sm16[base + 16 * j];
            float p0 = __builtin_amdgcn_exp2f(((float)cv.h[0] - mx) * 1.442695041f);
            float p1 = __builtin_amdgcn_exp2f(((float)cv.h[1] - mx) * 1.442695041f);
            s += p0 + p1;
            union { pk16 h; uint u; } o;
            o.h = __builtin_amdgcn_cvt_pkrtz(p0, p1);
            *(uint*)&sm16[base + 16 * j] = o.u;
        }
        s += __shfl_xor(s, 1);
        s += __shfl_xor(s, 2);
        s += __shfl_xor(s, 4);
        if (seg == 0) inv32[row] = 1.0f / s;
    }
    __syncthreads();

    // phase C: O = P V  (wave w owns dh cols [w*16,+16)); P read direct as f16x8
    const f16* Vt = v_t + bh * HD * SEQ + (w * 16 + lrow) * SEQ;
    f32x4 oacc0 = {}, oacc1 = {};
    for (int kt = 0; kt < 16; ++kt) {
        f16x8 bv = *(const f16x8*)(Vt + kt * 32 + hi * 8);
        f16x8 pa0 = *(const f16x8*)&sm16[lrow * 520 + kt * 32 + hi * 8];
        f16x8 pa1 = *(const f16x8*)&sm16[(16 + lrow) * 520 + kt * 32 + hi * 8];
        oacc0 = MFMA16H(pa0, bv, oacc0, 0, 0, 0);
        oacc1 = MFMA16H(pa1, bv, oacc1, 0, 0, 0);
    }
#pragma unroll
    for (int r = 0; r < 4; ++r) {
        int row0 = hi * 4 + r;
        float v0 = oacc0[r] * inv32[row0];
        attn_out[(b * SEQ + q0 + row0) * DIM + h * HD + w * 16 + lrow] = (f16)v0;
        int row1 = 16 + hi * 4 + r;
        float v1 = oacc1[r] * inv32[row1];
        attn_out[(b * SEQ + q0 + row1) * DIM + h * HD + w * 16 + lrow] = (f16)v1;
    }
}

extern "C" void kernel_launch(void* const* d_in, const int* in_sizes, int n_in,
                              void* d_out, int out_size, void* d_ws, size_t ws_size,
                              hipStream_t stream) {
    const float* query     = (const float*)d_in[0];
    const float* key_value = (const float*)d_in[1];
    const float* qc        = (const float*)d_in[2];
    const float* kc        = (const float*)d_in[3];
    const float* Wq        = (const float*)d_in[4];
    const float* bq        = (const float*)d_in[5];
    const float* Wk        = (const float*)d_in[6];
    const float* bk        = (const float*)d_in[7];
    const float* Wv        = (const float*)d_in[8];
    const float* bv        = (const float*)d_in[9];
    const float* Wo        = (const float*)d_in[10];
    const float* bo        = (const float*)d_in[11];
    const float* W1        = (const float*)d_in[12];
    const float* b1        = (const float*)d_in[13];
    const float* W2        = (const float*)d_in[14];
    const float* b2        = (const float*)d_in[15];

    char* ws = (char*)d_ws;
    f16* Xq   = (f16*)(ws + 0);          // reused as attn_out
    f16* Xkv  = (f16*)(ws + 6291456);
    f16* WqT  = (f16*)(ws + 12582912);
    f16* WkT  = (f16*)(ws + 13762560);
    f16* WvT  = (f16*)(ws + 14942208);
    f16* WoT  = (f16*)(ws + 16121856);
    f16* q_ws = (f16*)(ws + 17301504);
    f16* k_ws = (f16*)(ws + 23592960);
    f16* v_t  = (f16*)(ws + 29884416);   // V written directly transposed [b,h,d,l]
    f16* bias16 = (f16*)(ws + 36175872); // 6291456 B
    f16* W1tab  = (f16*)(ws + 42467328);
    f16* W2tab  = (f16*)(ws + 42516480);
    f16* attn_out = Xq;   // Xq dead after Q projection

    k_cvt16<<<dim3(1536, 2), dim3(256), 0, stream>>>(query, Xq, key_value, Xkv);
    W4 w4 = {{Wq, Wk, Wv, Wo}, {WqT, WkT, WvT, WoT}};
    k_wt4<<<dim3(24, 24, 4), dim3(32, 8), 0, stream>>>(w4);
    k_pack3<<<dim3(18), dim3(256), 0, stream>>>(W1, b1, W2, W1tab, W2tab);
    k_mlp5<<<dim3(4096), dim3(256), 0, stream>>>(qc, kc, (const f16x8*)W1tab, (const f16x8*)W2tab, b2, bias16);

    G3 qkv;
    qkv.a[0] = {Xq,  WqT, bq, q_ws};
    qkv.a[1] = {Xkv, WkT, bk, k_ws};
    qkv.a[2] = {Xkv, WvT, bv, v_t};
    k_gemm3<<<dim3(32, 6, 3), dim3(256), 0, stream>>>(qkv);

    k_attn4<<<dim3(16, NH, NB), dim3(256), 0, stream>>>(q_ws, k_ws, v_t, bias16, attn_out);
    k_gemmO<<<dim3(32, 6), dim3(256), 0, stream>>>(attn_out, WoT, bo, (float*)d_out);
}

// Round 8
// 152.500 us; speedup vs baseline: 1.7521x; 1.0524x over previous
//
#include <hip/hip_runtime.h>
#include <hip/hip_bf16.h>
#include <stdint.h>
#include <math.h>

typedef __attribute__((ext_vector_type(4))) float f32x4;
typedef _Float16 f16;
typedef __attribute__((ext_vector_type(8))) _Float16 f16x8;
typedef decltype(__builtin_amdgcn_cvt_pkrtz(0.f, 0.f)) pk16;

#define DIM   768
#define NH    12
#define HD    64
#define NB    8
#define SEQ   512
#define SCALE 0.125f

#define MFMA16H __builtin_amdgcn_mfma_f32_16x16x32_f16

// ---------------- prep: f32 -> f16 convert, 2 tensors ----------------
__global__ void k_cvt16(const float* __restrict__ in0, f16* __restrict__ out0,
                        const float* __restrict__ in1, f16* __restrict__ out1) {
    int i = blockIdx.x * blockDim.x + threadIdx.x;
    const float* in = blockIdx.y ? in1 : in0;
    f16* out = blockIdx.y ? out1 : out0;
    const float4* s = reinterpret_cast<const float4*>(in + i * 8);
    float4 f0 = s[0], f1 = s[1];
    union { pk16 h[4]; uint4 v; } o;
    o.h[0] = __builtin_amdgcn_cvt_pkrtz(f0.x, f0.y);
    o.h[1] = __builtin_amdgcn_cvt_pkrtz(f0.z, f0.w);
    o.h[2] = __builtin_amdgcn_cvt_pkrtz(f1.x, f1.y);
    o.h[3] = __builtin_amdgcn_cvt_pkrtz(f1.z, f1.w);
    reinterpret_cast<uint4*>(out)[i] = o.v;
}

// ---------------- prep: 4x W[768][768] f32 -> WT f16 transposed ----------------
struct W4 { const float* W[4]; f16* WT[4]; };
__global__ void k_wt4(W4 a) {
    __shared__ float t[32][33];
    const float* W = a.W[blockIdx.z];
    f16* WT = a.WT[blockIdx.z];
    int n0 = blockIdx.x * 32, k0 = blockIdx.y * 32;
    int tx = threadIdx.x, ty = threadIdx.y; // 32 x 8
#pragma unroll
    for (int j = 0; j < 4; ++j)
        t[ty + 8 * j][tx] = W[(k0 + ty + 8 * j) * DIM + n0 + tx];
    __syncthreads();
#pragma unroll
    for (int j = 0; j < 4; ++j)
        WT[(n0 + ty + 8 * j) * DIM + k0 + tx] = (f16)t[tx][ty + 8 * j];
}

// ---------------- prep: pack MLP param tables + exact-erf gelu LUT ----------------
// gtab[8192]: x = (i+0.5)/512 - 8, gelu_exact(x) as f16
__global__ void k_pack3(const float* __restrict__ W1, const float* __restrict__ b1,
                        const float* __restrict__ W2, f16* __restrict__ W1tab,
                        f16* __restrict__ W2tab, f16* __restrict__ gtab) {
    int i = blockIdx.x * 256 + threadIdx.x;
    if (i < 3072) {
        int lane = i & 63;
        int hi = lane >> 4, m = lane & 15;
        int u = (i >> 6) * 16 + m;
#pragma unroll
        for (int e = 0; e < 8; ++e) {
            float v = 0.f;
            if (hi == 0) {
                if (e < 6) v = W1[e * DIM + u];
                else if (e == 6) v = b1[u];
            }
            W1tab[i * 8 + e] = (f16)v;
        }
    } else if (i < 4608) {
        int i2 = i - 3072;
        int j = i2 >> 6, lane = i2 & 63;
        int g = lane >> 4, h = lane & 15;
#pragma unroll
        for (int e = 0; e < 8; ++e) {
            int u = 32 * j + ((e >> 2) << 4) + (g << 2) + (e & 3);
            float v = (h < 12) ? W2[u * 12 + h] : 0.f;
            W2tab[i2 * 8 + e] = (f16)v;
        }
    } else if (i < 12800) {
        int i2 = i - 4608;
        float x = (i2 + 0.5f) * (1.0f / 512.0f) - 8.0f;
        gtab[i2] = (f16)(0.5f * x * (1.0f + erff(x * 0.70710678f)));
    }
}

// ---------------- pairwise bias MLP (MFMA + LDS gelu LUT), f16 output ----------------
__global__ void __launch_bounds__(256) k_mlp6(const float* __restrict__ qc, const float* __restrict__ kc,
                                              const f16x8* __restrict__ W1tab,   // [48][64]
                                              const f16x8* __restrict__ W2tab,   // [24][64]
                                              const float* __restrict__ b2,
                                              const f16* __restrict__ gtab,
                                              f16* __restrict__ bias16) {
    __shared__ f16 tab[8192];   // 16 KB
    int t = threadIdx.x, lane = t & 63, w = t >> 6;
    {
        const uint4* gt = (const uint4*)gtab;
        uint4* st = (uint4*)tab;
#pragma unroll
        for (int i = 0; i < 4; ++i) st[i * 256 + t] = gt[i * 256 + t];
    }
    int hi = lane >> 4, m = lane & 15;
    int p0 = blockIdx.x * 64 + w * 16;
    int pair = p0 + m;
    int qi = pair >> 9, ki = pair & 511;
    float dx = qc[2 * qi] - kc[2 * ki];
    float dy = qc[2 * qi + 1] - kc[2 * ki + 1];

    union { f16x8 v; pk16 h2[4]; } rf;
    { f16x8 z = {}; rf.v = z; }
    if (hi == 0) {
        rf.h2[0] = __builtin_amdgcn_cvt_pkrtz(dx, dy);
        rf.h2[1] = __builtin_amdgcn_cvt_pkrtz(fabsf(dx), fabsf(dy));
        rf.h2[2] = __builtin_amdgcn_cvt_pkrtz(dx * dx, dy * dy);
        rf.h2[3] = __builtin_amdgcn_cvt_pkrtz(1.0f, 0.0f);
    }

    float b2h = (m < 12) ? b2[m] : 0.f;
    f32x4 acc = {b2h, b2h, b2h, b2h};
    const f32x4 zero = {};
    const f16x8* w1p = W1tab + lane;
    const f16x8* w2p = W2tab + lane;
    __syncthreads();

#pragma unroll 2
    for (int j = 0; j < 24; ++j) {
        f16x8 a0  = w1p[(2 * j) * 64];
        f16x8 a1  = w1p[(2 * j + 1) * 64];
        f16x8 w2v = w2p[j * 64];
        f32x4 pre0 = MFMA16H(a0, rf.v, zero, 0, 0, 0);
        f32x4 pre1 = MFMA16H(a1, rf.v, zero, 0, 0, 0);
        union { f16x8 v; f16 e[8]; } pa;
#pragma unroll
        for (int e = 0; e < 4; ++e) {
            float x0 = pre0[e];
            float xi0 = __builtin_amdgcn_fmed3f(__builtin_fmaf(x0, 512.f, 4096.f), 0.f, 8191.f);
            f16 g0 = tab[(int)xi0];
            pa.e[e] = (x0 > 8.f) ? (f16)x0 : g0;
            float x1 = pre1[e];
            float xi1 = __builtin_amdgcn_fmed3f(__builtin_fmaf(x1, 512.f, 4096.f), 0.f, 8191.f);
            f16 g1 = tab[(int)xi1];
            pa.e[4 + e] = (x1 > 8.f) ? (f16)x1 : g1;
        }
        acc = MFMA16H(pa.v, w2v, acc, 0, 0, 0);
    }
    if (m < 12) {
        union { pk16 h[2]; uint2 u2; } o;
        o.h[0] = __builtin_amdgcn_cvt_pkrtz(acc[0], acc[1]);
        o.h[1] = __builtin_amdgcn_cvt_pkrtz(acc[2], acc[3]);
        *reinterpret_cast<uint2*>(bias16 + m * (SEQ * SEQ) + p0 + hi * 4) = o.u2;
    }
}

// ---------------- LDS-staged QKV GEMM: 128x128, BK=32, dbuf, single barrier/iter ----------------
struct GArgs { const f16* X; const f16* W; const float* bias; f16* out; };
struct G3 { GArgs a[3]; };

__global__ void __launch_bounds__(256) k_gemm3(G3 args) {
    __shared__ uint4 lds[2048];
    int z = blockIdx.z;
    GArgs ga = args.a[z];
    int m0 = blockIdx.x * 128, n0 = blockIdx.y * 128;
    int t = threadIdx.x, lane = t & 63, w = t >> 6;
    int wr = w >> 1, wc = w & 1;
    int lm = lane & 15, hi = lane >> 4;

    int srow = t >> 1, sch = t & 1;
    const f16* Ag = ga.X + (m0 + srow) * DIM + sch * 16;
    const f16* Bg = ga.W + (n0 + srow) * DIM + sch * 16;
    int sw = (srow >> 1) & 3;
    int wiA0 = srow * 4 + ((2 * sch) ^ sw);
    int wiA1 = srow * 4 + ((2 * sch + 1) ^ sw);

    int aidx[4], bidx[4];
#pragma unroll
    for (int i = 0; i < 4; ++i) {
        int ar = wr * 64 + i * 16 + lm;
        aidx[i] = ar * 4 + (hi ^ ((ar >> 1) & 3));
        int br = wc * 64 + i * 16 + lm;
        bidx[i] = 512 + br * 4 + (hi ^ ((br >> 1) & 3));
    }

    f32x4 acc[4][4] = {};
    {
        uint4 a0 = *(const uint4*)(Ag);
        uint4 a1 = *(const uint4*)(Ag + 8);
        uint4 b0 = *(const uint4*)(Bg);
        uint4 b1 = *(const uint4*)(Bg + 8);
        lds[wiA0] = a0; lds[wiA1] = a1;
        lds[512 + wiA0] = b0; lds[512 + wiA1] = b1;
    }
    __syncthreads();

    for (int kt = 0; kt < 24; ++kt) {
        uint4 na0, na1, nb0, nb1;
        bool pf = kt < 23;
        if (pf) {
            const f16* An = Ag + (kt + 1) * 32;
            const f16* Bn = Bg + (kt + 1) * 32;
            na0 = *(const uint4*)(An);
            na1 = *(const uint4*)(An + 8);
            nb0 = *(const uint4*)(Bn);
            nb1 = *(const uint4*)(Bn + 8);
        }
        int bo = (kt & 1) << 10;
        f16x8 af[4], bf[4];
#pragma unroll
        for (int i = 0; i < 4; ++i) {
            af[i] = *(const f16x8*)&lds[bo + aidx[i]];
            bf[i] = *(const f16x8*)&lds[bo + bidx[i]];
        }
#pragma unroll
        for (int mi = 0; mi < 4; ++mi)
#pragma unroll
            for (int ni = 0; ni < 4; ++ni)
                acc[mi][ni] = MFMA16H(af[mi], bf[ni], acc[mi][ni], 0, 0, 0);
        if (pf) {
            // write OTHER buffer (disjoint from this iter's reads) -> one barrier suffices
            int bo2 = bo ^ 1024;
            lds[bo2 + wiA0] = na0; lds[bo2 + wiA1] = na1;
            lds[bo2 + 512 + wiA0] = nb0; lds[bo2 + 512 + wiA1] = nb1;
            __syncthreads();
        }
    }

#pragma unroll
    for (int mi = 0; mi < 4; ++mi)
#pragma unroll
        for (int ni = 0; ni < 4; ++ni) {
            int n = n0 + wc * 64 + ni * 16 + lm;
            float bn = ga.bias[n];
            int h = n >> 6, d = n & 63;
            int mbase = m0 + wr * 64 + mi * 16 + hi * 4;
            int bb = mbase >> 9, l0 = mbase & 511;
            if (z == 2) {
                union { pk16 h2[2]; uint2 u2; } o;
                o.h2[0] = __builtin_amdgcn_cvt_pkrtz(acc[mi][ni][0] + bn, acc[mi][ni][1] + bn);
                o.h2[1] = __builtin_amdgcn_cvt_pkrtz(acc[mi][ni][2] + bn, acc[mi][ni][3] + bn);
                *reinterpret_cast<uint2*>(ga.out + (((bb * NH + h) * HD) + d) * SEQ + l0) = o.u2;
            } else {
#pragma unroll
                for (int r = 0; r < 4; ++r)
                    ga.out[(((bb * NH + h) * SEQ) + l0 + r) * HD + d] = (f16)(acc[mi][ni][r] + bn);
            }
        }
}

// ---------------- O-proj GEMM: 128x128 tile, f32 out, single barrier/iter ----------------
__global__ void __launch_bounds__(256) k_gemmO(const f16* __restrict__ X,
                                               const f16* __restrict__ WT,
                                               const float* __restrict__ bias,
                                               float* __restrict__ out) {
    __shared__ uint4 lds[2048];
    int m0 = blockIdx.x * 128, n0 = blockIdx.y * 128;
    int t = threadIdx.x, lane = t & 63, w = t >> 6;
    int wr = w >> 1, wc = w & 1;
    int lm = lane & 15, hi = lane >> 4;

    int srow = t >> 1, sch = t & 1;
    const f16* Ag = X + (m0 + srow) * DIM + sch * 16;
    const f16* Bg = WT + (n0 + srow) * DIM + sch * 16;
    int sw = (srow >> 1) & 3;
    int wiA0 = srow * 4 + ((2 * sch) ^ sw);
    int wiA1 = srow * 4 + ((2 * sch + 1) ^ sw);

    int aidx[4], bidx[4];
#pragma unroll
    for (int i = 0; i < 4; ++i) {
        int ar = wr * 64 + i * 16 + lm;
        aidx[i] = ar * 4 + (hi ^ ((ar >> 1) & 3));
        int br = wc * 64 + i * 16 + lm;
        bidx[i] = 512 + br * 4 + (hi ^ ((br >> 1) & 3));
    }

    f32x4 acc[4][4] = {};
    {
        uint4 a0 = *(const uint4*)(Ag);
        uint4 a1 = *(const uint4*)(Ag + 8);
        uint4 b0 = *(const uint4*)(Bg);
        uint4 b1 = *(const uint4*)(Bg + 8);
        lds[wiA0] = a0; lds[wiA1] = a1;
        lds[512 + wiA0] = b0; lds[512 + wiA1] = b1;
    }
    __syncthreads();

    for (int kt = 0; kt < 24; ++kt) {
        uint4 na0, na1, nb0, nb1;
        bool pf = kt < 23;
        if (pf) {
            const f16* An = Ag + (kt + 1) * 32;
            const f16* Bn = Bg + (kt + 1) * 32;
            na0 = *(const uint4*)(An);
            na1 = *(const uint4*)(An + 8);
            nb0 = *(const uint4*)(Bn);
            nb1 = *(const uint4*)(Bn + 8);
        }
        int bo = (kt & 1) << 10;
        f16x8 af[4], bf[4];
#pragma unroll
        for (int i = 0; i < 4; ++i) {
            af[i] = *(const f16x8*)&lds[bo + aidx[i]];
            bf[i] = *(const f16x8*)&lds[bo + bidx[i]];
        }
#pragma unroll
        for (int mi = 0; mi < 4; ++mi)
#pragma unroll
            for (int ni = 0; ni < 4; ++ni)
                acc[mi][ni] = MFMA16H(af[mi], bf[ni], acc[mi][ni], 0, 0, 0);
        if (pf) {
            int bo2 = bo ^ 1024;
            lds[bo2 + wiA0] = na0; lds[bo2 + wiA1] = na1;
            lds[bo2 + 512 + wiA0] = nb0; lds[bo2 + 512 + wiA1] = nb1;
            __syncthreads();
        }
    }

#pragma unroll
    for (int mi = 0; mi < 4; ++mi)
#pragma unroll
        for (int ni = 0; ni < 4; ++ni) {
            int n = n0 + wc * 64 + ni * 16 + lm;
            float bn = bias[n];
#pragma unroll
            for (int r = 0; r < 4; ++r) {
                int m = m0 + wr * 64 + mi * 16 + hi * 4 + r;
                out[m * DIM + n] = acc[mi][ni][r] + bn;
            }
        }
}

// ---------------- attention: per (qtile32, h, b), f16 logits LDS ----------------
__global__ void __launch_bounds__(256) k_attn4(const f16* __restrict__ q_ws,
                                               const f16* __restrict__ k_ws,
                                               const f16* __restrict__ v_t,
                                               const f16* __restrict__ bias16,
                                               f16* __restrict__ attn_out) {
    __shared__ __align__(16) unsigned short sm16[32 * 520];  // f16 logits [32][520]
    __shared__ float inv32[32];
    int qt = blockIdx.x, h = blockIdx.y, b = blockIdx.z;
    int q0 = qt * 32;
    int t = threadIdx.x, lane = t & 63, w = t >> 6;
    int lrow = lane & 15, hi = lane >> 4;
    int bh = b * NH + h;
    const f16* Q = q_ws + (bh * SEQ + q0) * HD;
    const f16* K = k_ws + bh * SEQ * HD;
    const f16* Bias = bias16 + (h * SEQ + q0) * SEQ;

    f16x8 aq[2][2];
#pragma unroll
    for (int rt = 0; rt < 2; ++rt)
#pragma unroll
        for (int ds = 0; ds < 2; ++ds) {
            f16x8 v = *(const f16x8*)(Q + (rt * 16 + lrow) * HD + ds * 32 + hi * 8);
            aq[rt][ds] = v * (f16)SCALE;   // exact (pow2)
        }

#pragma unroll
    for (int ct = 0; ct < 8; ++ct) {
        f32x4 acc0 = {}, acc1 = {};
        int kk = w * 128 + ct * 16 + lrow;
#pragma unroll
        for (int ds = 0; ds < 2; ++ds) {
            f16x8 bk = *(const f16x8*)(K + kk * HD + ds * 32 + hi * 8);
            acc0 = MFMA16H(aq[0][ds], bk, acc0, 0, 0, 0);
            acc1 = MFMA16H(aq[1][ds], bk, acc1, 0, 0, 0);
        }
#pragma unroll
        for (int r = 0; r < 4; ++r) {
            int row0 = hi * 4 + r;
            sm16[row0 * 520 + kk] = (unsigned short)__builtin_bit_cast(unsigned short,
                (f16)(acc0[r] + (float)Bias[row0 * SEQ + kk]));
            int row1 = 16 + hi * 4 + r;
            sm16[row1 * 520 + kk] = (unsigned short)__builtin_bit_cast(unsigned short,
                (f16)(acc1[r] + (float)Bias[row1 * SEQ + kk]));
        }
    }
    __syncthreads();

    {
        int row = t >> 3, seg = t & 7;
        int base = row * 520 + 2 * seg;
        float mx = -1e30f;
#pragma unroll 8
        for (int j = 0; j < 32; ++j) {
            union { uint u; f16 h[2]; } cv;
            cv.u = *(const uint*)&sm16[base + 16 * j];
            mx = fmaxf(mx, fmaxf((float)cv.h[0], (float)cv.h[1]));
        }
        mx = fmaxf(mx, __shfl_xor(mx, 1));
        mx = fmaxf(mx, __shfl_xor(mx, 2));
        mx = fmaxf(mx, __shfl_xor(mx, 4));
        float s = 0.f;
#pragma unroll 8
        for (int j = 0; j < 32; ++j) {
            union { uint u; f16 h[2]; } cv;
            cv.u = *(const uint*)&sm16[base + 16 * j];
            float p0 = __builtin_amdgcn_exp2f(((float)cv.h[0] - mx) * 1.442695041f);
            float p1 = __builtin_amdgcn_exp2f(((float)cv.h[1] - mx) * 1.442695041f);
            s += p0 + p1;
            union { pk16 h; uint u; } o;
            o.h = __builtin_amdgcn_cvt_pkrtz(p0, p1);
            *(uint*)&sm16[base + 16 * j] = o.u;
        }
        s += __shfl_xor(s, 1);
        s += __shfl_xor(s, 2);
        s += __shfl_xor(s, 4);
        if (seg == 0) inv32[row] = 1.0f / s;
    }
    __syncthreads();

    const f16* Vt = v_t + bh * HD * SEQ + (w * 16 + lrow) * SEQ;
    f32x4 oacc0 = {}, oacc1 = {};
    for (int kt = 0; kt < 16; ++kt) {
        f16x8 bv = *(const f16x8*)(Vt + kt * 32 + hi * 8);
        f16x8 pa0 = *(const f16x8*)&sm16[lrow * 520 + kt * 32 + hi * 8];
        f16x8 pa1 = *(const f16x8*)&sm16[(16 + lrow) * 520 + kt * 32 + hi * 8];
        oacc0 = MFMA16H(pa0, bv, oacc0, 0, 0, 0);
        oacc1 = MFMA16H(pa1, bv, oacc1, 0, 0, 0);
    }
#pragma unroll
    for (int r = 0; r < 4; ++r) {
        int row0 = hi * 4 + r;
        float v0 = oacc0[r] * inv32[row0];
        attn_out[(b * SEQ + q0 + row0) * DIM + h * HD + w * 16 + lrow] = (f16)v0;
        int row1 = 16 + hi * 4 + r;
        float v1 = oacc1[r] * inv32[row1];
        attn_out[(b * SEQ + q0 + row1) * DIM + h * HD + w * 16 + lrow] = (f16)v1;
    }
}

extern "C" void kernel_launch(void* const* d_in, const int* in_sizes, int n_in,
                              void* d_out, int out_size, void* d_ws, size_t ws_size,
                              hipStream_t stream) {
    const float* query     = (const float*)d_in[0];
    const float* key_value = (const float*)d_in[1];
    const float* qc        = (const float*)d_in[2];
    const float* kc        = (const float*)d_in[3];
    const float* Wq        = (const float*)d_in[4];
    const float* bq        = (const float*)d_in[5];
    const float* Wk        = (const float*)d_in[6];
    const float* bk        = (const float*)d_in[7];
    const float* Wv        = (const float*)d_in[8];
    const float* bv        = (const float*)d_in[9];
    const float* Wo        = (const float*)d_in[10];
    const float* bo        = (const float*)d_in[11];
    const float* W1        = (const float*)d_in[12];
    const float* b1        = (const float*)d_in[13];
    const float* W2        = (const float*)d_in[14];
    const float* b2        = (const float*)d_in[15];

    char* ws = (char*)d_ws;
    f16* Xq   = (f16*)(ws + 0);          // reused as attn_out
    f16* Xkv  = (f16*)(ws + 6291456);
    f16* WqT  = (f16*)(ws + 12582912);
    f16* WkT  = (f16*)(ws + 13762560);
    f16* WvT  = (f16*)(ws + 14942208);
    f16* WoT  = (f16*)(ws + 16121856);
    f16* q_ws = (f16*)(ws + 17301504);
    f16* k_ws = (f16*)(ws + 23592960);
    f16* v_t  = (f16*)(ws + 29884416);   // V written directly transposed [b,h,d,l]
    f16* bias16 = (f16*)(ws + 36175872); // 6291456 B
    f16* W1tab  = (f16*)(ws + 42467328);
    f16* W2tab  = (f16*)(ws + 42516480);
    f16* gtab   = (f16*)(ws + 42541056); // 16384 B
    f16* attn_out = Xq;   // Xq dead after Q projection

    k_cvt16<<<dim3(1536, 2), dim3(256), 0, stream>>>(query, Xq, key_value, Xkv);
    W4 w4 = {{Wq, Wk, Wv, Wo}, {WqT, WkT, WvT, WoT}};
    k_wt4<<<dim3(24, 24, 4), dim3(32, 8), 0, stream>>>(w4);
    k_pack3<<<dim3(50), dim3(256), 0, stream>>>(W1, b1, W2, W1tab, W2tab, gtab);
    k_mlp6<<<dim3(4096), dim3(256), 0, stream>>>(qc, kc, (const f16x8*)W1tab, (const f16x8*)W2tab, b2, gtab, bias16);

    G3 qkv;
    qkv.a[0] = {Xq,  WqT, bq, q_ws};
    qkv.a[1] = {Xkv, WkT, bk, k_ws};
    qkv.a[2] = {Xkv, WvT, bv, v_t};
    k_gemm3<<<dim3(32, 6, 3), dim3(256), 0, stream>>>(qkv);

    k_attn4<<<dim3(16, NH, NB), dim3(256), 0, stream>>>(q_ws, k_ws, v_t, bias16, attn_out);
    k_gemmO<<<dim3(32, 6), dim3(256), 0, stream>>>(attn_out, WoT, bo, (float*)d_out);
}

// Round 9
// 136.209 us; speedup vs baseline: 1.9617x; 1.1196x over previous
//
#include <hip/hip_runtime.h>
#include <hip/hip_bf16.h>
#include <stdint.h>
#include <math.h>

typedef __attribute__((ext_vector_type(4))) float f32x4;
typedef _Float16 f16;
typedef __attribute__((ext_vector_type(8))) _Float16 f16x8;
typedef decltype(__builtin_amdgcn_cvt_pkrtz(0.f, 0.f)) pk16;

#define DIM   768
#define NH    12
#define HD    64
#define NB    8
#define SEQ   512
#define SCALE 0.125f

#define MFMA16H __builtin_amdgcn_mfma_f32_16x16x32_f16

// ---------------- prep (fused): f32->f16 converts + 4x W transpose + MLP tables ----------------
struct PrepArgs {
    const float* query; const float* key_value; f16* Xq; f16* Xkv;
    const float* W[4]; f16* WT[4];
    const float* W1; const float* b1; const float* W2;
    f16* W1tab; f16* W2tab; float* gtab32;
};

__global__ void __launch_bounds__(256) k_prep(PrepArgs pa) {
    __shared__ float tt[32][33];
    int g = blockIdx.x, t = threadIdx.x;
    if (g < 3072) {
        const float* in = (g < 1536) ? pa.query : pa.key_value;
        f16* out = (g < 1536) ? pa.Xq : pa.Xkv;
        int i = (g % 1536) * 256 + t;
        const float4* s = reinterpret_cast<const float4*>(in + i * 8);
        float4 f0 = s[0], f1 = s[1];
        union { pk16 h[4]; uint4 v; } o;
        o.h[0] = __builtin_amdgcn_cvt_pkrtz(f0.x, f0.y);
        o.h[1] = __builtin_amdgcn_cvt_pkrtz(f0.z, f0.w);
        o.h[2] = __builtin_amdgcn_cvt_pkrtz(f1.x, f1.y);
        o.h[3] = __builtin_amdgcn_cvt_pkrtz(f1.z, f1.w);
        reinterpret_cast<uint4*>(out)[i] = o.v;
    } else if (g < 5376) {
        int bi = g - 3072;               // 0..2303
        int z = bi / 576, rem = bi % 576;
        int bx = rem % 24, by = rem / 24;
        const float* W = pa.W[z];
        f16* WT = pa.WT[z];
        int n0 = bx * 32, k0 = by * 32;
        int tx = t & 31, ty = t >> 5;    // 32 x 8
#pragma unroll
        for (int j = 0; j < 4; ++j)
            tt[ty + 8 * j][tx] = W[(k0 + ty + 8 * j) * DIM + n0 + tx];
        __syncthreads();
#pragma unroll
        for (int j = 0; j < 4; ++j)
            WT[(n0 + ty + 8 * j) * DIM + k0 + tx] = (f16)tt[tx][ty + 8 * j];
    } else {
        int i = (g - 5376) * 256 + t;    // 0..8703
        if (i < 3072) {
            int lane = i & 63;
            int hi = lane >> 4, m = lane & 15;
            int u = (i >> 6) * 16 + m;
#pragma unroll
            for (int e = 0; e < 8; ++e) {
                float v = 0.f;
                if (hi == 0) {
                    if (e < 6) v = pa.W1[e * DIM + u];
                    else if (e == 6) v = pa.b1[u];
                }
                pa.W1tab[i * 8 + e] = (f16)v;
            }
        } else if (i < 4608) {
            int i2 = i - 3072;
            int j = i2 >> 6, lane = i2 & 63;
            int gq = lane >> 4, h = lane & 15;
#pragma unroll
            for (int e = 0; e < 8; ++e) {
                int u = 32 * j + ((e >> 2) << 4) + (gq << 2) + (e & 3);
                float v = (h < 12) ? pa.W2[u * 12 + h] : 0.f;
                pa.W2tab[i2 * 8 + e] = (f16)v;
            }
        } else {
            int i2 = i - 4608;           // 0..4095
            float x = (i2 + 0.5f) * (1.0f / 256.0f) - 8.0f;
            pa.gtab32[i2] = 0.5f * x * (1.0f + erff(x * 0.70710678f));
        }
    }
}

// ---------------- fused MLP + QKV GEMM (matched 16KB LDS footprint) ----------------
struct MQArgs {
    const float* qc; const float* kc;
    const f16x8* W1tab; const f16x8* W2tab; const float* b2; f16* bias16;
    const float* gtab32;
    const f16* Xq; const f16* Xkv;
    const f16* WqT; const f16* WkT; const f16* WvT;
    const float* bq; const float* bk; const float* bv;
    f16* q_ws; f16* k_ws; f16* v_t;
};

__global__ void __launch_bounds__(256) k_mq(MQArgs a) {
    __shared__ uint4 lds[1024];   // 16 KB: GEMM dbuf OR MLP gelu LUT
    int g = blockIdx.x, t = threadIdx.x;
    int lane = t & 63, w = t >> 6;
    int hi = lane >> 4, lm = lane & 15;
    int r25 = g % 25, q25 = g / 25;

    if (r25 < 9) {
        // ---------- GEMM role: 64x64 tile, BK=32, double-buffered ----------
        int id = q25 * 9 + r25;          // 0..2303
        int z = id / 768, rem = id % 768;
        int m0 = (rem & 63) * 64, n0 = (rem >> 6) * 64;
        const f16* X = (z == 0) ? a.Xq : a.Xkv;
        const f16* Wt = (z == 0) ? a.WqT : (z == 1) ? a.WkT : a.WvT;
        const float* bias = (z == 0) ? a.bq : (z == 1) ? a.bk : a.bv;
        f16* out = (z == 0) ? a.q_ws : (z == 1) ? a.k_ws : a.v_t;

        int wr = w >> 1, wc = w & 1;
        int srow = t >> 2, sslot = t & 3;      // 64 rows x 4 uint4-slots
        const f16* Ag = X + (m0 + srow) * DIM + sslot * 8;
        const f16* Bg = Wt + (n0 + srow) * DIM + sslot * 8;
        int wi = srow * 4 + (sslot ^ ((srow >> 1) & 3));

        int aidx[2], bidx[2];
#pragma unroll
        for (int i = 0; i < 2; ++i) {
            int ar = wr * 32 + i * 16 + lm;
            aidx[i] = ar * 4 + (hi ^ ((ar >> 1) & 3));
            int br = wc * 32 + i * 16 + lm;
            bidx[i] = 256 + br * 4 + (hi ^ ((br >> 1) & 3));
        }

        f32x4 acc[2][2] = {};
        lds[wi] = *(const uint4*)(Ag);
        lds[256 + wi] = *(const uint4*)(Bg);
        __syncthreads();

        for (int kt = 0; kt < 24; ++kt) {
            uint4 na, nb;
            bool pf = kt < 23;
            if (pf) {
                na = *(const uint4*)(Ag + (kt + 1) * 32);
                nb = *(const uint4*)(Bg + (kt + 1) * 32);
            }
            int bo = (kt & 1) << 9;
            f16x8 af[2], bf[2];
#pragma unroll
            for (int i = 0; i < 2; ++i) {
                af[i] = *(const f16x8*)&lds[bo + aidx[i]];
                bf[i] = *(const f16x8*)&lds[bo + bidx[i]];
            }
#pragma unroll
            for (int mi = 0; mi < 2; ++mi)
#pragma unroll
                for (int ni = 0; ni < 2; ++ni)
                    acc[mi][ni] = MFMA16H(af[mi], bf[ni], acc[mi][ni], 0, 0, 0);
            if (pf) {
                int bo2 = bo ^ 512;
                lds[bo2 + wi] = na;
                lds[bo2 + 256 + wi] = nb;
                __syncthreads();
            }
        }

#pragma unroll
        for (int mi = 0; mi < 2; ++mi)
#pragma unroll
            for (int ni = 0; ni < 2; ++ni) {
                int n = n0 + wc * 32 + ni * 16 + lm;
                float bn = bias[n];
                int h = n >> 6, d = n & 63;
                int mbase = m0 + wr * 32 + mi * 16 + hi * 4;
                int bb = mbase >> 9, l0 = mbase & 511;
                if (z == 2) {
                    union { pk16 h2[2]; uint2 u2; } o;
                    o.h2[0] = __builtin_amdgcn_cvt_pkrtz(acc[mi][ni][0] + bn, acc[mi][ni][1] + bn);
                    o.h2[1] = __builtin_amdgcn_cvt_pkrtz(acc[mi][ni][2] + bn, acc[mi][ni][3] + bn);
                    *reinterpret_cast<uint2*>(out + (((bb * NH + h) * HD) + d) * SEQ + l0) = o.u2;
                } else {
#pragma unroll
                    for (int r = 0; r < 4; ++r)
                        out[(((bb * NH + h) * SEQ) + l0 + r) * HD + d] = (f16)(acc[mi][ni][r] + bn);
                }
            }
    } else {
        // ---------- MLP role: MFMA + f32 gelu LUT ----------
        int id = q25 * 16 + (r25 - 9);   // 0..4095
        float* tab = (float*)lds;
        {
            const uint4* gt = (const uint4*)a.gtab32;
#pragma unroll
            for (int i = 0; i < 4; ++i) lds[i * 256 + t] = gt[i * 256 + t];
        }
        int p0 = id * 64 + w * 16;
        int pair = p0 + lm;
        int qi = pair >> 9, ki = pair & 511;
        float dx = a.qc[2 * qi] - a.kc[2 * ki];
        float dy = a.qc[2 * qi + 1] - a.kc[2 * ki + 1];

        union { f16x8 v; pk16 h2[4]; } rf;
        { f16x8 zz = {}; rf.v = zz; }
        if (hi == 0) {
            rf.h2[0] = __builtin_amdgcn_cvt_pkrtz(dx, dy);
            rf.h2[1] = __builtin_amdgcn_cvt_pkrtz(fabsf(dx), fabsf(dy));
            rf.h2[2] = __builtin_amdgcn_cvt_pkrtz(dx * dx, dy * dy);
            rf.h2[3] = __builtin_amdgcn_cvt_pkrtz(1.0f, 0.0f);
        }

        float b2h = (lm < 12) ? a.b2[lm] : 0.f;
        f32x4 acc = {b2h, b2h, b2h, b2h};
        const f32x4 zero = {};
        const f16x8* w1p = a.W1tab + lane;
        const f16x8* w2p = a.W2tab + lane;
        __syncthreads();

#pragma unroll 2
        for (int j = 0; j < 24; ++j) {
            f16x8 a0  = w1p[(2 * j) * 64];
            f16x8 a1  = w1p[(2 * j + 1) * 64];
            f16x8 w2v = w2p[j * 64];
            f32x4 pre0 = MFMA16H(a0, rf.v, zero, 0, 0, 0);
            f32x4 pre1 = MFMA16H(a1, rf.v, zero, 0, 0, 0);
            float s0[4], s1[4];
#pragma unroll
            for (int e = 0; e < 4; ++e) {
                float x0 = pre0[e];
                float xi0 = __builtin_amdgcn_fmed3f(__builtin_fmaf(x0, 256.f, 2048.f), 0.f, 4095.f);
                float g0 = tab[(int)xi0];
                s0[e] = (x0 > 8.f) ? x0 : g0;
                float x1 = pre1[e];
                float xi1 = __builtin_amdgcn_fmed3f(__builtin_fmaf(x1, 256.f, 2048.f), 0.f, 4095.f);
                float g1 = tab[(int)xi1];
                s1[e] = (x1 > 8.f) ? x1 : g1;
            }
            union { f16x8 v; pk16 h2[4]; } pav;
            pav.h2[0] = __builtin_amdgcn_cvt_pkrtz(s0[0], s0[1]);
            pav.h2[1] = __builtin_amdgcn_cvt_pkrtz(s0[2], s0[3]);
            pav.h2[2] = __builtin_amdgcn_cvt_pkrtz(s1[0], s1[1]);
            pav.h2[3] = __builtin_amdgcn_cvt_pkrtz(s1[2], s1[3]);
            acc = MFMA16H(pav.v, w2v, acc, 0, 0, 0);
        }
        if (lm < 12) {
            union { pk16 h[2]; uint2 u2; } o;
            o.h[0] = __builtin_amdgcn_cvt_pkrtz(acc[0], acc[1]);
            o.h[1] = __builtin_amdgcn_cvt_pkrtz(acc[2], acc[3]);
            *reinterpret_cast<uint2*>(a.bias16 + lm * (SEQ * SEQ) + p0 + hi * 4) = o.u2;
        }
    }
}

// ---------------- O-proj GEMM: 128x128 tile, f32 out, single barrier/iter ----------------
__global__ void __launch_bounds__(256) k_gemmO(const f16* __restrict__ X,
                                               const f16* __restrict__ WT,
                                               const float* __restrict__ bias,
                                               float* __restrict__ out) {
    __shared__ uint4 lds[2048];
    int m0 = blockIdx.x * 128, n0 = blockIdx.y * 128;
    int t = threadIdx.x, lane = t & 63, w = t >> 6;
    int wr = w >> 1, wc = w & 1;
    int lm = lane & 15, hi = lane >> 4;

    int srow = t >> 1, sch = t & 1;
    const f16* Ag = X + (m0 + srow) * DIM + sch * 16;
    const f16* Bg = WT + (n0 + srow) * DIM + sch * 16;
    int sw = (srow >> 1) & 3;
    int wiA0 = srow * 4 + ((2 * sch) ^ sw);
    int wiA1 = srow * 4 + ((2 * sch + 1) ^ sw);

    int aidx[4], bidx[4];
#pragma unroll
    for (int i = 0; i < 4; ++i) {
        int ar = wr * 64 + i * 16 + lm;
        aidx[i] = ar * 4 + (hi ^ ((ar >> 1) & 3));
        int br = wc * 64 + i * 16 + lm;
        bidx[i] = 512 + br * 4 + (hi ^ ((br >> 1) & 3));
    }

    f32x4 acc[4][4] = {};
    {
        uint4 a0 = *(const uint4*)(Ag);
        uint4 a1 = *(const uint4*)(Ag + 8);
        uint4 b0 = *(const uint4*)(Bg);
        uint4 b1 = *(const uint4*)(Bg + 8);
        lds[wiA0] = a0; lds[wiA1] = a1;
        lds[512 + wiA0] = b0; lds[512 + wiA1] = b1;
    }
    __syncthreads();

    for (int kt = 0; kt < 24; ++kt) {
        uint4 na0, na1, nb0, nb1;
        bool pf = kt < 23;
        if (pf) {
            const f16* An = Ag + (kt + 1) * 32;
            const f16* Bn = Bg + (kt + 1) * 32;
            na0 = *(const uint4*)(An);
            na1 = *(const uint4*)(An + 8);
            nb0 = *(const uint4*)(Bn);
            nb1 = *(const uint4*)(Bn + 8);
        }
        int bo = (kt & 1) << 10;
        f16x8 af[4], bf[4];
#pragma unroll
        for (int i = 0; i < 4; ++i) {
            af[i] = *(const f16x8*)&lds[bo + aidx[i]];
            bf[i] = *(const f16x8*)&lds[bo + bidx[i]];
        }
#pragma unroll
        for (int mi = 0; mi < 4; ++mi)
#pragma unroll
            for (int ni = 0; ni < 4; ++ni)
                acc[mi][ni] = MFMA16H(af[mi], bf[ni], acc[mi][ni], 0, 0, 0);
        if (pf) {
            int bo2 = bo ^ 1024;
            lds[bo2 + wiA0] = na0; lds[bo2 + wiA1] = na1;
            lds[bo2 + 512 + wiA0] = nb0; lds[bo2 + 512 + wiA1] = nb1;
            __syncthreads();
        }
    }

#pragma unroll
    for (int mi = 0; mi < 4; ++mi)
#pragma unroll
        for (int ni = 0; ni < 4; ++ni) {
            int n = n0 + wc * 64 + ni * 16 + lm;
            float bn = bias[n];
#pragma unroll
            for (int r = 0; r < 4; ++r) {
                int m = m0 + wr * 64 + mi * 16 + hi * 4 + r;
                out[m * DIM + n] = acc[mi][ni][r] + bn;
            }
        }
}

// ---------------- attention: per (qtile32, h, b), f16 logits LDS ----------------
__global__ void __launch_bounds__(256) k_attn4(const f16* __restrict__ q_ws,
                                               const f16* __restrict__ k_ws,
                                               const f16* __restrict__ v_t,
                                               const f16* __restrict__ bias16,
                                               f16* __restrict__ attn_out) {
    __shared__ __align__(16) unsigned short sm16[32 * 520];  // f16 logits [32][520]
    __shared__ float inv32[32];
    int qt = blockIdx.x, h = blockIdx.y, b = blockIdx.z;
    int q0 = qt * 32;
    int t = threadIdx.x, lane = t & 63, w = t >> 6;
    int lrow = lane & 15, hi = lane >> 4;
    int bh = b * NH + h;
    const f16* Q = q_ws + (bh * SEQ + q0) * HD;
    const f16* K = k_ws + bh * SEQ * HD;
    const f16* Bias = bias16 + (h * SEQ + q0) * SEQ;

    f16x8 aq[2][2];
#pragma unroll
    for (int rt = 0; rt < 2; ++rt)
#pragma unroll
        for (int ds = 0; ds < 2; ++ds) {
            f16x8 v = *(const f16x8*)(Q + (rt * 16 + lrow) * HD + ds * 32 + hi * 8);
            aq[rt][ds] = v * (f16)SCALE;   // exact (pow2)
        }

#pragma unroll
    for (int ct = 0; ct < 8; ++ct) {
        f32x4 acc0 = {}, acc1 = {};
        int kk = w * 128 + ct * 16 + lrow;
#pragma unroll
        for (int ds = 0; ds < 2; ++ds) {
            f16x8 bk = *(const f16x8*)(K + kk * HD + ds * 32 + hi * 8);
            acc0 = MFMA16H(aq[0][ds], bk, acc0, 0, 0, 0);
            acc1 = MFMA16H(aq[1][ds], bk, acc1, 0, 0, 0);
        }
#pragma unroll
        for (int r = 0; r < 4; ++r) {
            int row0 = hi * 4 + r;
            sm16[row0 * 520 + kk] = (unsigned short)__builtin_bit_cast(unsigned short,
                (f16)(acc0[r] + (float)Bias[row0 * SEQ + kk]));
            int row1 = 16 + hi * 4 + r;
            sm16[row1 * 520 + kk] = (unsigned short)__builtin_bit_cast(unsigned short,
                (f16)(acc1[r] + (float)Bias[row1 * SEQ + kk]));
        }
    }
    __syncthreads();

    {
        int row = t >> 3, seg = t & 7;
        int base = row * 520 + 2 * seg;
        float mx = -1e30f;
#pragma unroll 8
        for (int j = 0; j < 32; ++j) {
            union { uint u; f16 h[2]; } cv;
            cv.u = *(const uint*)&sm16[base + 16 * j];
            mx = fmaxf(mx, fmaxf((float)cv.h[0], (float)cv.h[1]));
        }
        mx = fmaxf(mx, __shfl_xor(mx, 1));
        mx = fmaxf(mx, __shfl_xor(mx, 2));
        mx = fmaxf(mx, __shfl_xor(mx, 4));
        float s = 0.f;
#pragma unroll 8
        for (int j = 0; j < 32; ++j) {
            union { uint u; f16 h[2]; } cv;
            cv.u = *(const uint*)&sm16[base + 16 * j];
            float p0 = __builtin_amdgcn_exp2f(((float)cv.h[0] - mx) * 1.442695041f);
            float p1 = __builtin_amdgcn_exp2f(((float)cv.h[1] - mx) * 1.442695041f);
            s += p0 + p1;
            union { pk16 h; uint u; } o;
            o.h = __builtin_amdgcn_cvt_pkrtz(p0, p1);
            *(uint*)&sm16[base + 16 * j] = o.u;
        }
        s += __shfl_xor(s, 1);
        s += __shfl_xor(s, 2);
        s += __shfl_xor(s, 4);
        if (seg == 0) inv32[row] = 1.0f / s;
    }
    __syncthreads();

    const f16* Vt = v_t + bh * HD * SEQ + (w * 16 + lrow) * SEQ;
    f32x4 oacc0 = {}, oacc1 = {};
    for (int kt = 0; kt < 16; ++kt) {
        f16x8 bv = *(const f16x8*)(Vt + kt * 32 + hi * 8);
        f16x8 pa0 = *(const f16x8*)&sm16[lrow * 520 + kt * 32 + hi * 8];
        f16x8 pa1 = *(const f16x8*)&sm16[(16 + lrow) * 520 + kt * 32 + hi * 8];
        oacc0 = MFMA16H(pa0, bv, oacc0, 0, 0, 0);
        oacc1 = MFMA16H(pa1, bv, oacc1, 0, 0, 0);
    }
#pragma unroll
    for (int r = 0; r < 4; ++r) {
        int row0 = hi * 4 + r;
        float v0 = oacc0[r] * inv32[row0];
        attn_out[(b * SEQ + q0 + row0) * DIM + h * HD + w * 16 + lrow] = (f16)v0;
        int row1 = 16 + hi * 4 + r;
        float v1 = oacc1[r] * inv32[row1];
        attn_out[(b * SEQ + q0 + row1) * DIM + h * HD + w * 16 + lrow] = (f16)v1;
    }
}

extern "C" void kernel_launch(void* const* d_in, const int* in_sizes, int n_in,
                              void* d_out, int out_size, void* d_ws, size_t ws_size,
                              hipStream_t stream) {
    const float* query     = (const float*)d_in[0];
    const float* key_value = (const float*)d_in[1];
    const float* qc        = (const float*)d_in[2];
    const float* kc        = (const float*)d_in[3];
    const float* Wq        = (const float*)d_in[4];
    const float* bq        = (const float*)d_in[5];
    const float* Wk        = (const float*)d_in[6];
    const float* bk        = (const float*)d_in[7];
    const float* Wv        = (const float*)d_in[8];
    const float* bv        = (const float*)d_in[9];
    const float* Wo        = (const float*)d_in[10];
    const float* bo        = (const float*)d_in[11];
    const float* W1        = (const float*)d_in[12];
    const float* b1        = (const float*)d_in[13];
    const float* W2        = (const float*)d_in[14];
    const float* b2        = (const float*)d_in[15];

    char* ws = (char*)d_ws;
    f16* Xq   = (f16*)(ws + 0);          // reused as attn_out
    f16* Xkv  = (f16*)(ws + 6291456);
    f16* WqT  = (f16*)(ws + 12582912);
    f16* WkT  = (f16*)(ws + 13762560);
    f16* WvT  = (f16*)(ws + 14942208);
    f16* WoT  = (f16*)(ws + 16121856);
    f16* q_ws = (f16*)(ws + 17301504);
    f16* k_ws = (f16*)(ws + 23592960);
    f16* v_t  = (f16*)(ws + 29884416);   // V written directly transposed [b,h,d,l]
    f16* bias16  = (f16*)(ws + 36175872); // 6291456 B
    f16* W1tab   = (f16*)(ws + 42467328);
    f16* W2tab   = (f16*)(ws + 42516480);
    float* gtab32 = (float*)(ws + 42541056); // 16384 B
    f16* attn_out = Xq;   // Xq dead after Q projection

    PrepArgs pa;
    pa.query = query; pa.key_value = key_value; pa.Xq = Xq; pa.Xkv = Xkv;
    pa.W[0] = Wq; pa.W[1] = Wk; pa.W[2] = Wv; pa.W[3] = Wo;
    pa.WT[0] = WqT; pa.WT[1] = WkT; pa.WT[2] = WvT; pa.WT[3] = WoT;
    pa.W1 = W1; pa.b1 = b1; pa.W2 = W2;
    pa.W1tab = W1tab; pa.W2tab = W2tab; pa.gtab32 = gtab32;
    k_prep<<<dim3(5410), dim3(256), 0, stream>>>(pa);

    MQArgs mq;
    mq.qc = qc; mq.kc = kc;
    mq.W1tab = (const f16x8*)W1tab; mq.W2tab = (const f16x8*)W2tab;
    mq.b2 = b2; mq.bias16 = bias16; mq.gtab32 = gtab32;
    mq.Xq = Xq; mq.Xkv = Xkv;
    mq.WqT = WqT; mq.WkT = WkT; mq.WvT = WvT;
    mq.bq = bq; mq.bk = bk; mq.bv = bv;
    mq.q_ws = q_ws; mq.k_ws = k_ws; mq.v_t = v_t;
    k_mq<<<dim3(6400), dim3(256), 0, stream>>>(mq);

    k_attn4<<<dim3(16, NH, NB), dim3(256), 0, stream>>>(q_ws, k_ws, v_t, bias16, attn_out);
    k_gemmO<<<dim3(32, 6), dim3(256), 0, stream>>>(attn_out, WoT, bo, (float*)d_out);
}

// Round 10
// 122.181 us; speedup vs baseline: 2.1869x; 1.1148x over previous
//
#include <hip/hip_runtime.h>
#include <hip/hip_bf16.h>
#include <stdint.h>
#include <math.h>

typedef __attribute__((ext_vector_type(4))) float f32x4;
typedef _Float16 f16;
typedef __attribute__((ext_vector_type(8))) _Float16 f16x8;
typedef decltype(__builtin_amdgcn_cvt_pkrtz(0.f, 0.f)) pk16;

#define DIM   768
#define NH    12
#define HD    64
#define NB    8
#define SEQ   512
#define SCALE 0.125f

#define GN    161          // grid points per axis (Δ=1/8 over [-10,10])
#define GPTS  (GN * GN)    // 25921

#define MFMA16H __builtin_amdgcn_mfma_f32_16x16x32_f16

// ---------------- prep (fused): f32->f16 converts + 4x W transpose + MLP tables ----------------
struct PrepArgs {
    const float* query; const float* key_value; f16* Xq; f16* Xkv;
    const float* W[4]; f16* WT[4];
    const float* W1; const float* b1; const float* W2;
    f16* W1tab; f16* W2tab; float* gtab32;
};

__global__ void __launch_bounds__(256) k_prep(PrepArgs pa) {
    __shared__ float tt[32][33];
    int g = blockIdx.x, t = threadIdx.x;
    if (g < 3072) {
        const float* in = (g < 1536) ? pa.query : pa.key_value;
        f16* out = (g < 1536) ? pa.Xq : pa.Xkv;
        int i = (g % 1536) * 256 + t;
        const float4* s = reinterpret_cast<const float4*>(in + i * 8);
        float4 f0 = s[0], f1 = s[1];
        union { pk16 h[4]; uint4 v; } o;
        o.h[0] = __builtin_amdgcn_cvt_pkrtz(f0.x, f0.y);
        o.h[1] = __builtin_amdgcn_cvt_pkrtz(f0.z, f0.w);
        o.h[2] = __builtin_amdgcn_cvt_pkrtz(f1.x, f1.y);
        o.h[3] = __builtin_amdgcn_cvt_pkrtz(f1.z, f1.w);
        reinterpret_cast<uint4*>(out)[i] = o.v;
    } else if (g < 5376) {
        int bi = g - 3072;               // 0..2303
        int z = bi / 576, rem = bi % 576;
        int bx = rem % 24, by = rem / 24;
        const float* W = pa.W[z];
        f16* WT = pa.WT[z];
        int n0 = bx * 32, k0 = by * 32;
        int tx = t & 31, ty = t >> 5;    // 32 x 8
#pragma unroll
        for (int j = 0; j < 4; ++j)
            tt[ty + 8 * j][tx] = W[(k0 + ty + 8 * j) * DIM + n0 + tx];
        __syncthreads();
#pragma unroll
        for (int j = 0; j < 4; ++j)
            WT[(n0 + ty + 8 * j) * DIM + k0 + tx] = (f16)tt[tx][ty + 8 * j];
    } else {
        int i = (g - 5376) * 256 + t;    // 0..8703
        if (i < 3072) {
            int lane = i & 63;
            int hi = lane >> 4, m = lane & 15;
            int u = (i >> 6) * 16 + m;
#pragma unroll
            for (int e = 0; e < 8; ++e) {
                float v = 0.f;
                if (hi == 0) {
                    if (e < 6) v = pa.W1[e * DIM + u];
                    else if (e == 6) v = pa.b1[u];
                }
                pa.W1tab[i * 8 + e] = (f16)v;
            }
        } else if (i < 4608) {
            int i2 = i - 3072;
            int j = i2 >> 6, lane = i2 & 63;
            int gq = lane >> 4, h = lane & 15;
#pragma unroll
            for (int e = 0; e < 8; ++e) {
                int u = 32 * j + ((e >> 2) << 4) + (gq << 2) + (e & 3);
                float v = (h < 12) ? pa.W2[u * 12 + h] : 0.f;
                pa.W2tab[i2 * 8 + e] = (f16)v;
            }
        } else {
            int i2 = i - 4608;           // 0..4095
            float x = (i2 + 0.5f) * (1.0f / 256.0f) - 8.0f;
            pa.gtab32[i2] = 0.5f * x * (1.0f + erff(x * 0.70710678f));
        }
    }
}

// ---------------- bias MLP evaluated on the 161x161 delta grid ----------------
// grid16[p][16]: p = gy*161+gx, delta=(gx/8-10, gy/8-10); entries 0..11 = bias heads (incl b2)
__global__ void __launch_bounds__(256) k_grid(const f16x8* __restrict__ W1tab,
                                              const f16x8* __restrict__ W2tab,
                                              const float* __restrict__ b2,
                                              const float* __restrict__ gtab32,
                                              f16* __restrict__ grid16) {
    __shared__ float tab[4096];   // 16 KB gelu LUT
    int t = threadIdx.x, lane = t & 63, w = t >> 6;
    {
        const uint4* gt = (const uint4*)gtab32;
        uint4* st = (uint4*)tab;
#pragma unroll
        for (int i = 0; i < 4; ++i) st[i * 256 + t] = gt[i * 256 + t];
    }
    int hi = lane >> 4, m = lane & 15;
    int p0 = blockIdx.x * 64 + w * 16;
    int p = p0 + m;
    int gy = p / GN, gx = p - gy * GN;
    float dx = gx * 0.125f - 10.0f;
    float dy = gy * 0.125f - 10.0f;

    union { f16x8 v; pk16 h2[4]; } rf;
    { f16x8 zz = {}; rf.v = zz; }
    if (hi == 0) {
        rf.h2[0] = __builtin_amdgcn_cvt_pkrtz(dx, dy);
        rf.h2[1] = __builtin_amdgcn_cvt_pkrtz(fabsf(dx), fabsf(dy));
        rf.h2[2] = __builtin_amdgcn_cvt_pkrtz(dx * dx, dy * dy);
        rf.h2[3] = __builtin_amdgcn_cvt_pkrtz(1.0f, 0.0f);
    }

    float b2h = (m < 12) ? b2[m] : 0.f;
    f32x4 acc = {b2h, b2h, b2h, b2h};
    const f32x4 zero = {};
    const f16x8* w1p = W1tab + lane;
    const f16x8* w2p = W2tab + lane;
    __syncthreads();

#pragma unroll 2
    for (int j = 0; j < 24; ++j) {
        f16x8 a0  = w1p[(2 * j) * 64];
        f16x8 a1  = w1p[(2 * j + 1) * 64];
        f16x8 w2v = w2p[j * 64];
        f32x4 pre0 = MFMA16H(a0, rf.v, zero, 0, 0, 0);
        f32x4 pre1 = MFMA16H(a1, rf.v, zero, 0, 0, 0);
        float s0[4], s1[4];
#pragma unroll
        for (int e = 0; e < 4; ++e) {
            float x0 = pre0[e];
            float xi0 = __builtin_amdgcn_fmed3f(__builtin_fmaf(x0, 256.f, 2048.f), 0.f, 4095.f);
            float g0 = tab[(int)xi0];
            s0[e] = (x0 > 8.f) ? x0 : g0;
            float x1 = pre1[e];
            float xi1 = __builtin_amdgcn_fmed3f(__builtin_fmaf(x1, 256.f, 2048.f), 0.f, 4095.f);
            float g1 = tab[(int)xi1];
            s1[e] = (x1 > 8.f) ? x1 : g1;
        }
        union { f16x8 v; pk16 h2[4]; } pav;
        pav.h2[0] = __builtin_amdgcn_cvt_pkrtz(s0[0], s0[1]);
        pav.h2[1] = __builtin_amdgcn_cvt_pkrtz(s0[2], s0[3]);
        pav.h2[2] = __builtin_amdgcn_cvt_pkrtz(s1[0], s1[1]);
        pav.h2[3] = __builtin_amdgcn_cvt_pkrtz(s1[2], s1[3]);
        acc = MFMA16H(pav.v, w2v, acc, 0, 0, 0);
    }
    // D: col=m=head, row=hi*4+r = point-local
    if (m < 12) {
#pragma unroll
        for (int r = 0; r < 4; ++r) {
            int pr = p0 + hi * 4 + r;
            if (pr < GPTS) grid16[pr * 16 + m] = (f16)acc[r];
        }
    }
}

// ---------------- fused QKV GEMM + bias bilinear-interp (every 19th block) ----------------
struct MQArgs {
    const float* qc; const float* kc;
    const f16* grid16; f16* bias16;
    const f16* Xq; const f16* Xkv;
    const f16* WqT; const f16* WkT; const f16* WvT;
    const float* bq; const float* bk; const float* bv;
    f16* q_ws; f16* k_ws; f16* v_t;
};

__global__ void __launch_bounds__(256) k_mq2(MQArgs a) {
    __shared__ uint4 lds[1024];   // 16 KB (GEMM role only)
    int g = blockIdx.x, t = threadIdx.x;
    int lane = t & 63, w = t >> 6;
    int hi = lane >> 4, lm = lane & 15;
    int q19 = g / 19, r19 = g % 19;

    if (r19 < 18) {
        // ---------- GEMM role: 64x64 tile, BK=32, double-buffered ----------
        int id = q19 * 18 + r19;         // 0..2303
        int z = id / 768, rem = id % 768;
        int m0 = (rem & 63) * 64, n0 = (rem >> 6) * 64;
        const f16* X = (z == 0) ? a.Xq : a.Xkv;
        const f16* Wt = (z == 0) ? a.WqT : (z == 1) ? a.WkT : a.WvT;
        const float* bias = (z == 0) ? a.bq : (z == 1) ? a.bk : a.bv;
        f16* out = (z == 0) ? a.q_ws : (z == 1) ? a.k_ws : a.v_t;

        int wr = w >> 1, wc = w & 1;
        int srow = t >> 2, sslot = t & 3;      // 64 rows x 4 uint4-slots
        const f16* Ag = X + (m0 + srow) * DIM + sslot * 8;
        const f16* Bg = Wt + (n0 + srow) * DIM + sslot * 8;
        int wi = srow * 4 + (sslot ^ ((srow >> 1) & 3));

        int aidx[2], bidx[2];
#pragma unroll
        for (int i = 0; i < 2; ++i) {
            int ar = wr * 32 + i * 16 + lm;
            aidx[i] = ar * 4 + (hi ^ ((ar >> 1) & 3));
            int br = wc * 32 + i * 16 + lm;
            bidx[i] = 256 + br * 4 + (hi ^ ((br >> 1) & 3));
        }

        f32x4 acc[2][2] = {};
        lds[wi] = *(const uint4*)(Ag);
        lds[256 + wi] = *(const uint4*)(Bg);
        __syncthreads();

        for (int kt = 0; kt < 24; ++kt) {
            uint4 na, nb;
            bool pf = kt < 23;
            if (pf) {
                na = *(const uint4*)(Ag + (kt + 1) * 32);
                nb = *(const uint4*)(Bg + (kt + 1) * 32);
            }
            int bo = (kt & 1) << 9;
            f16x8 af[2], bf[2];
#pragma unroll
            for (int i = 0; i < 2; ++i) {
                af[i] = *(const f16x8*)&lds[bo + aidx[i]];
                bf[i] = *(const f16x8*)&lds[bo + bidx[i]];
            }
#pragma unroll
            for (int mi = 0; mi < 2; ++mi)
#pragma unroll
                for (int ni = 0; ni < 2; ++ni)
                    acc[mi][ni] = MFMA16H(af[mi], bf[ni], acc[mi][ni], 0, 0, 0);
            if (pf) {
                int bo2 = bo ^ 512;
                lds[bo2 + wi] = na;
                lds[bo2 + 256 + wi] = nb;
                __syncthreads();
            }
        }

#pragma unroll
        for (int mi = 0; mi < 2; ++mi)
#pragma unroll
            for (int ni = 0; ni < 2; ++ni) {
                int n = n0 + wc * 32 + ni * 16 + lm;
                float bn = bias[n];
                int h = n >> 6, d = n & 63;
                int mbase = m0 + wr * 32 + mi * 16 + hi * 4;
                int bb = mbase >> 9, l0 = mbase & 511;
                if (z == 2) {
                    union { pk16 h2[2]; uint2 u2; } o;
                    o.h2[0] = __builtin_amdgcn_cvt_pkrtz(acc[mi][ni][0] + bn, acc[mi][ni][1] + bn);
                    o.h2[1] = __builtin_amdgcn_cvt_pkrtz(acc[mi][ni][2] + bn, acc[mi][ni][3] + bn);
                    *reinterpret_cast<uint2*>(out + (((bb * NH + h) * HD) + d) * SEQ + l0) = o.u2;
                } else {
#pragma unroll
                    for (int r = 0; r < 4; ++r)
                        out[(((bb * NH + h) * SEQ) + l0 + r) * HD + d] = (f16)(acc[mi][ni][r] + bn);
                }
            }
    } else {
        // ---------- interp role: bilinear bias from grid16 ----------
        int id = q19;                    // 0..127, 2048 pairs per block
#pragma unroll 2
        for (int i = 0; i < 8; ++i) {
            int p = id * 2048 + i * 256 + t;
            int qi = p >> 9, ki = p & 511;
            float dx = a.qc[2 * qi] - a.kc[2 * ki];
            float dy = a.qc[2 * qi + 1] - a.kc[2 * ki + 1];
            float fxf = __builtin_amdgcn_fmed3f(__builtin_fmaf(dx, 8.f, 80.f), 0.f, 159.9999f);
            float fyf = __builtin_amdgcn_fmed3f(__builtin_fmaf(dy, 8.f, 80.f), 0.f, 159.9999f);
            int ix = (int)fxf, iy = (int)fyf;
            float fx = fxf - (float)ix, fy = fyf - (float)iy;
            const f16* c00 = a.grid16 + (iy * GN + ix) * 16;
            f16x8 g00 = *(const f16x8*)(c00);
            f16x8 g00b = *(const f16x8*)(c00 + 8);
            f16x8 g01 = *(const f16x8*)(c00 + 16);
            f16x8 g01b = *(const f16x8*)(c00 + 24);
            f16x8 g10 = *(const f16x8*)(c00 + GN * 16);
            f16x8 g10b = *(const f16x8*)(c00 + GN * 16 + 8);
            f16x8 g11 = *(const f16x8*)(c00 + GN * 16 + 16);
            f16x8 g11b = *(const f16x8*)(c00 + GN * 16 + 24);
            float o[12];
#pragma unroll
            for (int h = 0; h < 12; ++h) {
                float v00 = (float)(h < 8 ? g00[h] : g00b[h - 8]);
                float v01 = (float)(h < 8 ? g01[h] : g01b[h - 8]);
                float v10 = (float)(h < 8 ? g10[h] : g10b[h - 8]);
                float v11 = (float)(h < 8 ? g11[h] : g11b[h - 8]);
                float v0 = __builtin_fmaf(fx, v01 - v00, v00);
                float v1 = __builtin_fmaf(fx, v11 - v10, v10);
                o[h] = __builtin_fmaf(fy, v1 - v0, v0);
            }
#pragma unroll
            for (int h = 0; h < 12; ++h)
                a.bias16[h * (SEQ * SEQ) + p] = (f16)o[h];
        }
    }
}

// ---------------- O-proj GEMM: 128x128 tile, f32 out, single barrier/iter ----------------
__global__ void __launch_bounds__(256) k_gemmO(const f16* __restrict__ X,
                                               const f16* __restrict__ WT,
                                               const float* __restrict__ bias,
                                               float* __restrict__ out) {
    __shared__ uint4 lds[2048];
    int m0 = blockIdx.x * 128, n0 = blockIdx.y * 128;
    int t = threadIdx.x, lane = t & 63, w = t >> 6;
    int wr = w >> 1, wc = w & 1;
    int lm = lane & 15, hi = lane >> 4;

    int srow = t >> 1, sch = t & 1;
    const f16* Ag = X + (m0 + srow) * DIM + sch * 16;
    const f16* Bg = WT + (n0 + srow) * DIM + sch * 16;
    int sw = (srow >> 1) & 3;
    int wiA0 = srow * 4 + ((2 * sch) ^ sw);
    int wiA1 = srow * 4 + ((2 * sch + 1) ^ sw);

    int aidx[4], bidx[4];
#pragma unroll
    for (int i = 0; i < 4; ++i) {
        int ar = wr * 64 + i * 16 + lm;
        aidx[i] = ar * 4 + (hi ^ ((ar >> 1) & 3));
        int br = wc * 64 + i * 16 + lm;
        bidx[i] = 512 + br * 4 + (hi ^ ((br >> 1) & 3));
    }

    f32x4 acc[4][4] = {};
    {
        lds[wiA0] = *(const uint4*)(Ag);
        lds[wiA1] = *(const uint4*)(Ag + 8);
        lds[512 + wiA0] = *(const uint4*)(Bg);
        lds[512 + wiA1] = *(const uint4*)(Bg + 8);
    }
    __syncthreads();

    for (int kt = 0; kt < 24; ++kt) {
        uint4 na0, na1, nb0, nb1;
        bool pf = kt < 23;
        if (pf) {
            const f16* An = Ag + (kt + 1) * 32;
            const f16* Bn = Bg + (kt + 1) * 32;
            na0 = *(const uint4*)(An);
            na1 = *(const uint4*)(An + 8);
            nb0 = *(const uint4*)(Bn);
            nb1 = *(const uint4*)(Bn + 8);
        }
        int bo = (kt & 1) << 10;
        f16x8 af[4], bf[4];
#pragma unroll
        for (int i = 0; i < 4; ++i) {
            af[i] = *(const f16x8*)&lds[bo + aidx[i]];
            bf[i] = *(const f16x8*)&lds[bo + bidx[i]];
        }
#pragma unroll
        for (int mi = 0; mi < 4; ++mi)
#pragma unroll
            for (int ni = 0; ni < 4; ++ni)
                acc[mi][ni] = MFMA16H(af[mi], bf[ni], acc[mi][ni], 0, 0, 0);
        if (pf) {
            int bo2 = bo ^ 1024;
            lds[bo2 + wiA0] = na0; lds[bo2 + wiA1] = na1;
            lds[bo2 + 512 + wiA0] = nb0; lds[bo2 + 512 + wiA1] = nb1;
            __syncthreads();
        }
    }

#pragma unroll
    for (int mi = 0; mi < 4; ++mi)
#pragma unroll
        for (int ni = 0; ni < 4; ++ni) {
            int n = n0 + wc * 64 + ni * 16 + lm;
            float bn = bias[n];
#pragma unroll
            for (int r = 0; r < 4; ++r) {
                int m = m0 + wr * 64 + mi * 16 + hi * 4 + r;
                out[m * DIM + n] = acc[mi][ni][r] + bn;
            }
        }
}

// ---------------- attention: per (qtile32, h, b), f16 logits LDS ----------------
__global__ void __launch_bounds__(256) k_attn4(const f16* __restrict__ q_ws,
                                               const f16* __restrict__ k_ws,
                                               const f16* __restrict__ v_t,
                                               const f16* __restrict__ bias16,
                                               f16* __restrict__ attn_out) {
    __shared__ __align__(16) unsigned short sm16[32 * 520];  // f16 logits [32][520]
    __shared__ float inv32[32];
    int qt = blockIdx.x, h = blockIdx.y, b = blockIdx.z;
    int q0 = qt * 32;
    int t = threadIdx.x, lane = t & 63, w = t >> 6;
    int lrow = lane & 15, hi = lane >> 4;
    int bh = b * NH + h;
    const f16* Q = q_ws + (bh * SEQ + q0) * HD;
    const f16* K = k_ws + bh * SEQ * HD;
    const f16* Bias = bias16 + (h * SEQ + q0) * SEQ;

    f16x8 aq[2][2];
#pragma unroll
    for (int rt = 0; rt < 2; ++rt)
#pragma unroll
        for (int ds = 0; ds < 2; ++ds) {
            f16x8 v = *(const f16x8*)(Q + (rt * 16 + lrow) * HD + ds * 32 + hi * 8);
            aq[rt][ds] = v * (f16)SCALE;   // exact (pow2)
        }

#pragma unroll
    for (int ct = 0; ct < 8; ++ct) {
        f32x4 acc0 = {}, acc1 = {};
        int kk = w * 128 + ct * 16 + lrow;
#pragma unroll
        for (int ds = 0; ds < 2; ++ds) {
            f16x8 bk = *(const f16x8*)(K + kk * HD + ds * 32 + hi * 8);
            acc0 = MFMA16H(aq[0][ds], bk, acc0, 0, 0, 0);
            acc1 = MFMA16H(aq[1][ds], bk, acc1, 0, 0, 0);
        }
#pragma unroll
        for (int r = 0; r < 4; ++r) {
            int row0 = hi * 4 + r;
            sm16[row0 * 520 + kk] = (unsigned short)__builtin_bit_cast(unsigned short,
                (f16)(acc0[r] + (float)Bias[row0 * SEQ + kk]));
            int row1 = 16 + hi * 4 + r;
            sm16[row1 * 520 + kk] = (unsigned short)__builtin_bit_cast(unsigned short,
                (f16)(acc1[r] + (float)Bias[row1 * SEQ + kk]));
        }
    }
    __syncthreads();

    {
        int row = t >> 3, seg = t & 7;
        int base = row * 520 + 2 * seg;
        float mx = -1e30f;
#pragma unroll 8
        for (int j = 0; j < 32; ++j) {
            union { uint u; f16 h[2]; } cv;
            cv.u = *(const uint*)&sm16[base + 16 * j];
            mx = fmaxf(mx, fmaxf((float)cv.h[0], (float)cv.h[1]));
        }
        mx = fmaxf(mx, __shfl_xor(mx, 1));
        mx = fmaxf(mx, __shfl_xor(mx, 2));
        mx = fmaxf(mx, __shfl_xor(mx, 4));
        float s = 0.f;
#pragma unroll 8
        for (int j = 0; j < 32; ++j) {
            union { uint u; f16 h[2]; } cv;
            cv.u = *(const uint*)&sm16[base + 16 * j];
            float p0 = __builtin_amdgcn_exp2f(((float)cv.h[0] - mx) * 1.442695041f);
            float p1 = __builtin_amdgcn_exp2f(((float)cv.h[1] - mx) * 1.442695041f);
            s += p0 + p1;
            union { pk16 h; uint u; } o;
            o.h = __builtin_amdgcn_cvt_pkrtz(p0, p1);
            *(uint*)&sm16[base + 16 * j] = o.u;
        }
        s += __shfl_xor(s, 1);
        s += __shfl_xor(s, 2);
        s += __shfl_xor(s, 4);
        if (seg == 0) inv32[row] = 1.0f / s;
    }
    __syncthreads();

    const f16* Vt = v_t + bh * HD * SEQ + (w * 16 + lrow) * SEQ;
    f32x4 oacc0 = {}, oacc1 = {};
    for (int kt = 0; kt < 16; ++kt) {
        f16x8 bv = *(const f16x8*)(Vt + kt * 32 + hi * 8);
        f16x8 pa0 = *(const f16x8*)&sm16[lrow * 520 + kt * 32 + hi * 8];
        f16x8 pa1 = *(const f16x8*)&sm16[(16 + lrow) * 520 + kt * 32 + hi * 8];
        oacc0 = MFMA16H(pa0, bv, oacc0, 0, 0, 0);
        oacc1 = MFMA16H(pa1, bv, oacc1, 0, 0, 0);
    }
#pragma unroll
    for (int r = 0; r < 4; ++r) {
        int row0 = hi * 4 + r;
        float v0 = oacc0[r] * inv32[row0];
        attn_out[(b * SEQ + q0 + row0) * DIM + h * HD + w * 16 + lrow] = (f16)v0;
        int row1 = 16 + hi * 4 + r;
        float v1 = oacc1[r] * inv32[row1];
        attn_out[(b * SEQ + q0 + row1) * DIM + h * HD + w * 16 + lrow] = (f16)v1;
    }
}

extern "C" void kernel_launch(void* const* d_in, const int* in_sizes, int n_in,
                              void* d_out, int out_size, void* d_ws, size_t ws_size,
                              hipStream_t stream) {
    const float* query     = (const float*)d_in[0];
    const float* key_value = (const float*)d_in[1];
    const float* qc        = (const float*)d_in[2];
    const float* kc        = (const float*)d_in[3];
    const float* Wq        = (const float*)d_in[4];
    const float* bq        = (const float*)d_in[5];
    const float* Wk        = (const float*)d_in[6];
    const float* bk        = (const float*)d_in[7];
    const float* Wv        = (const float*)d_in[8];
    const float* bv        = (const float*)d_in[9];
    const float* Wo        = (const float*)d_in[10];
    const float* bo        = (const float*)d_in[11];
    const float* W1        = (const float*)d_in[12];
    const float* b1        = (const float*)d_in[13];
    const float* W2        = (const float*)d_in[14];
    const float* b2        = (const float*)d_in[15];

    char* ws = (char*)d_ws;
    f16* Xq   = (f16*)(ws + 0);          // reused as attn_out
    f16* Xkv  = (f16*)(ws + 6291456);
    f16* WqT  = (f16*)(ws + 12582912);
    f16* WkT  = (f16*)(ws + 13762560);
    f16* WvT  = (f16*)(ws + 14942208);
    f16* WoT  = (f16*)(ws + 16121856);
    f16* q_ws = (f16*)(ws + 17301504);
    f16* k_ws = (f16*)(ws + 23592960);
    f16* v_t  = (f16*)(ws + 29884416);   // V written directly transposed [b,h,d,l]
    f16* bias16   = (f16*)(ws + 36175872); // 6291456 B
    f16* W1tab    = (f16*)(ws + 42467328);
    f16* W2tab    = (f16*)(ws + 42516480);
    float* gtab32 = (float*)(ws + 42541056); // 16384 B
    f16* grid16   = (f16*)(ws + 42557440);   // 829472 B
    f16* attn_out = Xq;   // Xq dead after Q projection

    PrepArgs pa;
    pa.query = query; pa.key_value = key_value; pa.Xq = Xq; pa.Xkv = Xkv;
    pa.W[0] = Wq; pa.W[1] = Wk; pa.W[2] = Wv; pa.W[3] = Wo;
    pa.WT[0] = WqT; pa.WT[1] = WkT; pa.WT[2] = WvT; pa.WT[3] = WoT;
    pa.W1 = W1; pa.b1 = b1; pa.W2 = W2;
    pa.W1tab = W1tab; pa.W2tab = W2tab; pa.gtab32 = gtab32;
    k_prep<<<dim3(5410), dim3(256), 0, stream>>>(pa);

    k_grid<<<dim3(406), dim3(256), 0, stream>>>((const f16x8*)W1tab, (const f16x8*)W2tab,
                                                b2, gtab32, grid16);

    MQArgs mq;
    mq.qc = qc; mq.kc = kc;
    mq.grid16 = grid16; mq.bias16 = bias16;
    mq.Xq = Xq; mq.Xkv = Xkv;
    mq.WqT = WqT; mq.WkT = WkT; mq.WvT = WvT;
    mq.bq = bq; mq.bk = bk; mq.bv = bv;
    mq.q_ws = q_ws; mq.k_ws = k_ws; mq.v_t = v_t;
    k_mq2<<<dim3(2432), dim3(256), 0, stream>>>(mq);

    k_attn4<<<dim3(16, NH, NB), dim3(256), 0, stream>>>(q_ws, k_ws, v_t, bias16, attn_out);
    k_gemmO<<<dim3(32, 6), dim3(256), 0, stream>>>(attn_out, WoT, bo, (float*)d_out);
}

// Round 11
// 111.582 us; speedup vs baseline: 2.3947x; 1.0950x over previous
//
#include <hip/hip_runtime.h>
#include <hip/hip_bf16.h>
#include <stdint.h>
#include <math.h>

typedef __attribute__((ext_vector_type(4))) float f32x4;
typedef _Float16 f16;
typedef __attribute__((ext_vector_type(8))) _Float16 f16x8;
typedef decltype(__builtin_amdgcn_cvt_pkrtz(0.f, 0.f)) pk16;

#define DIM   768
#define NH    12
#define HD    64
#define NB    8
#define SEQ   512
#define SCALE 0.125f

#define GN    161          // grid points per axis (Δ=1/8 over [-10,10])
#define GPTS  (GN * GN)    // 25921

#define MFMA16H __builtin_amdgcn_mfma_f32_16x16x32_f16

// ---------------- prep (fused): f32->f16 converts + 4x W transpose + MLP tables ----------------
struct PrepArgs {
    const float* query; const float* key_value; f16* Xq; f16* Xkv;
    const float* W[4]; f16* WT[4];
    const float* W1; const float* b1; const float* W2;
    f16* W1tab; f16* W2tab; float* gtab32;
};

__global__ void __launch_bounds__(256) k_prep(PrepArgs pa) {
    __shared__ float tt[32][33];
    int g = blockIdx.x, t = threadIdx.x;
    if (g < 3072) {
        const float* in = (g < 1536) ? pa.query : pa.key_value;
        f16* out = (g < 1536) ? pa.Xq : pa.Xkv;
        int i = (g % 1536) * 256 + t;
        const float4* s = reinterpret_cast<const float4*>(in + i * 8);
        float4 f0 = s[0], f1 = s[1];
        union { pk16 h[4]; uint4 v; } o;
        o.h[0] = __builtin_amdgcn_cvt_pkrtz(f0.x, f0.y);
        o.h[1] = __builtin_amdgcn_cvt_pkrtz(f0.z, f0.w);
        o.h[2] = __builtin_amdgcn_cvt_pkrtz(f1.x, f1.y);
        o.h[3] = __builtin_amdgcn_cvt_pkrtz(f1.z, f1.w);
        reinterpret_cast<uint4*>(out)[i] = o.v;
    } else if (g < 5376) {
        int bi = g - 3072;               // 0..2303
        int z = bi / 576, rem = bi % 576;
        int bx = rem % 24, by = rem / 24;
        const float* W = pa.W[z];
        f16* WT = pa.WT[z];
        int n0 = bx * 32, k0 = by * 32;
        int tx = t & 31, ty = t >> 5;    // 32 x 8
#pragma unroll
        for (int j = 0; j < 4; ++j)
            tt[ty + 8 * j][tx] = W[(k0 + ty + 8 * j) * DIM + n0 + tx];
        __syncthreads();
#pragma unroll
        for (int j = 0; j < 4; ++j)
            WT[(n0 + ty + 8 * j) * DIM + k0 + tx] = (f16)tt[tx][ty + 8 * j];
    } else {
        int i = (g - 5376) * 256 + t;    // 0..8703
        if (i < 3072) {
            int lane = i & 63;
            int hi = lane >> 4, m = lane & 15;
            int u = (i >> 6) * 16 + m;
#pragma unroll
            for (int e = 0; e < 8; ++e) {
                float v = 0.f;
                if (hi == 0) {
                    if (e < 6) v = pa.W1[e * DIM + u];
                    else if (e == 6) v = pa.b1[u];
                }
                pa.W1tab[i * 8 + e] = (f16)v;
            }
        } else if (i < 4608) {
            int i2 = i - 3072;
            int j = i2 >> 6, lane = i2 & 63;
            int gq = lane >> 4, h = lane & 15;
#pragma unroll
            for (int e = 0; e < 8; ++e) {
                int u = 32 * j + ((e >> 2) << 4) + (gq << 2) + (e & 3);
                float v = (h < 12) ? pa.W2[u * 12 + h] : 0.f;
                pa.W2tab[i2 * 8 + e] = (f16)v;
            }
        } else {
            int i2 = i - 4608;           // 0..4095
            float x = (i2 + 0.5f) * (1.0f / 256.0f) - 8.0f;
            pa.gtab32[i2] = 0.5f * x * (1.0f + erff(x * 0.70710678f));
        }
    }
}

// ---------------- bias MLP evaluated on the 161x161 delta grid ----------------
__global__ void __launch_bounds__(256) k_grid(const f16x8* __restrict__ W1tab,
                                              const f16x8* __restrict__ W2tab,
                                              const float* __restrict__ b2,
                                              const float* __restrict__ gtab32,
                                              f16* __restrict__ grid16) {
    __shared__ float tab[4096];   // 16 KB gelu LUT
    int t = threadIdx.x, lane = t & 63, w = t >> 6;
    {
        const uint4* gt = (const uint4*)gtab32;
        uint4* st = (uint4*)tab;
#pragma unroll
        for (int i = 0; i < 4; ++i) st[i * 256 + t] = gt[i * 256 + t];
    }
    int hi = lane >> 4, m = lane & 15;
    int p0 = blockIdx.x * 64 + w * 16;
    int p = p0 + m;
    int gy = p / GN, gx = p - gy * GN;
    float dx = gx * 0.125f - 10.0f;
    float dy = gy * 0.125f - 10.0f;

    union { f16x8 v; pk16 h2[4]; } rf;
    { f16x8 zz = {}; rf.v = zz; }
    if (hi == 0) {
        rf.h2[0] = __builtin_amdgcn_cvt_pkrtz(dx, dy);
        rf.h2[1] = __builtin_amdgcn_cvt_pkrtz(fabsf(dx), fabsf(dy));
        rf.h2[2] = __builtin_amdgcn_cvt_pkrtz(dx * dx, dy * dy);
        rf.h2[3] = __builtin_amdgcn_cvt_pkrtz(1.0f, 0.0f);
    }

    float b2h = (m < 12) ? b2[m] : 0.f;
    f32x4 acc = {b2h, b2h, b2h, b2h};
    const f32x4 zero = {};
    const f16x8* w1p = W1tab + lane;
    const f16x8* w2p = W2tab + lane;
    __syncthreads();

#pragma unroll 2
    for (int j = 0; j < 24; ++j) {
        f16x8 a0  = w1p[(2 * j) * 64];
        f16x8 a1  = w1p[(2 * j + 1) * 64];
        f16x8 w2v = w2p[j * 64];
        f32x4 pre0 = MFMA16H(a0, rf.v, zero, 0, 0, 0);
        f32x4 pre1 = MFMA16H(a1, rf.v, zero, 0, 0, 0);
        float s0[4], s1[4];
#pragma unroll
        for (int e = 0; e < 4; ++e) {
            float x0 = pre0[e];
            float xi0 = __builtin_amdgcn_fmed3f(__builtin_fmaf(x0, 256.f, 2048.f), 0.f, 4095.f);
            float g0 = tab[(int)xi0];
            s0[e] = (x0 > 8.f) ? x0 : g0;
            float x1 = pre1[e];
            float xi1 = __builtin_amdgcn_fmed3f(__builtin_fmaf(x1, 256.f, 2048.f), 0.f, 4095.f);
            float g1 = tab[(int)xi1];
            s1[e] = (x1 > 8.f) ? x1 : g1;
        }
        union { f16x8 v; pk16 h2[4]; } pav;
        pav.h2[0] = __builtin_amdgcn_cvt_pkrtz(s0[0], s0[1]);
        pav.h2[1] = __builtin_amdgcn_cvt_pkrtz(s0[2], s0[3]);
        pav.h2[2] = __builtin_amdgcn_cvt_pkrtz(s1[0], s1[1]);
        pav.h2[3] = __builtin_amdgcn_cvt_pkrtz(s1[2], s1[3]);
        acc = MFMA16H(pav.v, w2v, acc, 0, 0, 0);
    }
    if (m < 12) {
#pragma unroll
        for (int r = 0; r < 4; ++r) {
            int pr = p0 + hi * 4 + r;
            if (pr < GPTS) grid16[pr * 16 + m] = (f16)acc[r];
        }
    }
}

// ---------------- fused QKV GEMM + interp, XCD-aware panel-grouped mapping ----------------
// 2432 blocks; xcd = bid&7, slot = bid>>3 (0..303).
// slot<16: interp block id = xcd*16+slot.
// else: lid = xcd*288+(slot-16); m_group=lid/36 (8 consecutive per XCD share L2-resident
//       A-panels); within=lid%36: z=within/12 (Q/K/V), n_tile=within%12.
struct MQArgs {
    const float* qc; const float* kc;
    const f16* grid16; f16* bias16;
    const f16* Xq; const f16* Xkv;
    const f16* WqT; const f16* WkT; const f16* WvT;
    const float* bq; const float* bk; const float* bv;
    f16* q_ws; f16* k_ws; f16* v_t;
};

__global__ void __launch_bounds__(256) k_mq3(MQArgs a) {
    __shared__ uint4 lds[1024];   // 16 KB (GEMM role only)
    int bid = blockIdx.x, t = threadIdx.x;
    int lane = t & 63, w = t >> 6;
    int hi = lane >> 4, lm = lane & 15;
    int xcd = bid & 7, slot = bid >> 3;

    if (slot >= 16) {
        // ---------- GEMM role: 64x64 tile, BK=32, double-buffered ----------
        int lid = xcd * 288 + (slot - 16);     // 0..2303
        int m_group = lid / 36;
        int within = lid - m_group * 36;
        int z = within / 12;
        int n_tile = within - z * 12;
        int m0 = m_group * 64, n0 = n_tile * 64;
        const f16* X = (z == 0) ? a.Xq : a.Xkv;
        const f16* Wt = (z == 0) ? a.WqT : (z == 1) ? a.WkT : a.WvT;
        const float* bias = (z == 0) ? a.bq : (z == 1) ? a.bk : a.bv;
        f16* out = (z == 0) ? a.q_ws : (z == 1) ? a.k_ws : a.v_t;

        int wr = w >> 1, wc = w & 1;
        int srow = t >> 2, sslot = t & 3;      // 64 rows x 4 uint4-slots
        const f16* Ag = X + (m0 + srow) * DIM + sslot * 8;
        const f16* Bg = Wt + (n0 + srow) * DIM + sslot * 8;
        int wi = srow * 4 + (sslot ^ ((srow >> 1) & 3));

        int aidx[2], bidx[2];
#pragma unroll
        for (int i = 0; i < 2; ++i) {
            int ar = wr * 32 + i * 16 + lm;
            aidx[i] = ar * 4 + (hi ^ ((ar >> 1) & 3));
            int br = wc * 32 + i * 16 + lm;
            bidx[i] = 256 + br * 4 + (hi ^ ((br >> 1) & 3));
        }

        f32x4 acc[2][2] = {};
        lds[wi] = *(const uint4*)(Ag);
        lds[256 + wi] = *(const uint4*)(Bg);
        __syncthreads();

        for (int kt = 0; kt < 24; ++kt) {
            uint4 na, nb;
            bool pf = kt < 23;
            if (pf) {
                na = *(const uint4*)(Ag + (kt + 1) * 32);
                nb = *(const uint4*)(Bg + (kt + 1) * 32);
            }
            int bo = (kt & 1) << 9;
            f16x8 af[2], bf[2];
#pragma unroll
            for (int i = 0; i < 2; ++i) {
                af[i] = *(const f16x8*)&lds[bo + aidx[i]];
                bf[i] = *(const f16x8*)&lds[bo + bidx[i]];
            }
#pragma unroll
            for (int mi = 0; mi < 2; ++mi)
#pragma unroll
                for (int ni = 0; ni < 2; ++ni)
                    acc[mi][ni] = MFMA16H(af[mi], bf[ni], acc[mi][ni], 0, 0, 0);
            if (pf) {
                int bo2 = bo ^ 512;
                lds[bo2 + wi] = na;
                lds[bo2 + 256 + wi] = nb;
                __syncthreads();
            }
        }

#pragma unroll
        for (int mi = 0; mi < 2; ++mi)
#pragma unroll
            for (int ni = 0; ni < 2; ++ni) {
                int n = n0 + wc * 32 + ni * 16 + lm;
                float bn = bias[n];
                int h = n >> 6, d = n & 63;
                int mbase = m0 + wr * 32 + mi * 16 + hi * 4;
                int bb = mbase >> 9, l0 = mbase & 511;
                if (z == 2) {
                    union { pk16 h2[2]; uint2 u2; } o;
                    o.h2[0] = __builtin_amdgcn_cvt_pkrtz(acc[mi][ni][0] + bn, acc[mi][ni][1] + bn);
                    o.h2[1] = __builtin_amdgcn_cvt_pkrtz(acc[mi][ni][2] + bn, acc[mi][ni][3] + bn);
                    *reinterpret_cast<uint2*>(out + (((bb * NH + h) * HD) + d) * SEQ + l0) = o.u2;
                } else {
#pragma unroll
                    for (int r = 0; r < 4; ++r)
                        out[(((bb * NH + h) * SEQ) + l0 + r) * HD + d] = (f16)(acc[mi][ni][r] + bn);
                }
            }
    } else {
        // ---------- interp role: bilinear bias from grid16 ----------
        int id = xcd * 16 + slot;        // 0..127, 2048 pairs per block
#pragma unroll 2
        for (int i = 0; i < 8; ++i) {
            int p = id * 2048 + i * 256 + t;
            int qi = p >> 9, ki = p & 511;
            float dx = a.qc[2 * qi] - a.kc[2 * ki];
            float dy = a.qc[2 * qi + 1] - a.kc[2 * ki + 1];
            float fxf = __builtin_amdgcn_fmed3f(__builtin_fmaf(dx, 8.f, 80.f), 0.f, 159.9999f);
            float fyf = __builtin_amdgcn_fmed3f(__builtin_fmaf(dy, 8.f, 80.f), 0.f, 159.9999f);
            int ix = (int)fxf, iy = (int)fyf;
            float fx = fxf - (float)ix, fy = fyf - (float)iy;
            const f16* c00 = a.grid16 + (iy * GN + ix) * 16;
            f16x8 g00 = *(const f16x8*)(c00);
            f16x8 g00b = *(const f16x8*)(c00 + 8);
            f16x8 g01 = *(const f16x8*)(c00 + 16);
            f16x8 g01b = *(const f16x8*)(c00 + 24);
            f16x8 g10 = *(const f16x8*)(c00 + GN * 16);
            f16x8 g10b = *(const f16x8*)(c00 + GN * 16 + 8);
            f16x8 g11 = *(const f16x8*)(c00 + GN * 16 + 16);
            f16x8 g11b = *(const f16x8*)(c00 + GN * 16 + 24);
            float o[12];
#pragma unroll
            for (int h = 0; h < 12; ++h) {
                float v00 = (float)(h < 8 ? g00[h] : g00b[h - 8]);
                float v01 = (float)(h < 8 ? g01[h] : g01b[h - 8]);
                float v10 = (float)(h < 8 ? g10[h] : g10b[h - 8]);
                float v11 = (float)(h < 8 ? g11[h] : g11b[h - 8]);
                float v0 = __builtin_fmaf(fx, v01 - v00, v00);
                float v1 = __builtin_fmaf(fx, v11 - v10, v10);
                o[h] = __builtin_fmaf(fy, v1 - v0, v0);
            }
#pragma unroll
            for (int h = 0; h < 12; ++h)
                a.bias16[h * (SEQ * SEQ) + p] = (f16)o[h];
        }
    }
}

// ---------------- O-proj GEMM: 128x128 tile, XCD-grouped mapping ----------------
// 192 blocks 1-D: xcd=bid&7, slot=bid>>3 (0..23); m_tile = xcd*4 + slot/6; n_tile = slot%6.
__global__ void __launch_bounds__(256) k_gemmO(const f16* __restrict__ X,
                                               const f16* __restrict__ WT,
                                               const float* __restrict__ bias,
                                               float* __restrict__ out) {
    __shared__ uint4 lds[2048];
    int bid = blockIdx.x;
    int xcd = bid & 7, slot = bid >> 3;
    int m0 = (xcd * 4 + slot / 6) * 128, n0 = (slot % 6) * 128;
    int t = threadIdx.x, lane = t & 63, w = t >> 6;
    int wr = w >> 1, wc = w & 1;
    int lm = lane & 15, hi = lane >> 4;

    int srow = t >> 1, sch = t & 1;
    const f16* Ag = X + (m0 + srow) * DIM + sch * 16;
    const f16* Bg = WT + (n0 + srow) * DIM + sch * 16;
    int sw = (srow >> 1) & 3;
    int wiA0 = srow * 4 + ((2 * sch) ^ sw);
    int wiA1 = srow * 4 + ((2 * sch + 1) ^ sw);

    int aidx[4], bidx[4];
#pragma unroll
    for (int i = 0; i < 4; ++i) {
        int ar = wr * 64 + i * 16 + lm;
        aidx[i] = ar * 4 + (hi ^ ((ar >> 1) & 3));
        int br = wc * 64 + i * 16 + lm;
        bidx[i] = 512 + br * 4 + (hi ^ ((br >> 1) & 3));
    }

    f32x4 acc[4][4] = {};
    {
        lds[wiA0] = *(const uint4*)(Ag);
        lds[wiA1] = *(const uint4*)(Ag + 8);
        lds[512 + wiA0] = *(const uint4*)(Bg);
        lds[512 + wiA1] = *(const uint4*)(Bg + 8);
    }
    __syncthreads();

    for (int kt = 0; kt < 24; ++kt) {
        uint4 na0, na1, nb0, nb1;
        bool pf = kt < 23;
        if (pf) {
            const f16* An = Ag + (kt + 1) * 32;
            const f16* Bn = Bg + (kt + 1) * 32;
            na0 = *(const uint4*)(An);
            na1 = *(const uint4*)(An + 8);
            nb0 = *(const uint4*)(Bn);
            nb1 = *(const uint4*)(Bn + 8);
        }
        int bo = (kt & 1) << 10;
        f16x8 af[4], bf[4];
#pragma unroll
        for (int i = 0; i < 4; ++i) {
            af[i] = *(const f16x8*)&lds[bo + aidx[i]];
            bf[i] = *(const f16x8*)&lds[bo + bidx[i]];
        }
#pragma unroll
        for (int mi = 0; mi < 4; ++mi)
#pragma unroll
            for (int ni = 0; ni < 4; ++ni)
                acc[mi][ni] = MFMA16H(af[mi], bf[ni], acc[mi][ni], 0, 0, 0);
        if (pf) {
            int bo2 = bo ^ 1024;
            lds[bo2 + wiA0] = na0; lds[bo2 + wiA1] = na1;
            lds[bo2 + 512 + wiA0] = nb0; lds[bo2 + 512 + wiA1] = nb1;
            __syncthreads();
        }
    }

#pragma unroll
    for (int mi = 0; mi < 4; ++mi)
#pragma unroll
        for (int ni = 0; ni < 4; ++ni) {
            int n = n0 + wc * 64 + ni * 16 + lm;
            float bn = bias[n];
#pragma unroll
            for (int r = 0; r < 4; ++r) {
                int m = m0 + wr * 64 + mi * 16 + hi * 4 + r;
                out[m * DIM + n] = acc[mi][ni][r] + bn;
            }
        }
}

// ---------------- attention: 1536 blocks 1-D, XCD-grouped (b,h) ----------------
// xcd=bid&7, slot=bid>>3 (0..191); g = xcd*12 + slot/16 -> h=g%12, b=g/12; qt=slot%16.
__global__ void __launch_bounds__(256) k_attn4(const f16* __restrict__ q_ws,
                                               const f16* __restrict__ k_ws,
                                               const f16* __restrict__ v_t,
                                               const f16* __restrict__ bias16,
                                               f16* __restrict__ attn_out) {
    __shared__ __align__(16) unsigned short sm16[32 * 520];  // f16 logits [32][520]
    __shared__ float inv32[32];
    int bid = blockIdx.x;
    int xcd = bid & 7, slot = bid >> 3;
    int g = xcd * 12 + (slot >> 4);
    int h = g % 12, b = g / 12;
    int qt = slot & 15;
    int q0 = qt * 32;
    int t = threadIdx.x, lane = t & 63, w = t >> 6;
    int lrow = lane & 15, hi = lane >> 4;
    int bh = b * NH + h;
    const f16* Q = q_ws + (bh * SEQ + q0) * HD;
    const f16* K = k_ws + bh * SEQ * HD;
    const f16* Bias = bias16 + (h * SEQ + q0) * SEQ;

    f16x8 aq[2][2];
#pragma unroll
    for (int rt = 0; rt < 2; ++rt)
#pragma unroll
        for (int ds = 0; ds < 2; ++ds) {
            f16x8 v = *(const f16x8*)(Q + (rt * 16 + lrow) * HD + ds * 32 + hi * 8);
            aq[rt][ds] = v * (f16)SCALE;   // exact (pow2)
        }

#pragma unroll
    for (int ct = 0; ct < 8; ++ct) {
        f32x4 acc0 = {}, acc1 = {};
        int kk = w * 128 + ct * 16 + lrow;
#pragma unroll
        for (int ds = 0; ds < 2; ++ds) {
            f16x8 bk = *(const f16x8*)(K + kk * HD + ds * 32 + hi * 8);
            acc0 = MFMA16H(aq[0][ds], bk, acc0, 0, 0, 0);
            acc1 = MFMA16H(aq[1][ds], bk, acc1, 0, 0, 0);
        }
#pragma unroll
        for (int r = 0; r < 4; ++r) {
            int row0 = hi * 4 + r;
            sm16[row0 * 520 + kk] = (unsigned short)__builtin_bit_cast(unsigned short,
                (f16)(acc0[r] + (float)Bias[row0 * SEQ + kk]));
            int row1 = 16 + hi * 4 + r;
            sm16[row1 * 520 + kk] = (unsigned short)__builtin_bit_cast(unsigned short,
                (f16)(acc1[r] + (float)Bias[row1 * SEQ + kk]));
        }
    }
    __syncthreads();

    {
        int row = t >> 3, seg = t & 7;
        int base = row * 520 + 2 * seg;
        float mx = -1e30f;
#pragma unroll 8
        for (int j = 0; j < 32; ++j) {
            union { uint u; f16 h[2]; } cv;
            cv.u = *(const uint*)&sm16[base + 16 * j];
            mx = fmaxf(mx, fmaxf((float)cv.h[0], (float)cv.h[1]));
        }
        mx = fmaxf(mx, __shfl_xor(mx, 1));
        mx = fmaxf(mx, __shfl_xor(mx, 2));
        mx = fmaxf(mx, __shfl_xor(mx, 4));
        float s = 0.f;
#pragma unroll 8
        for (int j = 0; j < 32; ++j) {
            union { uint u; f16 h[2]; } cv;
            cv.u = *(const uint*)&sm16[base + 16 * j];
            float p0 = __builtin_amdgcn_exp2f(((float)cv.h[0] - mx) * 1.442695041f);
            float p1 = __builtin_amdgcn_exp2f(((float)cv.h[1] - mx) * 1.442695041f);
            s += p0 + p1;
            union { pk16 h; uint u; } o;
            o.h = __builtin_amdgcn_cvt_pkrtz(p0, p1);
            *(uint*)&sm16[base + 16 * j] = o.u;
        }
        s += __shfl_xor(s, 1);
        s += __shfl_xor(s, 2);
        s += __shfl_xor(s, 4);
        if (seg == 0) inv32[row] = 1.0f / s;
    }
    __syncthreads();

    const f16* Vt = v_t + bh * HD * SEQ + (w * 16 + lrow) * SEQ;
    f32x4 oacc0 = {}, oacc1 = {};
    for (int kt = 0; kt < 16; ++kt) {
        f16x8 bv = *(const f16x8*)(Vt + kt * 32 + hi * 8);
        f16x8 pa0 = *(const f16x8*)&sm16[lrow * 520 + kt * 32 + hi * 8];
        f16x8 pa1 = *(const f16x8*)&sm16[(16 + lrow) * 520 + kt * 32 + hi * 8];
        oacc0 = MFMA16H(pa0, bv, oacc0, 0, 0, 0);
        oacc1 = MFMA16H(pa1, bv, oacc1, 0, 0, 0);
    }
#pragma unroll
    for (int r = 0; r < 4; ++r) {
        int row0 = hi * 4 + r;
        float v0 = oacc0[r] * inv32[row0];
        attn_out[(b * SEQ + q0 + row0) * DIM + h * HD + w * 16 + lrow] = (f16)v0;
        int row1 = 16 + hi * 4 + r;
        float v1 = oacc1[r] * inv32[row1];
        attn_out[(b * SEQ + q0 + row1) * DIM + h * HD + w * 16 + lrow] = (f16)v1;
    }
}

extern "C" void kernel_launch(void* const* d_in, const int* in_sizes, int n_in,
                              void* d_out, int out_size, void* d_ws, size_t ws_size,
                              hipStream_t stream) {
    const float* query     = (const float*)d_in[0];
    const float* key_value = (const float*)d_in[1];
    const float* qc        = (const float*)d_in[2];
    const float* kc        = (const float*)d_in[3];
    const float* Wq        = (const float*)d_in[4];
    const float* bq        = (const float*)d_in[5];
    const float* Wk        = (const float*)d_in[6];
    const float* bk        = (const float*)d_in[7];
    const float* Wv        = (const float*)d_in[8];
    const float* bv        = (const float*)d_in[9];
    const float* Wo        = (const float*)d_in[10];
    const float* bo        = (const float*)d_in[11];
    const float* W1        = (const float*)d_in[12];
    const float* b1        = (const float*)d_in[13];
    const float* W2        = (const float*)d_in[14];
    const float* b2        = (const float*)d_in[15];

    char* ws = (char*)d_ws;
    f16* Xq   = (f16*)(ws + 0);          // reused as attn_out
    f16* Xkv  = (f16*)(ws + 6291456);
    f16* WqT  = (f16*)(ws + 12582912);
    f16* WkT  = (f16*)(ws + 13762560);
    f16* WvT  = (f16*)(ws + 14942208);
    f16* WoT  = (f16*)(ws + 16121856);
    f16* q_ws = (f16*)(ws + 17301504);
    f16* k_ws = (f16*)(ws + 23592960);
    f16* v_t  = (f16*)(ws + 29884416);   // V written directly transposed [b,h,d,l]
    f16* bias16   = (f16*)(ws + 36175872); // 6291456 B
    f16* W1tab    = (f16*)(ws + 42467328);
    f16* W2tab    = (f16*)(ws + 42516480);
    float* gtab32 = (float*)(ws + 42541056); // 16384 B
    f16* grid16   = (f16*)(ws + 42557440);   // 829472 B
    f16* attn_out = Xq;   // Xq dead after Q projection

    PrepArgs pa;
    pa.query = query; pa.key_value = key_value; pa.Xq = Xq; pa.Xkv = Xkv;
    pa.W[0] = Wq; pa.W[1] = Wk; pa.W[2] = Wv; pa.W[3] = Wo;
    pa.WT[0] = WqT; pa.WT[1] = WkT; pa.WT[2] = WvT; pa.WT[3] = WoT;
    pa.W1 = W1; pa.b1 = b1; pa.W2 = W2;
    pa.W1tab = W1tab; pa.W2tab = W2tab; pa.gtab32 = gtab32;
    k_prep<<<dim3(5410), dim3(256), 0, stream>>>(pa);

    k_grid<<<dim3(406), dim3(256), 0, stream>>>((const f16x8*)W1tab, (const f16x8*)W2tab,
                                                b2, gtab32, grid16);

    MQArgs mq;
    mq.qc = qc; mq.kc = kc;
    mq.grid16 = grid16; mq.bias16 = bias16;
    mq.Xq = Xq; mq.Xkv = Xkv;
    mq.WqT = WqT; mq.WkT = WkT; mq.WvT = WvT;
    mq.bq = bq; mq.bk = bk; mq.bv = bv;
    mq.q_ws = q_ws; mq.k_ws = k_ws; mq.v_t = v_t;
    k_mq3<<<dim3(2432), dim3(256), 0, stream>>>(mq);

    k_attn4<<<dim3(1536), dim3(256), 0, stream>>>(q_ws, k_ws, v_t, bias16, attn_out);
    k_gemmO<<<dim3(192), dim3(256), 0, stream>>>(attn_out, WoT, bo, (float*)d_out);
}

// Round 12
// 110.380 us; speedup vs baseline: 2.4207x; 1.0109x over previous
//
#include <hip/hip_runtime.h>
#include <hip/hip_bf16.h>
#include <stdint.h>
#include <math.h>

typedef __attribute__((ext_vector_type(4))) float f32x4;
typedef _Float16 f16;
typedef __attribute__((ext_vector_type(8))) _Float16 f16x8;
typedef decltype(__builtin_amdgcn_cvt_pkrtz(0.f, 0.f)) pk16;

#define DIM   768
#define NH    12
#define HD    64
#define NB    8
#define SEQ   512
#define SCALE 0.125f

#define GN    161          // grid points per axis (Δ=1/8 over [-10,10])
#define GPTS  (GN * GN)    // 25921

#define MFMA16H __builtin_amdgcn_mfma_f32_16x16x32_f16

// ---------------- prep (fused): f32->f16 converts + 4x W transpose + MLP tables ----------------
struct PrepArgs {
    const float* query; const float* key_value; f16* Xq; f16* Xkv;
    const float* W[4]; f16* WT[4];
    const float* W1; const float* b1; const float* W2;
    f16* W1tab; f16* W2tab; float* gtab32;
};

__global__ void __launch_bounds__(256) k_prep(PrepArgs pa) {
    __shared__ float tt[32][33];
    int g = blockIdx.x, t = threadIdx.x;
    if (g < 3072) {
        const float* in = (g < 1536) ? pa.query : pa.key_value;
        f16* out = (g < 1536) ? pa.Xq : pa.Xkv;
        int i = (g % 1536) * 256 + t;
        const float4* s = reinterpret_cast<const float4*>(in + i * 8);
        float4 f0 = s[0], f1 = s[1];
        union { pk16 h[4]; uint4 v; } o;
        o.h[0] = __builtin_amdgcn_cvt_pkrtz(f0.x, f0.y);
        o.h[1] = __builtin_amdgcn_cvt_pkrtz(f0.z, f0.w);
        o.h[2] = __builtin_amdgcn_cvt_pkrtz(f1.x, f1.y);
        o.h[3] = __builtin_amdgcn_cvt_pkrtz(f1.z, f1.w);
        reinterpret_cast<uint4*>(out)[i] = o.v;
    } else if (g < 5376) {
        int bi = g - 3072;               // 0..2303
        int z = bi / 576, rem = bi % 576;
        int bx = rem % 24, by = rem / 24;
        const float* W = pa.W[z];
        f16* WT = pa.WT[z];
        int n0 = bx * 32, k0 = by * 32;
        int tx = t & 31, ty = t >> 5;    // 32 x 8
#pragma unroll
        for (int j = 0; j < 4; ++j)
            tt[ty + 8 * j][tx] = W[(k0 + ty + 8 * j) * DIM + n0 + tx];
        __syncthreads();
#pragma unroll
        for (int j = 0; j < 4; ++j)
            WT[(n0 + ty + 8 * j) * DIM + k0 + tx] = (f16)tt[tx][ty + 8 * j];
    } else {
        int i = (g - 5376) * 256 + t;    // 0..8703
        if (i < 3072) {
            int lane = i & 63;
            int hi = lane >> 4, m = lane & 15;
            int u = (i >> 6) * 16 + m;
#pragma unroll
            for (int e = 0; e < 8; ++e) {
                float v = 0.f;
                if (hi == 0) {
                    if (e < 6) v = pa.W1[e * DIM + u];
                    else if (e == 6) v = pa.b1[u];
                }
                pa.W1tab[i * 8 + e] = (f16)v;
            }
        } else if (i < 4608) {
            int i2 = i - 3072;
            int j = i2 >> 6, lane = i2 & 63;
            int gq = lane >> 4, h = lane & 15;
#pragma unroll
            for (int e = 0; e < 8; ++e) {
                int u = 32 * j + ((e >> 2) << 4) + (gq << 2) + (e & 3);
                float v = (h < 12) ? pa.W2[u * 12 + h] : 0.f;
                pa.W2tab[i2 * 8 + e] = (f16)v;
            }
        } else {
            int i2 = i - 4608;           // 0..4095
            float x = (i2 + 0.5f) * (1.0f / 256.0f) - 8.0f;
            pa.gtab32[i2] = 0.5f * x * (1.0f + erff(x * 0.70710678f));
        }
    }
}

// ---------------- bias MLP evaluated on the 161x161 delta grid ----------------
__global__ void __launch_bounds__(256) k_grid(const f16x8* __restrict__ W1tab,
                                              const f16x8* __restrict__ W2tab,
                                              const float* __restrict__ b2,
                                              const float* __restrict__ gtab32,
                                              f16* __restrict__ grid16) {
    __shared__ float tab[4096];   // 16 KB gelu LUT
    int t = threadIdx.x, lane = t & 63, w = t >> 6;
    {
        const uint4* gt = (const uint4*)gtab32;
        uint4* st = (uint4*)tab;
#pragma unroll
        for (int i = 0; i < 4; ++i) st[i * 256 + t] = gt[i * 256 + t];
    }
    int hi = lane >> 4, m = lane & 15;
    int p0 = blockIdx.x * 64 + w * 16;
    int p = p0 + m;
    int gy = p / GN, gx = p - gy * GN;
    float dx = gx * 0.125f - 10.0f;
    float dy = gy * 0.125f - 10.0f;

    union { f16x8 v; pk16 h2[4]; } rf;
    { f16x8 zz = {}; rf.v = zz; }
    if (hi == 0) {
        rf.h2[0] = __builtin_amdgcn_cvt_pkrtz(dx, dy);
        rf.h2[1] = __builtin_amdgcn_cvt_pkrtz(fabsf(dx), fabsf(dy));
        rf.h2[2] = __builtin_amdgcn_cvt_pkrtz(dx * dx, dy * dy);
        rf.h2[3] = __builtin_amdgcn_cvt_pkrtz(1.0f, 0.0f);
    }

    float b2h = (m < 12) ? b2[m] : 0.f;
    f32x4 acc = {b2h, b2h, b2h, b2h};
    const f32x4 zero = {};
    const f16x8* w1p = W1tab + lane;
    const f16x8* w2p = W2tab + lane;
    __syncthreads();

#pragma unroll 2
    for (int j = 0; j < 24; ++j) {
        f16x8 a0  = w1p[(2 * j) * 64];
        f16x8 a1  = w1p[(2 * j + 1) * 64];
        f16x8 w2v = w2p[j * 64];
        f32x4 pre0 = MFMA16H(a0, rf.v, zero, 0, 0, 0);
        f32x4 pre1 = MFMA16H(a1, rf.v, zero, 0, 0, 0);
        float s0[4], s1[4];
#pragma unroll
        for (int e = 0; e < 4; ++e) {
            float x0 = pre0[e];
            float xi0 = __builtin_amdgcn_fmed3f(__builtin_fmaf(x0, 256.f, 2048.f), 0.f, 4095.f);
            float g0 = tab[(int)xi0];
            s0[e] = (x0 > 8.f) ? x0 : g0;
            float x1 = pre1[e];
            float xi1 = __builtin_amdgcn_fmed3f(__builtin_fmaf(x1, 256.f, 2048.f), 0.f, 4095.f);
            float g1 = tab[(int)xi1];
            s1[e] = (x1 > 8.f) ? x1 : g1;
        }
        union { f16x8 v; pk16 h2[4]; } pav;
        pav.h2[0] = __builtin_amdgcn_cvt_pkrtz(s0[0], s0[1]);
        pav.h2[1] = __builtin_amdgcn_cvt_pkrtz(s0[2], s0[3]);
        pav.h2[2] = __builtin_amdgcn_cvt_pkrtz(s1[0], s1[1]);
        pav.h2[3] = __builtin_amdgcn_cvt_pkrtz(s1[2], s1[3]);
        acc = MFMA16H(pav.v, w2v, acc, 0, 0, 0);
    }
    if (m < 12) {
#pragma unroll
        for (int r = 0; r < 4; ++r) {
            int pr = p0 + hi * 4 + r;
            if (pr < GPTS) grid16[pr * 16 + m] = (f16)acc[r];
        }
    }
}

// ---------------- fused QKV GEMM (128x128) + interp, XCD-aware mapping ----------------
// 704 blocks = 8 XCD x 88 slots. slot<16: interp (id=xcd*16+slot).
// slot>=16: lid = xcd*72+(slot-16); m_tile = lid/18 (4 consecutive per XCD -> A panels
//           L2-resident); within = lid%18: z=within/6, n_tile=within%6 (n0=n_tile*128).
struct MQArgs {
    const float* qc; const float* kc;
    const f16* grid16; f16* bias16;
    const f16* Xq; const f16* Xkv;
    const f16* WqT; const f16* WkT; const f16* WvT;
    const float* bq; const float* bk; const float* bv;
    f16* q_ws; f16* k_ws; f16* v_t;
};

__global__ void __launch_bounds__(256) k_mq4(MQArgs a) {
    __shared__ uint4 lds[2048];   // 32 KB (GEMM role)
    int bid = blockIdx.x, t = threadIdx.x;
    int lane = t & 63, w = t >> 6;
    int hi = lane >> 4, lm = lane & 15;
    int xcd = bid & 7, slot = bid >> 3;

    if (slot >= 16) {
        // ---------- GEMM role: 128x128 tile, BK=32, double-buffered ----------
        int lid = xcd * 72 + (slot - 16);      // 0..575
        int m_tile = lid / 18;
        int within = lid - m_tile * 18;
        int z = within / 6;
        int n_tile = within - z * 6;
        int m0 = m_tile * 128, n0 = n_tile * 128;
        const f16* X = (z == 0) ? a.Xq : a.Xkv;
        const f16* Wt = (z == 0) ? a.WqT : (z == 1) ? a.WkT : a.WvT;
        const float* bias = (z == 0) ? a.bq : (z == 1) ? a.bk : a.bv;
        f16* out = (z == 0) ? a.q_ws : (z == 1) ? a.k_ws : a.v_t;

        int wr = w >> 1, wc = w & 1;
        int srow = t >> 1, sch = t & 1;
        const f16* Ag = X + (m0 + srow) * DIM + sch * 16;
        const f16* Bg = Wt + (n0 + srow) * DIM + sch * 16;
        int sw = (srow >> 1) & 3;
        int wiA0 = srow * 4 + ((2 * sch) ^ sw);
        int wiA1 = srow * 4 + ((2 * sch + 1) ^ sw);

        int aidx[4], bidx[4];
#pragma unroll
        for (int i = 0; i < 4; ++i) {
            int ar = wr * 64 + i * 16 + lm;
            aidx[i] = ar * 4 + (hi ^ ((ar >> 1) & 3));
            int br = wc * 64 + i * 16 + lm;
            bidx[i] = 512 + br * 4 + (hi ^ ((br >> 1) & 3));
        }

        f32x4 acc[4][4] = {};
        {
            lds[wiA0] = *(const uint4*)(Ag);
            lds[wiA1] = *(const uint4*)(Ag + 8);
            lds[512 + wiA0] = *(const uint4*)(Bg);
            lds[512 + wiA1] = *(const uint4*)(Bg + 8);
        }
        __syncthreads();

        for (int kt = 0; kt < 24; ++kt) {
            uint4 na0, na1, nb0, nb1;
            bool pf = kt < 23;
            if (pf) {
                const f16* An = Ag + (kt + 1) * 32;
                const f16* Bn = Bg + (kt + 1) * 32;
                na0 = *(const uint4*)(An);
                na1 = *(const uint4*)(An + 8);
                nb0 = *(const uint4*)(Bn);
                nb1 = *(const uint4*)(Bn + 8);
            }
            int bo = (kt & 1) << 10;
            f16x8 af[4], bf[4];
#pragma unroll
            for (int i = 0; i < 4; ++i) {
                af[i] = *(const f16x8*)&lds[bo + aidx[i]];
                bf[i] = *(const f16x8*)&lds[bo + bidx[i]];
            }
#pragma unroll
            for (int mi = 0; mi < 4; ++mi)
#pragma unroll
                for (int ni = 0; ni < 4; ++ni)
                    acc[mi][ni] = MFMA16H(af[mi], bf[ni], acc[mi][ni], 0, 0, 0);
            if (pf) {
                int bo2 = bo ^ 1024;
                lds[bo2 + wiA0] = na0; lds[bo2 + wiA1] = na1;
                lds[bo2 + 512 + wiA0] = nb0; lds[bo2 + 512 + wiA1] = nb1;
                __syncthreads();
            }
        }

#pragma unroll
        for (int mi = 0; mi < 4; ++mi)
#pragma unroll
            for (int ni = 0; ni < 4; ++ni) {
                int n = n0 + wc * 64 + ni * 16 + lm;
                float bn = bias[n];
                int h = n >> 6, d = n & 63;
                int mbase = m0 + wr * 64 + mi * 16 + hi * 4;
                int bb = mbase >> 9, l0 = mbase & 511;
                if (z == 2) {
                    union { pk16 h2[2]; uint2 u2; } o;
                    o.h2[0] = __builtin_amdgcn_cvt_pkrtz(acc[mi][ni][0] + bn, acc[mi][ni][1] + bn);
                    o.h2[1] = __builtin_amdgcn_cvt_pkrtz(acc[mi][ni][2] + bn, acc[mi][ni][3] + bn);
                    *reinterpret_cast<uint2*>(out + (((bb * NH + h) * HD) + d) * SEQ + l0) = o.u2;
                } else {
#pragma unroll
                    for (int r = 0; r < 4; ++r)
                        out[(((bb * NH + h) * SEQ) + l0 + r) * HD + d] = (f16)(acc[mi][ni][r] + bn);
                }
            }
    } else {
        // ---------- interp role: bilinear bias from grid16 ----------
        int id = xcd * 16 + slot;        // 0..127, 2048 pairs per block
#pragma unroll 2
        for (int i = 0; i < 8; ++i) {
            int p = id * 2048 + i * 256 + t;
            int qi = p >> 9, ki = p & 511;
            float dx = a.qc[2 * qi] - a.kc[2 * ki];
            float dy = a.qc[2 * qi + 1] - a.kc[2 * ki + 1];
            float fxf = __builtin_amdgcn_fmed3f(__builtin_fmaf(dx, 8.f, 80.f), 0.f, 159.9999f);
            float fyf = __builtin_amdgcn_fmed3f(__builtin_fmaf(dy, 8.f, 80.f), 0.f, 159.9999f);
            int ix = (int)fxf, iy = (int)fyf;
            float fx = fxf - (float)ix, fy = fyf - (float)iy;
            const f16* c00 = a.grid16 + (iy * GN + ix) * 16;
            f16x8 g00 = *(const f16x8*)(c00);
            f16x8 g00b = *(const f16x8*)(c00 + 8);
            f16x8 g01 = *(const f16x8*)(c00 + 16);
            f16x8 g01b = *(const f16x8*)(c00 + 24);
            f16x8 g10 = *(const f16x8*)(c00 + GN * 16);
            f16x8 g10b = *(const f16x8*)(c00 + GN * 16 + 8);
            f16x8 g11 = *(const f16x8*)(c00 + GN * 16 + 16);
            f16x8 g11b = *(const f16x8*)(c00 + GN * 16 + 24);
            float o[12];
#pragma unroll
            for (int h = 0; h < 12; ++h) {
                float v00 = (float)(h < 8 ? g00[h] : g00b[h - 8]);
                float v01 = (float)(h < 8 ? g01[h] : g01b[h - 8]);
                float v10 = (float)(h < 8 ? g10[h] : g10b[h - 8]);
                float v11 = (float)(h < 8 ? g11[h] : g11b[h - 8]);
                float v0 = __builtin_fmaf(fx, v01 - v00, v00);
                float v1 = __builtin_fmaf(fx, v11 - v10, v10);
                o[h] = __builtin_fmaf(fy, v1 - v0, v0);
            }
#pragma unroll
            for (int h = 0; h < 12; ++h)
                a.bias16[h * (SEQ * SEQ) + p] = (f16)o[h];
        }
    }
}

// ---------------- O-proj GEMM: 128x128 tile, XCD-grouped mapping ----------------
__global__ void __launch_bounds__(256) k_gemmO(const f16* __restrict__ X,
                                               const f16* __restrict__ WT,
                                               const float* __restrict__ bias,
                                               float* __restrict__ out) {
    __shared__ uint4 lds[2048];
    int bid = blockIdx.x;
    int xcd = bid & 7, slot = bid >> 3;
    int m0 = (xcd * 4 + slot / 6) * 128, n0 = (slot % 6) * 128;
    int t = threadIdx.x, lane = t & 63, w = t >> 6;
    int wr = w >> 1, wc = w & 1;
    int lm = lane & 15, hi = lane >> 4;

    int srow = t >> 1, sch = t & 1;
    const f16* Ag = X + (m0 + srow) * DIM + sch * 16;
    const f16* Bg = WT + (n0 + srow) * DIM + sch * 16;
    int sw = (srow >> 1) & 3;
    int wiA0 = srow * 4 + ((2 * sch) ^ sw);
    int wiA1 = srow * 4 + ((2 * sch + 1) ^ sw);

    int aidx[4], bidx[4];
#pragma unroll
    for (int i = 0; i < 4; ++i) {
        int ar = wr * 64 + i * 16 + lm;
        aidx[i] = ar * 4 + (hi ^ ((ar >> 1) & 3));
        int br = wc * 64 + i * 16 + lm;
        bidx[i] = 512 + br * 4 + (hi ^ ((br >> 1) & 3));
    }

    f32x4 acc[4][4] = {};
    {
        lds[wiA0] = *(const uint4*)(Ag);
        lds[wiA1] = *(const uint4*)(Ag + 8);
        lds[512 + wiA0] = *(const uint4*)(Bg);
        lds[512 + wiA1] = *(const uint4*)(Bg + 8);
    }
    __syncthreads();

    for (int kt = 0; kt < 24; ++kt) {
        uint4 na0, na1, nb0, nb1;
        bool pf = kt < 23;
        if (pf) {
            const f16* An = Ag + (kt + 1) * 32;
            const f16* Bn = Bg + (kt + 1) * 32;
            na0 = *(const uint4*)(An);
            na1 = *(const uint4*)(An + 8);
            nb0 = *(const uint4*)(Bn);
            nb1 = *(const uint4*)(Bn + 8);
        }
        int bo = (kt & 1) << 10;
        f16x8 af[4], bf[4];
#pragma unroll
        for (int i = 0; i < 4; ++i) {
            af[i] = *(const f16x8*)&lds[bo + aidx[i]];
            bf[i] = *(const f16x8*)&lds[bo + bidx[i]];
        }
#pragma unroll
        for (int mi = 0; mi < 4; ++mi)
#pragma unroll
            for (int ni = 0; ni < 4; ++ni)
                acc[mi][ni] = MFMA16H(af[mi], bf[ni], acc[mi][ni], 0, 0, 0);
        if (pf) {
            int bo2 = bo ^ 1024;
            lds[bo2 + wiA0] = na0; lds[bo2 + wiA1] = na1;
            lds[bo2 + 512 + wiA0] = nb0; lds[bo2 + 512 + wiA1] = nb1;
            __syncthreads();
        }
    }

#pragma unroll
    for (int mi = 0; mi < 4; ++mi)
#pragma unroll
        for (int ni = 0; ni < 4; ++ni) {
            int n = n0 + wc * 64 + ni * 16 + lm;
            float bn = bias[n];
#pragma unroll
            for (int r = 0; r < 4; ++r) {
                int m = m0 + wr * 64 + mi * 16 + hi * 4 + r;
                out[m * DIM + n] = acc[mi][ni][r] + bn;
            }
        }
}

// ---------------- attention: 1536 blocks 1-D, XCD-grouped (b,h) ----------------
__global__ void __launch_bounds__(256) k_attn4(const f16* __restrict__ q_ws,
                                               const f16* __restrict__ k_ws,
                                               const f16* __restrict__ v_t,
                                               const f16* __restrict__ bias16,
                                               f16* __restrict__ attn_out) {
    __shared__ __align__(16) unsigned short sm16[32 * 520];  // f16 logits [32][520]
    __shared__ float inv32[32];
    int bid = blockIdx.x;
    int xcd = bid & 7, slot = bid >> 3;
    int g = xcd * 12 + (slot >> 4);
    int h = g % 12, b = g / 12;
    int qt = slot & 15;
    int q0 = qt * 32;
    int t = threadIdx.x, lane = t & 63, w = t >> 6;
    int lrow = lane & 15, hi = lane >> 4;
    int bh = b * NH + h;
    const f16* Q = q_ws + (bh * SEQ + q0) * HD;
    const f16* K = k_ws + bh * SEQ * HD;
    const f16* Bias = bias16 + (h * SEQ + q0) * SEQ;

    f16x8 aq[2][2];
#pragma unroll
    for (int rt = 0; rt < 2; ++rt)
#pragma unroll
        for (int ds = 0; ds < 2; ++ds) {
            f16x8 v = *(const f16x8*)(Q + (rt * 16 + lrow) * HD + ds * 32 + hi * 8);
            aq[rt][ds] = v * (f16)SCALE;   // exact (pow2)
        }

#pragma unroll
    for (int ct = 0; ct < 8; ++ct) {
        f32x4 acc0 = {}, acc1 = {};
        int kk = w * 128 + ct * 16 + lrow;
#pragma unroll
        for (int ds = 0; ds < 2; ++ds) {
            f16x8 bk = *(const f16x8*)(K + kk * HD + ds * 32 + hi * 8);
            acc0 = MFMA16H(aq[0][ds], bk, acc0, 0, 0, 0);
            acc1 = MFMA16H(aq[1][ds], bk, acc1, 0, 0, 0);
        }
#pragma unroll
        for (int r = 0; r < 4; ++r) {
            int row0 = hi * 4 + r;
            sm16[row0 * 520 + kk] = (unsigned short)__builtin_bit_cast(unsigned short,
                (f16)(acc0[r] + (float)Bias[row0 * SEQ + kk]));
            int row1 = 16 + hi * 4 + r;
            sm16[row1 * 520 + kk] = (unsigned short)__builtin_bit_cast(unsigned short,
                (f16)(acc1[r] + (float)Bias[row1 * SEQ + kk]));
        }
    }
    __syncthreads();

    {
        int row = t >> 3, seg = t & 7;
        int base = row * 520 + 2 * seg;
        float mx = -1e30f;
#pragma unroll 8
        for (int j = 0; j < 32; ++j) {
            union { uint u; f16 h[2]; } cv;
            cv.u = *(const uint*)&sm16[base + 16 * j];
            mx = fmaxf(mx, fmaxf((float)cv.h[0], (float)cv.h[1]));
        }
        mx = fmaxf(mx, __shfl_xor(mx, 1));
        mx = fmaxf(mx, __shfl_xor(mx, 2));
        mx = fmaxf(mx, __shfl_xor(mx, 4));
        float s = 0.f;
#pragma unroll 8
        for (int j = 0; j < 32; ++j) {
            union { uint u; f16 h[2]; } cv;
            cv.u = *(const uint*)&sm16[base + 16 * j];
            float p0 = __builtin_amdgcn_exp2f(((float)cv.h[0] - mx) * 1.442695041f);
            float p1 = __builtin_amdgcn_exp2f(((float)cv.h[1] - mx) * 1.442695041f);
            s += p0 + p1;
            union { pk16 h; uint u; } o;
            o.h = __builtin_amdgcn_cvt_pkrtz(p0, p1);
            *(uint*)&sm16[base + 16 * j] = o.u;
        }
        s += __shfl_xor(s, 1);
        s += __shfl_xor(s, 2);
        s += __shfl_xor(s, 4);
        if (seg == 0) inv32[row] = 1.0f / s;
    }
    __syncthreads();

    const f16* Vt = v_t + bh * HD * SEQ + (w * 16 + lrow) * SEQ;
    f32x4 oacc0 = {}, oacc1 = {};
    for (int kt = 0; kt < 16; ++kt) {
        f16x8 bv = *(const f16x8*)(Vt + kt * 32 + hi * 8);
        f16x8 pa0 = *(const f16x8*)&sm16[lrow * 520 + kt * 32 + hi * 8];
        f16x8 pa1 = *(const f16x8*)&sm16[(16 + lrow) * 520 + kt * 32 + hi * 8];
        oacc0 = MFMA16H(pa0, bv, oacc0, 0, 0, 0);
        oacc1 = MFMA16H(pa1, bv, oacc1, 0, 0, 0);
    }
#pragma unroll
    for (int r = 0; r < 4; ++r) {
        int row0 = hi * 4 + r;
        float v0 = oacc0[r] * inv32[row0];
        attn_out[(b * SEQ + q0 + row0) * DIM + h * HD + w * 16 + lrow] = (f16)v0;
        int row1 = 16 + hi * 4 + r;
        float v1 = oacc1[r] * inv32[row1];
        attn_out[(b * SEQ + q0 + row1) * DIM + h * HD + w * 16 + lrow] = (f16)v1;
    }
}

extern "C" void kernel_launch(void* const* d_in, const int* in_sizes, int n_in,
                              void* d_out, int out_size, void* d_ws, size_t ws_size,
                              hipStream_t stream) {
    const float* query     = (const float*)d_in[0];
    const float* key_value = (const float*)d_in[1];
    const float* qc        = (const float*)d_in[2];
    const float* kc        = (const float*)d_in[3];
    const float* Wq        = (const float*)d_in[4];
    const float* bq        = (const float*)d_in[5];
    const float* Wk        = (const float*)d_in[6];
    const float* bk        = (const float*)d_in[7];
    const float* Wv        = (const float*)d_in[8];
    const float* bv        = (const float*)d_in[9];
    const float* Wo        = (const float*)d_in[10];
    const float* bo        = (const float*)d_in[11];
    const float* W1        = (const float*)d_in[12];
    const float* b1        = (const float*)d_in[13];
    const float* W2        = (const float*)d_in[14];
    const float* b2        = (const float*)d_in[15];

    char* ws = (char*)d_ws;
    f16* Xq   = (f16*)(ws + 0);          // reused as attn_out
    f16* Xkv  = (f16*)(ws + 6291456);
    f16* WqT  = (f16*)(ws + 12582912);
    f16* WkT  = (f16*)(ws + 13762560);
    f16* WvT  = (f16*)(ws + 14942208);
    f16* WoT  = (f16*)(ws + 16121856);
    f16* q_ws = (f16*)(ws + 17301504);
    f16* k_ws = (f16*)(ws + 23592960);
    f16* v_t  = (f16*)(ws + 29884416);   // V written directly transposed [b,h,d,l]
    f16* bias16   = (f16*)(ws + 36175872); // 6291456 B
    f16* W1tab    = (f16*)(ws + 42467328);
    f16* W2tab    = (f16*)(ws + 42516480);
    float* gtab32 = (float*)(ws + 42541056); // 16384 B
    f16* grid16   = (f16*)(ws + 42557440);   // 829472 B
    f16* attn_out = Xq;   // Xq dead after Q projection

    PrepArgs pa;
    pa.query = query; pa.key_value = key_value; pa.Xq = Xq; pa.Xkv = Xkv;
    pa.W[0] = Wq; pa.W[1] = Wk; pa.W[2] = Wv; pa.W[3] = Wo;
    pa.WT[0] = WqT; pa.WT[1] = WkT; pa.WT[2] = WvT; pa.WT[3] = WoT;
    pa.W1 = W1; pa.b1 = b1; pa.W2 = W2;
    pa.W1tab = W1tab; pa.W2tab = W2tab; pa.gtab32 = gtab32;
    k_prep<<<dim3(5410), dim3(256), 0, stream>>>(pa);

    k_grid<<<dim3(406), dim3(256), 0, stream>>>((const f16x8*)W1tab, (const f16x8*)W2tab,
                                                b2, gtab32, grid16);

    MQArgs mq;
    mq.qc = qc; mq.kc = kc;
    mq.grid16 = grid16; mq.bias16 = bias16;
    mq.Xq = Xq; mq.Xkv = Xkv;
    mq.WqT = WqT; mq.WkT = WkT; mq.WvT = WvT;
    mq.bq = bq; mq.bk = bk; mq.bv = bv;
    mq.q_ws = q_ws; mq.k_ws = k_ws; mq.v_t = v_t;
    k_mq4<<<dim3(704), dim3(256), 0, stream>>>(mq);

    k_attn4<<<dim3(1536), dim3(256), 0, stream>>>(q_ws, k_ws, v_t, bias16, attn_out);
    k_gemmO<<<dim3(192), dim3(256), 0, stream>>>(attn_out, WoT, bo, (float*)d_out);
}

// Round 13
// 110.124 us; speedup vs baseline: 2.4264x; 1.0023x over previous
//
#include <hip/hip_runtime.h>
#include <hip/hip_bf16.h>
#include <stdint.h>
#include <math.h>

typedef __attribute__((ext_vector_type(4))) float f32x4;
typedef _Float16 f16;
typedef __attribute__((ext_vector_type(8))) _Float16 f16x8;
typedef decltype(__builtin_amdgcn_cvt_pkrtz(0.f, 0.f)) pk16;

#define DIM   768
#define NH    12
#define HD    64
#define NB    8
#define SEQ   512
#define SCALE 0.125f

#define GN    161          // grid points per axis (Δ=1/8 over [-10,10])
#define GPTS  (GN * GN)    // 25921

#define MFMA16H __builtin_amdgcn_mfma_f32_16x16x32_f16

// ---------------- prep (fused): f32->f16 converts + 4x W transpose + MLP tables ----------------
struct PrepArgs {
    const float* query; const float* key_value; f16* Xq; f16* Xkv;
    const float* W[4]; f16* WT[4];
    const float* W1; const float* b1; const float* W2;
    f16* W1tab; f16* W2tab; float* gtab32;
};

__global__ void __launch_bounds__(256) k_prep(PrepArgs pa) {
    __shared__ float tt[32][33];
    int g = blockIdx.x, t = threadIdx.x;
    if (g < 3072) {
        const float* in = (g < 1536) ? pa.query : pa.key_value;
        f16* out = (g < 1536) ? pa.Xq : pa.Xkv;
        int i = (g % 1536) * 256 + t;
        const float4* s = reinterpret_cast<const float4*>(in + i * 8);
        float4 f0 = s[0], f1 = s[1];
        union { pk16 h[4]; uint4 v; } o;
        o.h[0] = __builtin_amdgcn_cvt_pkrtz(f0.x, f0.y);
        o.h[1] = __builtin_amdgcn_cvt_pkrtz(f0.z, f0.w);
        o.h[2] = __builtin_amdgcn_cvt_pkrtz(f1.x, f1.y);
        o.h[3] = __builtin_amdgcn_cvt_pkrtz(f1.z, f1.w);
        reinterpret_cast<uint4*>(out)[i] = o.v;
    } else if (g < 5376) {
        int bi = g - 3072;               // 0..2303
        int z = bi / 576, rem = bi % 576;
        int bx = rem % 24, by = rem / 24;
        const float* W = pa.W[z];
        f16* WT = pa.WT[z];
        int n0 = bx * 32, k0 = by * 32;
        int tx = t & 31, ty = t >> 5;    // 32 x 8
#pragma unroll
        for (int j = 0; j < 4; ++j)
            tt[ty + 8 * j][tx] = W[(k0 + ty + 8 * j) * DIM + n0 + tx];
        __syncthreads();
#pragma unroll
        for (int j = 0; j < 4; ++j)
            WT[(n0 + ty + 8 * j) * DIM + k0 + tx] = (f16)tt[tx][ty + 8 * j];
    } else {
        int i = (g - 5376) * 256 + t;    // 0..8703
        if (i < 3072) {
            int lane = i & 63;
            int hi = lane >> 4, m = lane & 15;
            int u = (i >> 6) * 16 + m;
#pragma unroll
            for (int e = 0; e < 8; ++e) {
                float v = 0.f;
                if (hi == 0) {
                    if (e < 6) v = pa.W1[e * DIM + u];
                    else if (e == 6) v = pa.b1[u];
                }
                pa.W1tab[i * 8 + e] = (f16)v;
            }
        } else if (i < 4608) {
            int i2 = i - 3072;
            int j = i2 >> 6, lane = i2 & 63;
            int gq = lane >> 4, h = lane & 15;
#pragma unroll
            for (int e = 0; e < 8; ++e) {
                int u = 32 * j + ((e >> 2) << 4) + (gq << 2) + (e & 3);
                float v = (h < 12) ? pa.W2[u * 12 + h] : 0.f;
                pa.W2tab[i2 * 8 + e] = (f16)v;
            }
        } else {
            int i2 = i - 4608;           // 0..4095
            float x = (i2 + 0.5f) * (1.0f / 256.0f) - 8.0f;
            pa.gtab32[i2] = 0.5f * x * (1.0f + erff(x * 0.70710678f));
        }
    }
}

// ---------------- bias MLP evaluated on the 161x161 delta grid ----------------
__global__ void __launch_bounds__(256) k_grid(const f16x8* __restrict__ W1tab,
                                              const f16x8* __restrict__ W2tab,
                                              const float* __restrict__ b2,
                                              const float* __restrict__ gtab32,
                                              f16* __restrict__ grid16) {
    __shared__ float tab[4096];   // 16 KB gelu LUT
    int t = threadIdx.x, lane = t & 63, w = t >> 6;
    {
        const uint4* gt = (const uint4*)gtab32;
        uint4* st = (uint4*)tab;
#pragma unroll
        for (int i = 0; i < 4; ++i) st[i * 256 + t] = gt[i * 256 + t];
    }
    int hi = lane >> 4, m = lane & 15;
    int p0 = blockIdx.x * 64 + w * 16;
    int p = p0 + m;
    int gy = p / GN, gx = p - gy * GN;
    float dx = gx * 0.125f - 10.0f;
    float dy = gy * 0.125f - 10.0f;

    union { f16x8 v; pk16 h2[4]; } rf;
    { f16x8 zz = {}; rf.v = zz; }
    if (hi == 0) {
        rf.h2[0] = __builtin_amdgcn_cvt_pkrtz(dx, dy);
        rf.h2[1] = __builtin_amdgcn_cvt_pkrtz(fabsf(dx), fabsf(dy));
        rf.h2[2] = __builtin_amdgcn_cvt_pkrtz(dx * dx, dy * dy);
        rf.h2[3] = __builtin_amdgcn_cvt_pkrtz(1.0f, 0.0f);
    }

    float b2h = (m < 12) ? b2[m] : 0.f;
    f32x4 acc = {b2h, b2h, b2h, b2h};
    const f32x4 zero = {};
    const f16x8* w1p = W1tab + lane;
    const f16x8* w2p = W2tab + lane;
    __syncthreads();

#pragma unroll 2
    for (int j = 0; j < 24; ++j) {
        f16x8 a0  = w1p[(2 * j) * 64];
        f16x8 a1  = w1p[(2 * j + 1) * 64];
        f16x8 w2v = w2p[j * 64];
        f32x4 pre0 = MFMA16H(a0, rf.v, zero, 0, 0, 0);
        f32x4 pre1 = MFMA16H(a1, rf.v, zero, 0, 0, 0);
        float s0[4], s1[4];
#pragma unroll
        for (int e = 0; e < 4; ++e) {
            float x0 = pre0[e];
            float xi0 = __builtin_amdgcn_fmed3f(__builtin_fmaf(x0, 256.f, 2048.f), 0.f, 4095.f);
            float g0 = tab[(int)xi0];
            s0[e] = (x0 > 8.f) ? x0 : g0;
            float x1 = pre1[e];
            float xi1 = __builtin_amdgcn_fmed3f(__builtin_fmaf(x1, 256.f, 2048.f), 0.f, 4095.f);
            float g1 = tab[(int)xi1];
            s1[e] = (x1 > 8.f) ? x1 : g1;
        }
        union { f16x8 v; pk16 h2[4]; } pav;
        pav.h2[0] = __builtin_amdgcn_cvt_pkrtz(s0[0], s0[1]);
        pav.h2[1] = __builtin_amdgcn_cvt_pkrtz(s0[2], s0[3]);
        pav.h2[2] = __builtin_amdgcn_cvt_pkrtz(s1[0], s1[1]);
        pav.h2[3] = __builtin_amdgcn_cvt_pkrtz(s1[2], s1[3]);
        acc = MFMA16H(pav.v, w2v, acc, 0, 0, 0);
    }
    if (m < 12) {
#pragma unroll
        for (int r = 0; r < 4; ++r) {
            int pr = p0 + hi * 4 + r;
            if (pr < GPTS) grid16[pr * 16 + m] = (f16)acc[r];
        }
    }
}

// ---------------- fused QKV GEMM (64x64, depth-3 reg prefetch) + interp ----------------
// 2432 blocks = 8 XCD x 304 slots. slot<16: interp (id=xcd*16+slot).
// slot>=16: lid = xcd*288+(slot-16); m_group=lid/36 (8 per XCD -> A panels L2-resident);
//           within=lid%36: z=within/12, n_tile=within%12.
struct MQArgs {
    const float* qc; const float* kc;
    const f16* grid16; f16* bias16;
    const f16* Xq; const f16* Xkv;
    const f16* WqT; const f16* WkT; const f16* WvT;
    const float* bq; const float* bk; const float* bv;
    f16* q_ws; f16* k_ws; f16* v_t;
};

__global__ void __launch_bounds__(256) k_mq5(MQArgs a) {
    __shared__ uint4 lds[1024];   // 16 KB (GEMM dbuf)
    int bid = blockIdx.x, t = threadIdx.x;
    int lane = t & 63, w = t >> 6;
    int hi = lane >> 4, lm = lane & 15;
    int xcd = bid & 7, slot = bid >> 3;

    if (slot >= 16) {
        // ---------- GEMM role: 64x64 tile, BK=32, LDS dbuf + depth-3 reg prefetch ----------
        int lid = xcd * 288 + (slot - 16);     // 0..2303
        int m_group = lid / 36;
        int within = lid - m_group * 36;
        int z = within / 12;
        int n_tile = within - z * 12;
        int m0 = m_group * 64, n0 = n_tile * 64;
        const f16* X = (z == 0) ? a.Xq : a.Xkv;
        const f16* Wt = (z == 0) ? a.WqT : (z == 1) ? a.WkT : a.WvT;
        const float* bias = (z == 0) ? a.bq : (z == 1) ? a.bk : a.bv;
        f16* out = (z == 0) ? a.q_ws : (z == 1) ? a.k_ws : a.v_t;

        int wr = w >> 1, wc = w & 1;
        int srow = t >> 2, sslot = t & 3;      // 64 rows x 4 uint4-slots
        const f16* Ag = X + (m0 + srow) * DIM + sslot * 8;
        const f16* Bg = Wt + (n0 + srow) * DIM + sslot * 8;
        int wi = srow * 4 + (sslot ^ ((srow >> 1) & 3));

        int aidx[2], bidx[2];
#pragma unroll
        for (int i = 0; i < 2; ++i) {
            int ar = wr * 32 + i * 16 + lm;
            aidx[i] = ar * 4 + (hi ^ ((ar >> 1) & 3));
            int br = wc * 32 + i * 16 + lm;
            bidx[i] = 256 + br * 4 + (hi ^ ((br >> 1) & 3));
        }

        f32x4 acc[2][2] = {};
        // prologue: stage t0 to buf0; issue t1 -> set1, t2 -> set0
        {
            uint4 a0 = *(const uint4*)(Ag);
            uint4 b0 = *(const uint4*)(Bg);
            lds[wi] = a0;
            lds[256 + wi] = b0;
        }
        uint4 sA1 = *(const uint4*)(Ag + 32);   // t1 (odd set)
        uint4 sB1 = *(const uint4*)(Bg + 32);
        uint4 sA0 = *(const uint4*)(Ag + 64);   // t2 (even set)
        uint4 sB0 = *(const uint4*)(Bg + 64);
        __syncthreads();

#define MQ_COMPUTE(kt)                                                        \
        {                                                                     \
            int bo = ((kt) & 1) << 9;                                         \
            f16x8 af0 = *(const f16x8*)&lds[bo + aidx[0]];                    \
            f16x8 af1 = *(const f16x8*)&lds[bo + aidx[1]];                    \
            f16x8 bf0 = *(const f16x8*)&lds[bo + bidx[0]];                    \
            f16x8 bf1 = *(const f16x8*)&lds[bo + bidx[1]];                    \
            acc[0][0] = MFMA16H(af0, bf0, acc[0][0], 0, 0, 0);                \
            acc[0][1] = MFMA16H(af0, bf1, acc[0][1], 0, 0, 0);                \
            acc[1][0] = MFMA16H(af1, bf0, acc[1][0], 0, 0, 0);                \
            acc[1][1] = MFMA16H(af1, bf1, acc[1][1], 0, 0, 0);                \
        }

        for (int kp = 0; kp < 12; ++kp) {
            int kt = 2 * kp;
            // even iter: writes t(kt+1) from set1, re-issues set1 <- t(kt+3)
            MQ_COMPUTE(kt)
            {
                int bo2 = (((kt) & 1) << 9) ^ 512;
                lds[bo2 + wi] = sA1;             // waits only set1's loads (counted vmcnt)
                lds[bo2 + 256 + wi] = sB1;
                if (kt + 3 < 24) {
                    sA1 = *(const uint4*)(Ag + (kt + 3) * 32);
                    sB1 = *(const uint4*)(Bg + (kt + 3) * 32);
                }
                __syncthreads();
            }
            kt = 2 * kp + 1;
            // odd iter: writes t(kt+1) from set0, re-issues set0 <- t(kt+3)
            MQ_COMPUTE(kt)
            if (kt < 23) {
                int bo2 = (((kt) & 1) << 9) ^ 512;
                lds[bo2 + wi] = sA0;
                lds[bo2 + 256 + wi] = sB0;
                if (kt + 3 < 24) {
                    sA0 = *(const uint4*)(Ag + (kt + 3) * 32);
                    sB0 = *(const uint4*)(Bg + (kt + 3) * 32);
                }
                __syncthreads();
            }
        }
#undef MQ_COMPUTE

#pragma unroll
        for (int mi = 0; mi < 2; ++mi)
#pragma unroll
            for (int ni = 0; ni < 2; ++ni) {
                int n = n0 + wc * 32 + ni * 16 + lm;
                float bn = bias[n];
                int h = n >> 6, d = n & 63;
                int mbase = m0 + wr * 32 + mi * 16 + hi * 4;
                int bb = mbase >> 9, l0 = mbase & 511;
                if (z == 2) {
                    union { pk16 h2[2]; uint2 u2; } o;
                    o.h2[0] = __builtin_amdgcn_cvt_pkrtz(acc[mi][ni][0] + bn, acc[mi][ni][1] + bn);
                    o.h2[1] = __builtin_amdgcn_cvt_pkrtz(acc[mi][ni][2] + bn, acc[mi][ni][3] + bn);
                    *reinterpret_cast<uint2*>(out + (((bb * NH + h) * HD) + d) * SEQ + l0) = o.u2;
                } else {
#pragma unroll
                    for (int r = 0; r < 4; ++r)
                        out[(((bb * NH + h) * SEQ) + l0 + r) * HD + d] = (f16)(acc[mi][ni][r] + bn);
                }
            }
    } else {
        // ---------- interp role: bilinear bias from grid16 ----------
        int id = xcd * 16 + slot;        // 0..127, 2048 pairs per block
#pragma unroll 2
        for (int i = 0; i < 8; ++i) {
            int p = id * 2048 + i * 256 + t;
            int qi = p >> 9, ki = p & 511;
            float dx = a.qc[2 * qi] - a.kc[2 * ki];
            float dy = a.qc[2 * qi + 1] - a.kc[2 * ki + 1];
            float fxf = __builtin_amdgcn_fmed3f(__builtin_fmaf(dx, 8.f, 80.f), 0.f, 159.9999f);
            float fyf = __builtin_amdgcn_fmed3f(__builtin_fmaf(dy, 8.f, 80.f), 0.f, 159.9999f);
            int ix = (int)fxf, iy = (int)fyf;
            float fx = fxf - (float)ix, fy = fyf - (float)iy;
            const f16* c00 = a.grid16 + (iy * GN + ix) * 16;
            f16x8 g00 = *(const f16x8*)(c00);
            f16x8 g00b = *(const f16x8*)(c00 + 8);
            f16x8 g01 = *(const f16x8*)(c00 + 16);
            f16x8 g01b = *(const f16x8*)(c00 + 24);
            f16x8 g10 = *(const f16x8*)(c00 + GN * 16);
            f16x8 g10b = *(const f16x8*)(c00 + GN * 16 + 8);
            f16x8 g11 = *(const f16x8*)(c00 + GN * 16 + 16);
            f16x8 g11b = *(const f16x8*)(c00 + GN * 16 + 24);
            float o[12];
#pragma unroll
            for (int h = 0; h < 12; ++h) {
                float v00 = (float)(h < 8 ? g00[h] : g00b[h - 8]);
                float v01 = (float)(h < 8 ? g01[h] : g01b[h - 8]);
                float v10 = (float)(h < 8 ? g10[h] : g10b[h - 8]);
                float v11 = (float)(h < 8 ? g11[h] : g11b[h - 8]);
                float v0 = __builtin_fmaf(fx, v01 - v00, v00);
                float v1 = __builtin_fmaf(fx, v11 - v10, v10);
                o[h] = __builtin_fmaf(fy, v1 - v0, v0);
            }
#pragma unroll
            for (int h = 0; h < 12; ++h)
                a.bias16[h * (SEQ * SEQ) + p] = (f16)o[h];
        }
    }
}

// ---------------- O-proj GEMM: 128x128 tile, XCD-grouped mapping ----------------
__global__ void __launch_bounds__(256) k_gemmO(const f16* __restrict__ X,
                                               const f16* __restrict__ WT,
                                               const float* __restrict__ bias,
                                               float* __restrict__ out) {
    __shared__ uint4 lds[2048];
    int bid = blockIdx.x;
    int xcd = bid & 7, slot = bid >> 3;
    int m0 = (xcd * 4 + slot / 6) * 128, n0 = (slot % 6) * 128;
    int t = threadIdx.x, lane = t & 63, w = t >> 6;
    int wr = w >> 1, wc = w & 1;
    int lm = lane & 15, hi = lane >> 4;

    int srow = t >> 1, sch = t & 1;
    const f16* Ag = X + (m0 + srow) * DIM + sch * 16;
    const f16* Bg = WT + (n0 + srow) * DIM + sch * 16;
    int sw = (srow >> 1) & 3;
    int wiA0 = srow * 4 + ((2 * sch) ^ sw);
    int wiA1 = srow * 4 + ((2 * sch + 1) ^ sw);

    int aidx[4], bidx[4];
#pragma unroll
    for (int i = 0; i < 4; ++i) {
        int ar = wr * 64 + i * 16 + lm;
        aidx[i] = ar * 4 + (hi ^ ((ar >> 1) & 3));
        int br = wc * 64 + i * 16 + lm;
        bidx[i] = 512 + br * 4 + (hi ^ ((br >> 1) & 3));
    }

    f32x4 acc[4][4] = {};
    {
        lds[wiA0] = *(const uint4*)(Ag);
        lds[wiA1] = *(const uint4*)(Ag + 8);
        lds[512 + wiA0] = *(const uint4*)(Bg);
        lds[512 + wiA1] = *(const uint4*)(Bg + 8);
    }
    __syncthreads();

    for (int kt = 0; kt < 24; ++kt) {
        uint4 na0, na1, nb0, nb1;
        bool pf = kt < 23;
        if (pf) {
            const f16* An = Ag + (kt + 1) * 32;
            const f16* Bn = Bg + (kt + 1) * 32;
            na0 = *(const uint4*)(An);
            na1 = *(const uint4*)(An + 8);
            nb0 = *(const uint4*)(Bn);
            nb1 = *(const uint4*)(Bn + 8);
        }
        int bo = (kt & 1) << 10;
        f16x8 af[4], bf[4];
#pragma unroll
        for (int i = 0; i < 4; ++i) {
            af[i] = *(const f16x8*)&lds[bo + aidx[i]];
            bf[i] = *(const f16x8*)&lds[bo + bidx[i]];
        }
#pragma unroll
        for (int mi = 0; mi < 4; ++mi)
#pragma unroll
            for (int ni = 0; ni < 4; ++ni)
                acc[mi][ni] = MFMA16H(af[mi], bf[ni], acc[mi][ni], 0, 0, 0);
        if (pf) {
            int bo2 = bo ^ 1024;
            lds[bo2 + wiA0] = na0; lds[bo2 + wiA1] = na1;
            lds[bo2 + 512 + wiA0] = nb0; lds[bo2 + 512 + wiA1] = nb1;
            __syncthreads();
        }
    }

#pragma unroll
    for (int mi = 0; mi < 4; ++mi)
#pragma unroll
        for (int ni = 0; ni < 4; ++ni) {
            int n = n0 + wc * 64 + ni * 16 + lm;
            float bn = bias[n];
#pragma unroll
            for (int r = 0; r < 4; ++r) {
                int m = m0 + wr * 64 + mi * 16 + hi * 4 + r;
                out[m * DIM + n] = acc[mi][ni][r] + bn;
            }
        }
}

// ---------------- attention: 1536 blocks 1-D, XCD-grouped (b,h) ----------------
__global__ void __launch_bounds__(256) k_attn4(const f16* __restrict__ q_ws,
                                               const f16* __restrict__ k_ws,
                                               const f16* __restrict__ v_t,
                                               const f16* __restrict__ bias16,
                                               f16* __restrict__ attn_out) {
    __shared__ __align__(16) unsigned short sm16[32 * 520];  // f16 logits [32][520]
    __shared__ float inv32[32];
    int bid = blockIdx.x;
    int xcd = bid & 7, slot = bid >> 3;
    int g = xcd * 12 + (slot >> 4);
    int h = g % 12, b = g / 12;
    int qt = slot & 15;
    int q0 = qt * 32;
    int t = threadIdx.x, lane = t & 63, w = t >> 6;
    int lrow = lane & 15, hi = lane >> 4;
    int bh = b * NH + h;
    const f16* Q = q_ws + (bh * SEQ + q0) * HD;
    const f16* K = k_ws + bh * SEQ * HD;
    const f16* Bias = bias16 + (h * SEQ + q0) * SEQ;

    f16x8 aq[2][2];
#pragma unroll
    for (int rt = 0; rt < 2; ++rt)
#pragma unroll
        for (int ds = 0; ds < 2; ++ds) {
            f16x8 v = *(const f16x8*)(Q + (rt * 16 + lrow) * HD + ds * 32 + hi * 8);
            aq[rt][ds] = v * (f16)SCALE;   // exact (pow2)
        }

#pragma unroll
    for (int ct = 0; ct < 8; ++ct) {
        f32x4 acc0 = {}, acc1 = {};
        int kk = w * 128 + ct * 16 + lrow;
#pragma unroll
        for (int ds = 0; ds < 2; ++ds) {
            f16x8 bk = *(const f16x8*)(K + kk * HD + ds * 32 + hi * 8);
            acc0 = MFMA16H(aq[0][ds], bk, acc0, 0, 0, 0);
            acc1 = MFMA16H(aq[1][ds], bk, acc1, 0, 0, 0);
        }
#pragma unroll
        for (int r = 0; r < 4; ++r) {
            int row0 = hi * 4 + r;
            sm16[row0 * 520 + kk] = (unsigned short)__builtin_bit_cast(unsigned short,
                (f16)(acc0[r] + (float)Bias[row0 * SEQ + kk]));
            int row1 = 16 + hi * 4 + r;
            sm16[row1 * 520 + kk] = (unsigned short)__builtin_bit_cast(unsigned short,
                (f16)(acc1[r] + (float)Bias[row1 * SEQ + kk]));
        }
    }
    __syncthreads();

    {
        int row = t >> 3, seg = t & 7;
        int base = row * 520 + 2 * seg;
        float mx = -1e30f;
#pragma unroll 8
        for (int j = 0; j < 32; ++j) {
            union { uint u; f16 h[2]; } cv;
            cv.u = *(const uint*)&sm16[base + 16 * j];
            mx = fmaxf(mx, fmaxf((float)cv.h[0], (float)cv.h[1]));
        }
        mx = fmaxf(mx, __shfl_xor(mx, 1));
        mx = fmaxf(mx, __shfl_xor(mx, 2));
        mx = fmaxf(mx, __shfl_xor(mx, 4));
        float s = 0.f;
#pragma unroll 8
        for (int j = 0; j < 32; ++j) {
            union { uint u; f16 h[2]; } cv;
            cv.u = *(const uint*)&sm16[base + 16 * j];
            float p0 = __builtin_amdgcn_exp2f(((float)cv.h[0] - mx) * 1.442695041f);
            float p1 = __builtin_amdgcn_exp2f(((float)cv.h[1] - mx) * 1.442695041f);
            s += p0 + p1;
            union { pk16 h; uint u; } o;
            o.h = __builtin_amdgcn_cvt_pkrtz(p0, p1);
            *(uint*)&sm16[base + 16 * j] = o.u;
        }
        s += __shfl_xor(s, 1);
        s += __shfl_xor(s, 2);
        s += __shfl_xor(s, 4);
        if (seg == 0) inv32[row] = 1.0f / s;
    }
    __syncthreads();

    const f16* Vt = v_t + bh * HD * SEQ + (w * 16 + lrow) * SEQ;
    f32x4 oacc0 = {}, oacc1 = {};
    for (int kt = 0; kt < 16; ++kt) {
        f16x8 bv = *(const f16x8*)(Vt + kt * 32 + hi * 8);
        f16x8 pa0 = *(const f16x8*)&sm16[lrow * 520 + kt * 32 + hi * 8];
        f16x8 pa1 = *(const f16x8*)&sm16[(16 + lrow) * 520 + kt * 32 + hi * 8];
        oacc0 = MFMA16H(pa0, bv, oacc0, 0, 0, 0);
        oacc1 = MFMA16H(pa1, bv, oacc1, 0, 0, 0);
    }
#pragma unroll
    for (int r = 0; r < 4; ++r) {
        int row0 = hi * 4 + r;
        float v0 = oacc0[r] * inv32[row0];
        attn_out[(b * SEQ + q0 + row0) * DIM + h * HD + w * 16 + lrow] = (f16)v0;
        int row1 = 16 + hi * 4 + r;
        float v1 = oacc1[r] * inv32[row1];
        attn_out[(b * SEQ + q0 + row1) * DIM + h * HD + w * 16 + lrow] = (f16)v1;
    }
}

extern "C" void kernel_launch(void* const* d_in, const int* in_sizes, int n_in,
                              void* d_out, int out_size, void* d_ws, size_t ws_size,
                              hipStream_t stream) {
    const float* query     = (const float*)d_in[0];
    const float* key_value = (const float*)d_in[1];
    const float* qc        = (const float*)d_in[2];
    const float* kc        = (const float*)d_in[3];
    const float* Wq        = (const float*)d_in[4];
    const float* bq        = (const float*)d_in[5];
    const float* Wk        = (const float*)d_in[6];
    const float* bk        = (const float*)d_in[7];
    const float* Wv        = (const float*)d_in[8];
    const float* bv        = (const float*)d_in[9];
    const float* Wo        = (const float*)d_in[10];
    const float* bo        = (const float*)d_in[11];
    const float* W1        = (const float*)d_in[12];
    const float* b1        = (const float*)d_in[13];
    const float* W2        = (const float*)d_in[14];
    const float* b2        = (const float*)d_in[15];

    char* ws = (char*)d_ws;
    f16* Xq   = (f16*)(ws + 0);          // reused as attn_out
    f16* Xkv  = (f16*)(ws + 6291456);
    f16* WqT  = (f16*)(ws + 12582912);
    f16* WkT  = (f16*)(ws + 13762560);
    f16* WvT  = (f16*)(ws + 14942208);
    f16* WoT  = (f16*)(ws + 16121856);
    f16* q_ws = (f16*)(ws + 17301504);
    f16* k_ws = (f16*)(ws + 23592960);
    f16* v_t  = (f16*)(ws + 29884416);   // V written directly transposed [b,h,d,l]
    f16* bias16   = (f16*)(ws + 36175872); // 6291456 B
    f16* W1tab    = (f16*)(ws + 42467328);
    f16* W2tab    = (f16*)(ws + 42516480);
    float* gtab32 = (float*)(ws + 42541056); // 16384 B
    f16* grid16   = (f16*)(ws + 42557440);   // 829472 B
    f16* attn_out = Xq;   // Xq dead after Q projection

    PrepArgs pa;
    pa.query = query; pa.key_value = key_value; pa.Xq = Xq; pa.Xkv = Xkv;
    pa.W[0] = Wq; pa.W[1] = Wk; pa.W[2] = Wv; pa.W[3] = Wo;
    pa.WT[0] = WqT; pa.WT[1] = WkT; pa.WT[2] = WvT; pa.WT[3] = WoT;
    pa.W1 = W1; pa.b1 = b1; pa.W2 = W2;
    pa.W1tab = W1tab; pa.W2tab = W2tab; pa.gtab32 = gtab32;
    k_prep<<<dim3(5410), dim3(256), 0, stream>>>(pa);

    k_grid<<<dim3(406), dim3(256), 0, stream>>>((const f16x8*)W1tab, (const f16x8*)W2tab,
                                                b2, gtab32, grid16);

    MQArgs mq;
    mq.qc = qc; mq.kc = kc;
    mq.grid16 = grid16; mq.bias16 = bias16;
    mq.Xq = Xq; mq.Xkv = Xkv;
    mq.WqT = WqT; mq.WkT = WkT; mq.WvT = WvT;
    mq.bq = bq; mq.bk = bk; mq.bv = bv;
    mq.q_ws = q_ws; mq.k_ws = k_ws; mq.v_t = v_t;
    k_mq5<<<dim3(2432), dim3(256), 0, stream>>>(mq);

    k_attn4<<<dim3(1536), dim3(256), 0, stream>>>(q_ws, k_ws, v_t, bias16, attn_out);
    k_gemmO<<<dim3(192), dim3(256), 0, stream>>>(attn_out, WoT, bo, (float*)d_out);
}